// Round 9
// baseline (635.047 us; speedup 1.0000x reference)
//
#include <hip/hip_runtime.h>
#include <hip/hip_bf16.h>
#include <hip/hip_fp8.h>
#include <cstdint>
#include <cstddef>

// Problem constants
#define NN     20000     // nodes
#define NF     128       // in features
#define NH     56        // heads
#define OC     32        // out channels per head
#define DD1    1792      // NH*OC
#define NE     100000    // edges (before self loops)
#define ETOT   120000    // edges + self loops
#define NG     50        // graphs
#define EPS_BN 1e-5f
#define GRP    16        // nodes per wave in aggregate
#define EB     16        // edge batch (x2 buffers = 32 loads in flight)
#define NGROUPS (NN / GRP)   // 1250

typedef __bf16 bf16x8 __attribute__((ext_vector_type(8)));
typedef float  floatx4 __attribute__((ext_vector_type(4)));
typedef float  floatx2 __attribute__((ext_vector_type(2)));
typedef unsigned int u32;
typedef __attribute__((address_space(1))) u32 gu32;
typedef __attribute__((address_space(3))) u32 lu32;

__device__ __forceinline__ void async_copy16(void* lds, const void* g) {
    __builtin_amdgcn_global_load_lds((gu32*)const_cast<void*>(g), (lu32*)lds, 16, 0, 0);
}

// decode 4 fp8 (e4m3, packed in u32) to 4 floats (HW cvt when available)
__device__ __forceinline__ void dec_fp8x4(u32 u, float* v) {
#if __has_builtin(__builtin_amdgcn_cvt_pk_f32_fp8)
    floatx2 lo = __builtin_amdgcn_cvt_pk_f32_fp8(u, false);
    floatx2 hi = __builtin_amdgcn_cvt_pk_f32_fp8(u, true);
    v[0] = lo[0]; v[1] = lo[1]; v[2] = hi[0]; v[3] = hi[1];
#else
    #pragma unroll
    for (int b = 0; b < 4; ++b) {
        __hip_fp8_e4m3 t;
        t.__x = (u >> (8 * b)) & 0xff;
        v[b] = (float)t;
    }
#endif
}

__device__ __forceinline__ void fma_fp8x4(u32 u, float a, float* acc) {
    float v[4];
    dec_fp8x4(u, v);
    #pragma unroll
    for (int b = 0; b < 4; ++b) acc[b] += a * v[b];
}

// ---------------- elementwise cast fp32 -> bf16 ----------------
__global__ __launch_bounds__(256) void cast_bf16_kernel(const float* __restrict__ in,
                                                        __hip_bfloat16* __restrict__ out, int n) {
    int i = blockIdx.x * 256 + threadIdx.x;
    if (i < n) out[i] = __float2bfloat16(in[i]);
}

// ---------------- tiled transpose + cast: in[R][C] f32 -> out[C][R] bf16 ----------------
__global__ __launch_bounds__(256) void transpose_cast_kernel(const float* __restrict__ in,
                                                             __hip_bfloat16* __restrict__ out,
                                                             int R, int C) {
    __shared__ float tile[32][33];
    int c0 = blockIdx.x * 32, r0 = blockIdx.y * 32;
    int tx = threadIdx.x & 31, ty = threadIdx.x >> 5;   // ty in 0..7
    #pragma unroll
    for (int i = 0; i < 32; i += 8) {
        int r = r0 + ty + i, c = c0 + tx;
        if (r < R && c < C) tile[ty + i][tx] = in[(size_t)r * C + c];
    }
    __syncthreads();
    #pragma unroll
    for (int i = 0; i < 32; i += 8) {
        int c = c0 + ty + i, r = r0 + tx;
        if (c < C && r < R) out[(size_t)c * R + r] = __float2bfloat16(tile[tx][ty + i]);
    }
}

// ---------------- CSR build: histogram / scan / scatter ----------------
__global__ __launch_bounds__(256) void hist_kernel(const int* __restrict__ ei, int* __restrict__ deg) {
    int i = blockIdx.x * 256 + threadIdx.x;
    if (i >= ETOT) return;
    int dst = (i < NE) ? ei[NE + i] : (i - NE);
    atomicAdd(&deg[dst], 1);
}

__global__ __launch_bounds__(1024) void scan_kernel(const int* __restrict__ deg,
                                                    int* __restrict__ rowptr,
                                                    int* __restrict__ cursor) {
    __shared__ int buf[1024];
    int t = threadIdx.x;
    const int CH = (NN + 1023) >> 10;   // 20
    int base = t * CH;
    int s = 0;
    for (int j = 0; j < CH; ++j) { int idx = base + j; if (idx < NN) s += deg[idx]; }
    buf[t] = s;
    __syncthreads();
    for (int off = 1; off < 1024; off <<= 1) {
        int v = (t >= off) ? buf[t - off] : 0;
        __syncthreads();
        buf[t] += v;
        __syncthreads();
    }
    int run = buf[t] - s;   // exclusive
    for (int j = 0; j < CH; ++j) {
        int idx = base + j;
        if (idx < NN) { rowptr[idx] = run; cursor[idx] = run; run += deg[idx]; }
    }
    if (t == 1023) rowptr[NN] = buf[1023];
}

__global__ __launch_bounds__(256) void scatter_kernel(const int* __restrict__ ei,
                                                      int* __restrict__ cursor,
                                                      int* __restrict__ csr_src) {
    int i = blockIdx.x * 256 + threadIdx.x;
    if (i >= ETOT) return;
    int s, d;
    if (i < NE) { s = ei[i]; d = ei[NE + i]; } else { s = i - NE; d = i - NE; }
    int pos = atomicAdd(&cursor[d], 1);
    csr_src[pos] = s;
}

// ---------------- bf16 MFMA GEMM, 192x256 tile, 3-phase (round-5 proven, 8 waves) ----------------
// REVERTED from the 4-wave experiment (round 8: 164us, occupancy 10.8% — TLP loss beat
// the 24% LDS-traffic saving). 8 waves (2Mx4N), per-wave C 96x64, BK=64, 2 LDS bufs.
// Output C8 is written SLICE-MAJOR: h8[f][row][256B] where f = col>>8 (n0 is a multiple
// of 256 so f = bx uniformly per block) — zero-cost relayout for the gather kernels.
__global__ __launch_bounds__(512, 2) void gemm_192(const __hip_bfloat16* __restrict__ A,
                                                   const __hip_bfloat16* __restrict__ Bt,
                                                   unsigned char* __restrict__ C8,
                                                   int M, int N, int K) {
    __shared__ __align__(16) unsigned short lds[2][28672];  // per buf: A[192][64] | B[256][64]
    const int tid  = threadIdx.x;
    const int lane = tid & 63, wave = tid >> 6;
    const int wm = wave >> 2, wn = wave & 3;     // 2 x 4 wave grid; per-wave C: 96 x 64

    const int nbx = N >> 8;                      // 7
    const int nby = (M + 191) / 192;             // 105
    const int nwg = nbx * nby;                   // 735
    const int q = nwg >> 3, r = nwg & 7;
    const int xcd = blockIdx.x & 7, bidx = blockIdx.x >> 3;
    const int wg = (xcd < r ? xcd * (q + 1) : r * (q + 1) + (xcd - r) * q) + bidx;
    const int by = wg / nbx, bx = wg - by * nbx;
    const int m0 = by * 192, n0 = bx << 8;

    const int NT = K >> 6;                       // K-tiles of 64: 28 (L2) / 2 (L1)

    const int qq = lane >> 4, rr = lane & 15;

    auto stageA = [&](int kt, int b) {
        #pragma unroll
        for (int i = 0; i < 3; ++i) {
            int slot = i * 512 + tid;
            int row = slot >> 3, pch = slot & 7;
            int lc = pch ^ (row & 7);            // pre-swizzled global source (rule #21)
            int gr = m0 + row; if (gr > M - 1) gr = M - 1;
            async_copy16(&lds[b][slot * 8], A + (size_t)gr * K + (kt << 6) + lc * 8);
        }
    };
    auto stageB = [&](int kt, int b) {
        #pragma unroll
        for (int i = 0; i < 4; ++i) {
            int slot = i * 512 + tid;
            int row = slot >> 3, pch = slot & 7;
            int lc = pch ^ (row & 7);
            async_copy16(&lds[b][12288 + slot * 8], Bt + (size_t)(n0 + row) * K + (kt << 6) + lc * 8);
        }
    };

    floatx4 zero = {0.f, 0.f, 0.f, 0.f};
    floatx4 acc[6][4];
    #pragma unroll
    for (int i = 0; i < 6; ++i)
        #pragma unroll
        for (int jj = 0; jj < 4; ++jj) acc[i][jj] = zero;

    bf16x8 aF[3][2], bA[2][2], bB[2][2];

    auto loadA = [&](int b, int mg) {
        #pragma unroll
        for (int mf = 0; mf < 3; ++mf)
            #pragma unroll
            for (int s = 0; s < 2; ++s) {
                int row = wm * 96 + mg * 48 + mf * 16 + rr;
                int pch = (s * 4 + qq) ^ (row & 7);
                aF[mf][s] = *(const bf16x8*)&lds[b][row * 64 + pch * 8];
            }
    };
    auto loadB = [&](int b, bf16x8 (&bF)[2][2], int ng) {
        #pragma unroll
        for (int nf = 0; nf < 2; ++nf)
            #pragma unroll
            for (int s = 0; s < 2; ++s) {
                int row = wn * 64 + (ng * 2 + nf) * 16 + rr;
                int pch = (s * 4 + qq) ^ (row & 7);
                bF[nf][s] = *(const bf16x8*)&lds[b][12288 + row * 64 + pch * 8];
            }
    };
    auto mfmaQ = [&](int mg, int ng, bf16x8 (&bF)[2][2]) {
        #pragma unroll
        for (int mf = 0; mf < 3; ++mf)
            #pragma unroll
            for (int nf = 0; nf < 2; ++nf)
                #pragma unroll
                for (int s = 0; s < 2; ++s)
                    acc[mg * 3 + mf][ng * 2 + nf] = __builtin_amdgcn_mfma_f32_16x16x32_bf16(
                        aF[mf][s], bF[nf][s], acc[mg * 3 + mf][ng * 2 + nf], 0, 0, 0);
    };

#define SB0 __builtin_amdgcn_sched_barrier(0)
#define GBAR do { SB0; __builtin_amdgcn_s_barrier(); SB0; } while (0)

    stageB(0, 0); stageA(0, 0);
    stageB(1, 1); stageA(1, 1);
    SB0;
    asm volatile("s_waitcnt vmcnt(7)" ::: "memory");
    GBAR;

    for (int t = 0; t < NT; ++t) {
        const int p = t & 1;
        int tp = t + 2; while (tp >= NT) tp -= 2;

        loadA(p, 0); loadB(p, bA, 0);
        GBAR;
        __builtin_amdgcn_s_setprio(1);
        mfmaQ(0, 0, bA);
        __builtin_amdgcn_s_setprio(0);
        GBAR;

        loadB(p, bB, 1);
        stageB(tp, p);
        GBAR;
        __builtin_amdgcn_s_setprio(1);
        mfmaQ(0, 1, bB);
        __builtin_amdgcn_s_setprio(0);
        GBAR;

        loadA(p, 1);
        stageA(tp, p);
        SB0;
        asm volatile("s_waitcnt vmcnt(7)" ::: "memory");
        GBAR;
        __builtin_amdgcn_s_setprio(1);
        mfmaQ(1, 1, bB);
        mfmaQ(1, 0, bA);
        __builtin_amdgcn_s_setprio(0);
        GBAR;
    }
#undef GBAR
#undef SB0

    // epilogue: fp8 quantize + store, SLICE-MAJOR: C8[bx][rowc][inner] (inner < 256)
    #pragma unroll
    for (int mt = 0; mt < 6; ++mt) {
        #pragma unroll
        for (int r4 = 0; r4 < 4; ++r4) {
            int rowc = m0 + wm * 96 + mt * 16 + (lane >> 4) * 4 + r4;
            if (rowc < M) {
                float v0 = acc[mt][0][r4], v1 = acc[mt][1][r4];
                float v2 = acc[mt][2][r4], v3 = acc[mt][3][r4];
                unsigned char q8[4];
#if __has_builtin(__builtin_amdgcn_cvt_pk_fp8_f32)
                u32 p01 = (u32)__builtin_amdgcn_cvt_pk_fp8_f32(v0, v1, 0, false);
                u32 p23 = (u32)__builtin_amdgcn_cvt_pk_fp8_f32(v2, v3, 0, false);
                q8[0] = p01 & 0xff; q8[1] = (p01 >> 8) & 0xff;
                q8[2] = p23 & 0xff; q8[3] = (p23 >> 8) & 0xff;
#else
                { __hip_fp8_e4m3 t0(v0), t1(v1), t2(v2), t3(v3);
                  q8[0] = t0.__x; q8[1] = t1.__x; q8[2] = t2.__x; q8[3] = t3.__x; }
#endif
                #pragma unroll
                for (int nt = 0; nt < 4; ++nt) {
                    int inner = wn * 64 + nt * 16 + (lane & 15);       // < 256
                    C8[(size_t)bx * NN * 256 + (size_t)rowc * 256 + inner] = q8[nt];
                }
            }
        }
    }
}

// ---------------- attention scores (slice-major h8): head h lives at h8[h>>3][node][(h&7)*32] ----------------
__global__ __launch_bounds__(256) void attn_score(const unsigned char* __restrict__ h8,
                                                  const float* __restrict__ att_src,
                                                  const float* __restrict__ att_dst,
                                                  float* __restrict__ as_,
                                                  float* __restrict__ ad_) {
    int wave = threadIdx.x >> 6, lane = threadIdx.x & 63;
    int node = blockIdx.x * 4 + wave;
    if (node >= NN || lane >= NH) return;
    const uint2* hp = (const uint2*)(h8 + (size_t)(lane >> 3) * NN * 256
                                        + (size_t)node * 256 + (lane & 7) * OC);   // 32 B / head
    float s = 0.f, d = 0.f;
    #pragma unroll
    for (int jj = 0; jj < 4; ++jj) {
        uint2 u2 = hp[jj];
        u32 us[2] = {u2.x, u2.y};
        #pragma unroll
        for (int w = 0; w < 2; ++w) {
            float v[4];
            dec_fp8x4(us[w], v);
            #pragma unroll
            for (int b = 0; b < 4; ++b) {
                int o = jj * 8 + w * 4 + b;
                s += v[b] * att_src[lane * OC + o];
                d += v[b] * att_dst[lane * OC + o];
            }
        }
    }
    as_[(size_t)node * NH + lane] = s;
    ad_[(size_t)node * NH + lane] = d;
}

// ---------------- node-boundary flush for the fused streaming aggregate ----------------
template <int LAYER>
__device__ __forceinline__ void flush_node(float* acc, float den, int cur, int f, int lane,
                                           const float* __restrict__ bias,
                                           const float* __restrict__ bng,
                                           const float* __restrict__ bnb,
                                           const float* __restrict__ bnm,
                                           const float* __restrict__ bnv,
                                           void* __restrict__ outp) {
    float inv = 1.f / den;
    #pragma unroll
    for (int k = 0; k < 4; ++k) acc[k] *= inv;

    if constexpr (LAYER == 1) {
        int d0 = f * 256 + lane * 4;
        u32 r01, r23;
        {
            float v0 = acc[0] + bias[d0 + 0];
            float v1 = acc[1] + bias[d0 + 1];
            float v2 = acc[2] + bias[d0 + 2];
            float v3 = acc[3] + bias[d0 + 3];
            v0 = v0 > 0.f ? v0 : expm1f(v0);
            v1 = v1 > 0.f ? v1 : expm1f(v1);
            v2 = v2 > 0.f ? v2 : expm1f(v2);
            v3 = v3 > 0.f ? v3 : expm1f(v3);
            v0 = (v0 - bnm[d0 + 0]) * rsqrtf(bnv[d0 + 0] + EPS_BN) * bng[d0 + 0] + bnb[d0 + 0];
            v1 = (v1 - bnm[d0 + 1]) * rsqrtf(bnv[d0 + 1] + EPS_BN) * bng[d0 + 1] + bnb[d0 + 1];
            v2 = (v2 - bnm[d0 + 2]) * rsqrtf(bnv[d0 + 2] + EPS_BN) * bng[d0 + 2] + bnb[d0 + 2];
            v3 = (v3 - bnm[d0 + 3]) * rsqrtf(bnv[d0 + 3] + EPS_BN) * bng[d0 + 3] + bnb[d0 + 3];
            __hip_bfloat16 b0 = __float2bfloat16(v0), b1 = __float2bfloat16(v1);
            __hip_bfloat16 b2 = __float2bfloat16(v2), b3 = __float2bfloat16(v3);
            r01 = (u32)*(unsigned short*)&b0 | ((u32)*(unsigned short*)&b1 << 16);
            r23 = (u32)*(unsigned short*)&b2 | ((u32)*(unsigned short*)&b3 << 16);
        }
        uint2 pk; pk.x = r01; pk.y = r23;
        *(uint2*)((__hip_bfloat16*)outp + (size_t)cur * DD1 + d0) = pk;
    } else {
        // sum over the 8 heads held by this wave (lane groups stride 8)
        #pragma unroll
        for (int k = 0; k < 4; ++k) {
            acc[k] += __shfl_xor(acc[k], 8, 64);
            acc[k] += __shfl_xor(acc[k], 16, 64);
            acc[k] += __shfl_xor(acc[k], 32, 64);
        }
        if (lane < 8) {
            floatx4 pk;
            #pragma unroll
            for (int k = 0; k < 4; ++k) pk[k] = acc[k] * (1.f / NH);
            *(floatx4*)((float*)outp + ((size_t)cur * 7 + f) * OC + lane * 4) = pk;
        }
    }
    acc[0] = acc[1] = acc[2] = acc[3] = 0.f;
}

// ---------------- fused streaming aggregation: online softmax + slice-major gather ----------------
// Wave mapping is F-MAJOR: w = f*NGROUPS + g, so consecutive blocks share slice f and
// gather from ONE 5.1MB region (h8[f][*][256]) -> band-wise L2-residency per XCD
// (vs 35.8MB random before). Edge batches are DOUBLE-BUFFERED (named A/B arrays,
// rule #20): batch i+1's 32 loads issue before batch i's compute (T14), 2x MLP.
template <int LAYER>
__global__ __launch_bounds__(256) void attn_aggregate(const int* __restrict__ rowptr,
                                                      const int* __restrict__ csr_src,
                                                      const float* __restrict__ as_,
                                                      const float* __restrict__ ad_,
                                                      const unsigned char* __restrict__ h8,
                                                      const float* __restrict__ bias,
                                                      const float* __restrict__ bng,
                                                      const float* __restrict__ bnb,
                                                      const float* __restrict__ bnm,
                                                      const float* __restrict__ bnv,
                                                      void* __restrict__ outp) {
    const int wv = threadIdx.x >> 6, lane = threadIdx.x & 63;
    const int w = blockIdx.x * 4 + wv;
    const int NWAVES = 7 * NGROUPS;
    if (w >= NWAVES) return;
    const int f = w / NGROUPS;        // feature slice — F-MAJOR: band locality
    const int g = w - f * NGROUPS;    // node group
    const int n0 = g * GRP;
    const unsigned char* hslice = h8 + (size_t)f * NN * 256;   // 5.1MB slice region
    const int loff = lane * 4;
    const int head = f * 8 + (lane >> 3);

    const int e0 = rowptr[n0], e1 = rowptr[n0 + GRP];
    int cur = n0;
    int bound = rowptr[n0 + 1];
    float adv = ad_[(size_t)cur * NH + head];

    float acc[4] = {0.f, 0.f, 0.f, 0.f};
    float m = -1e30f, den = 0.f;

    u32 hvA[EB], hvB[EB];
    float svA[EB], svB[EB];

    auto loadBatch = [&](int eb, u32* hv, float* sv) {
        #pragma unroll
        for (int i = 0; i < EB; ++i) {
            int idx = eb + i; if (idx > e1 - 1) idx = e1 - 1;    // clamp-padded, unconditional
            int s = csr_src[idx];
            hv[i] = *(const u32*)(hslice + (size_t)s * 256 + loff);
            sv[i] = as_[(size_t)s * NH + head];
        }
    };
    auto computeBatch = [&](int eb, u32* hv, float* sv) {
        #pragma unroll
        for (int i = 0; i < EB; ++i) {
            if (eb + i >= e1) break;                // tail padding: skip
            if (eb + i >= bound) {                  // crossed into next node
                flush_node<LAYER>(acc, den, cur, f, lane, bias, bng, bnb, bnm, bnv, outp);
                ++cur;
                bound = rowptr[cur + 1];
                adv = ad_[(size_t)cur * NH + head];
                m = -1e30f; den = 0.f;
            }
            float lr = sv[i] + adv;
            lr = lr > 0.f ? lr : 0.2f * lr;         // leaky_relu
            float wgt;
            if (lr > m) {                           // new max: rescale history
                float scale = __expf(m - lr);
                den = den * scale + 1.f;
                #pragma unroll
                for (int k = 0; k < 4; ++k) acc[k] *= scale;
                m = lr;
                wgt = 1.f;
            } else {
                wgt = __expf(lr - m);
                den += wgt;
            }
            fma_fp8x4(hv[i], wgt, acc);
        }
    };

    loadBatch(e0, hvA, svA);                        // prime buffer A
    for (int e = e0; e < e1; e += 2 * EB) {
        loadBatch(e + EB, hvB, svB);                // issue B's loads early (T14)
        computeBatch(e, hvA, svA);
        loadBatch(e + 2 * EB, hvA, svA);            // issue A's next loads early
        computeBatch(e + EB, hvB, svB);
    }
    flush_node<LAYER>(acc, den, cur, f, lane, bias, bng, bnb, bnm, bnv, outp);
}

// ---------------- mean pool: sorted-batch segmented reduction, minimal atomics ----------------
__global__ __launch_bounds__(256) void pool_kernel(const float* __restrict__ h2part,
                                                   const int* __restrict__ batch,
                                                   float* __restrict__ sums,
                                                   float* __restrict__ cnt) {
    __shared__ float red[4][OC];
    const int g = blockIdx.x >> 3, c = blockIdx.x & 7;
    const int t = threadIdx.x;
    const int ch = t & 31, nl = t >> 5;          // nl in 0..7
    int lo = 0, hi = NN;
    while (lo < hi) { int mid = (lo + hi) >> 1; if (batch[mid] < g) lo = mid + 1; else hi = mid; }
    const int s = lo;
    hi = NN;
    while (lo < hi) { int mid = (lo + hi) >> 1; if (batch[mid] <= g) lo = mid + 1; else hi = mid; }
    const int e = lo;
    const int len = e - s;
    const int n0 = s + (len * c) / 8;
    const int n1 = s + (len * (c + 1)) / 8;
    float acc = 0.f;
    for (int n = n0 + nl; n < n1; n += 8) {
        const float* p = h2part + (size_t)n * 7 * OC + ch;
        float a = 0.f;
        #pragma unroll
        for (int f = 0; f < 7; ++f) a += p[f * OC];
        acc += a;
    }
    acc += __shfl_xor(acc, 32, 64);
    if ((t & 32) == 0) red[t >> 6][ch] = acc;
    __syncthreads();
    if (t < OC) {
        float total = red[0][t] + red[1][t] + red[2][t] + red[3][t];
        atomicAdd(&sums[g * OC + t], total);
    }
    if (t == 0 && c == 0) cnt[g] = (float)len;
}

// final: pooled = sums/cnt; v = BN2(pooled + b2); out = v @ lin_w + lin_b
__global__ __launch_bounds__(128) void final_kernel(const float* __restrict__ sums,
                                                    const float* __restrict__ cnt,
                                                    const float* __restrict__ b2,
                                                    const float* __restrict__ bn2g,
                                                    const float* __restrict__ bn2b,
                                                    const float* __restrict__ bn2m,
                                                    const float* __restrict__ bn2v,
                                                    const float* __restrict__ lin_w,
                                                    const float* __restrict__ lin_b,
                                                    float* __restrict__ out) {
    int t = threadIdx.x;
    if (t >= NG * 2) return;
    int g = t >> 1, c = t & 1;
    float invc = 1.f / fmaxf(cnt[g], 1.f);
    float acc = lin_b[c];
    #pragma unroll
    for (int o = 0; o < OC; ++o) {
        float pooled = sums[g * OC + o] * invc + b2[o];
        float v = (pooled - bn2m[o]) * rsqrtf(bn2v[o] + EPS_BN) * bn2g[o] + bn2b[o];
        acc += v * lin_w[o * 2 + c];
    }
    out[t] = acc;
}

// ---------------- host-side launch ----------------
extern "C" void kernel_launch(void* const* d_in, const int* in_sizes, int n_in,
                              void* d_out, int out_size, void* d_ws, size_t ws_size,
                              hipStream_t stream) {
    const float* x    = (const float*)d_in[0];
    const int*   ei   = (const int*)d_in[1];
    const int*   bat  = (const int*)d_in[2];
    const float* W1   = (const float*)d_in[3];
    const float* at_s1 = (const float*)d_in[4];
    const float* at_d1 = (const float*)d_in[5];
    const float* b1   = (const float*)d_in[6];
    const float* bn1g = (const float*)d_in[7];
    const float* bn1b = (const float*)d_in[8];
    const float* bn1m = (const float*)d_in[9];
    const float* bn1v = (const float*)d_in[10];
    const float* W2   = (const float*)d_in[11];
    const float* at_s2 = (const float*)d_in[12];
    const float* at_d2 = (const float*)d_in[13];
    const float* b2   = (const float*)d_in[14];
    const float* bn2g = (const float*)d_in[15];
    const float* bn2b = (const float*)d_in[16];
    const float* bn2m = (const float*)d_in[17];
    const float* bn2v = (const float*)d_in[18];
    const float* linw = (const float*)d_in[19];
    const float* linb = (const float*)d_in[20];
    float* out = (float*)d_out;

    char* wsp = (char*)d_ws;
    auto alloc = [&](size_t bytes) -> void* {
        void* p = (void*)wsp;
        wsp += (bytes + 255) & ~(size_t)255;
        return p;
    };
    unsigned char*  h8  = (unsigned char*)alloc((size_t)NN * DD1);      // fp8 gemm output (slice-major [7][NN][256])
    __hip_bfloat16* h1p = (__hip_bfloat16*)alloc((size_t)NN * DD1 * 2); // agg1 out (gemm2 A)
    __hip_bfloat16* xb  = (__hip_bfloat16*)alloc((size_t)NN * NF * 2);
    __hip_bfloat16* w1t = (__hip_bfloat16*)alloc((size_t)DD1 * NF * 2);
    __hip_bfloat16* w2t = (__hip_bfloat16*)alloc((size_t)DD1 * DD1 * 2);
    float* asb   = (float*)alloc((size_t)NN * NH * 4);
    float* adb   = (float*)alloc((size_t)NN * NH * 4);
    int*   deg   = (int*)alloc((size_t)NN * 4);
    int*   rowp  = (int*)alloc((size_t)(NN + 1) * 4);
    int*   curs  = (int*)alloc((size_t)NN * 4);
    int*   csr   = (int*)alloc((size_t)ETOT * 4);
    float* h2part = (float*)alloc((size_t)NN * 7 * OC * 4);
    float* sums  = (float*)alloc((size_t)(NG * OC + NG) * 4);
    float* cnt   = sums + NG * OC;

    hipMemsetAsync(deg, 0, (size_t)NN * 4, stream);
    hipMemsetAsync(sums, 0, (size_t)(NG * OC + NG) * 4, stream);

    cast_bf16_kernel<<<(NN * NF + 255) / 256, 256, 0, stream>>>(x, xb, NN * NF);
    transpose_cast_kernel<<<dim3(DD1 / 32, NF / 32), 256, 0, stream>>>(W1, w1t, NF, DD1);
    transpose_cast_kernel<<<dim3(DD1 / 32, DD1 / 32), 256, 0, stream>>>(W2, w2t, DD1, DD1);
    hist_kernel<<<(ETOT + 255) / 256, 256, 0, stream>>>(ei, deg);
    scan_kernel<<<1, 1024, 0, stream>>>(deg, rowp, curs);
    scatter_kernel<<<(ETOT + 255) / 256, 256, 0, stream>>>(ei, curs, csr);

    const int AGG_BLOCKS = (7 * NGROUPS + 3) / 4;
    const int NBY192 = (NN + 191) / 192;                   // 105
    const int GEMM_BLOCKS = NBY192 * (DD1 / 256);          // 735

    // layer 1
    gemm_192<<<GEMM_BLOCKS, 512, 0, stream>>>(xb, w1t, h8, NN, DD1, NF);
    attn_score<<<NN / 4, 256, 0, stream>>>(h8, at_s1, at_d1, asb, adb);
    attn_aggregate<1><<<AGG_BLOCKS, 256, 0, stream>>>(rowp, csr, asb, adb, h8, b1, bn1g, bn1b, bn1m, bn1v, (void*)h1p);

    // layer 2
    gemm_192<<<GEMM_BLOCKS, 512, 0, stream>>>(h1p, w2t, h8, NN, DD1, DD1);
    attn_score<<<NN / 4, 256, 0, stream>>>(h8, at_s2, at_d2, asb, adb);
    attn_aggregate<2><<<AGG_BLOCKS, 256, 0, stream>>>(rowp, csr, asb, adb, h8, b2, bn2g, bn2b, bn2m, bn2v, (void*)h2part);

    pool_kernel<<<NG * 8, 256, 0, stream>>>(h2part, bat, sums, cnt);
    final_kernel<<<1, 128, 0, stream>>>(sums, cnt, b2, bn2g, bn2b, bn2m, bn2v, linw, linb, out);
}

// Round 10
// 605.862 us; speedup vs baseline: 1.0482x; 1.0482x over previous
//
#include <hip/hip_runtime.h>
#include <hip/hip_bf16.h>
#include <hip/hip_fp8.h>
#include <cstdint>
#include <cstddef>

// Problem constants
#define NN     20000     // nodes
#define NF     128       // in features
#define NH     56        // heads
#define OC     32        // out channels per head
#define DD1    1792      // NH*OC
#define NE     100000    // edges (before self loops)
#define ETOT   120000    // edges + self loops
#define NG     50        // graphs
#define EPS_BN 1e-5f
#define GRP    16        // nodes per wave in aggregate
#define EB     16        // edge batch (x2 buffers = 32 loads in flight)

typedef __bf16 bf16x8 __attribute__((ext_vector_type(8)));
typedef float  floatx4 __attribute__((ext_vector_type(4)));
typedef float  floatx2 __attribute__((ext_vector_type(2)));
typedef unsigned int u32;
typedef __attribute__((address_space(1))) u32 gu32;
typedef __attribute__((address_space(3))) u32 lu32;

__device__ __forceinline__ void async_copy16(void* lds, const void* g) {
    __builtin_amdgcn_global_load_lds((gu32*)const_cast<void*>(g), (lu32*)lds, 16, 0, 0);
}

// decode 4 fp8 (e4m3, packed in u32) to 4 floats (HW cvt when available)
__device__ __forceinline__ void dec_fp8x4(u32 u, float* v) {
#if __has_builtin(__builtin_amdgcn_cvt_pk_f32_fp8)
    floatx2 lo = __builtin_amdgcn_cvt_pk_f32_fp8(u, false);
    floatx2 hi = __builtin_amdgcn_cvt_pk_f32_fp8(u, true);
    v[0] = lo[0]; v[1] = lo[1]; v[2] = hi[0]; v[3] = hi[1];
#else
    #pragma unroll
    for (int b = 0; b < 4; ++b) {
        __hip_fp8_e4m3 t;
        t.__x = (u >> (8 * b)) & 0xff;
        v[b] = (float)t;
    }
#endif
}

__device__ __forceinline__ void fma_fp8x4(u32 u, float a, float* acc) {
    float v[4];
    dec_fp8x4(u, v);
    #pragma unroll
    for (int b = 0; b < 4; ++b) acc[b] += a * v[b];
}

// ---------------- elementwise cast fp32 -> bf16 ----------------
__global__ __launch_bounds__(256) void cast_bf16_kernel(const float* __restrict__ in,
                                                        __hip_bfloat16* __restrict__ out, int n) {
    int i = blockIdx.x * 256 + threadIdx.x;
    if (i < n) out[i] = __float2bfloat16(in[i]);
}

// ---------------- tiled transpose + cast: in[R][C] f32 -> out[C][R] bf16 ----------------
__global__ __launch_bounds__(256) void transpose_cast_kernel(const float* __restrict__ in,
                                                             __hip_bfloat16* __restrict__ out,
                                                             int R, int C) {
    __shared__ float tile[32][33];
    int c0 = blockIdx.x * 32, r0 = blockIdx.y * 32;
    int tx = threadIdx.x & 31, ty = threadIdx.x >> 5;   // ty in 0..7
    #pragma unroll
    for (int i = 0; i < 32; i += 8) {
        int r = r0 + ty + i, c = c0 + tx;
        if (r < R && c < C) tile[ty + i][tx] = in[(size_t)r * C + c];
    }
    __syncthreads();
    #pragma unroll
    for (int i = 0; i < 32; i += 8) {
        int c = c0 + ty + i, r = r0 + tx;
        if (c < C && r < R) out[(size_t)c * R + r] = __float2bfloat16(tile[tx][ty + i]);
    }
}

// ---------------- CSR build: histogram / scan / scatter ----------------
__global__ __launch_bounds__(256) void hist_kernel(const int* __restrict__ ei, int* __restrict__ deg) {
    int i = blockIdx.x * 256 + threadIdx.x;
    if (i >= ETOT) return;
    int dst = (i < NE) ? ei[NE + i] : (i - NE);
    atomicAdd(&deg[dst], 1);
}

__global__ __launch_bounds__(1024) void scan_kernel(const int* __restrict__ deg,
                                                    int* __restrict__ rowptr,
                                                    int* __restrict__ cursor) {
    __shared__ int buf[1024];
    int t = threadIdx.x;
    const int CH = (NN + 1023) >> 10;   // 20
    int base = t * CH;
    int s = 0;
    for (int j = 0; j < CH; ++j) { int idx = base + j; if (idx < NN) s += deg[idx]; }
    buf[t] = s;
    __syncthreads();
    for (int off = 1; off < 1024; off <<= 1) {
        int v = (t >= off) ? buf[t - off] : 0;
        __syncthreads();
        buf[t] += v;
        __syncthreads();
    }
    int run = buf[t] - s;   // exclusive
    for (int j = 0; j < CH; ++j) {
        int idx = base + j;
        if (idx < NN) { rowptr[idx] = run; cursor[idx] = run; run += deg[idx]; }
    }
    if (t == 1023) rowptr[NN] = buf[1023];
}

__global__ __launch_bounds__(256) void scatter_kernel(const int* __restrict__ ei,
                                                      int* __restrict__ cursor,
                                                      int* __restrict__ csr_src) {
    int i = blockIdx.x * 256 + threadIdx.x;
    if (i >= ETOT) return;
    int s, d;
    if (i < NE) { s = ei[i]; d = ei[NE + i]; } else { s = i - NE; d = i - NE; }
    int pos = atomicAdd(&cursor[d], 1);
    csr_src[pos] = s;
}

// ---------------- bf16 MFMA GEMM, 192x256 tile, 3-phase (round-5 proven, 8 waves) ----------------
// 8 waves (2Mx4N), per-wave C 96x64, BK=64, 2 LDS bufs, stage t+2 during t, single
// counted vmcnt(7) per K-tile (never drained: T4). ROW-MAJOR C8 output (round-5 form;
// the slice-major experiment destroyed intra-block gather sharing and was reverted).
__global__ __launch_bounds__(512, 2) void gemm_192(const __hip_bfloat16* __restrict__ A,
                                                   const __hip_bfloat16* __restrict__ Bt,
                                                   unsigned char* __restrict__ C8,
                                                   int M, int N, int K) {
    __shared__ __align__(16) unsigned short lds[2][28672];  // per buf: A[192][64] | B[256][64]
    const int tid  = threadIdx.x;
    const int lane = tid & 63, wave = tid >> 6;
    const int wm = wave >> 2, wn = wave & 3;     // 2 x 4 wave grid; per-wave C: 96 x 64

    const int nbx = N >> 8;                      // 7
    const int nby = (M + 191) / 192;             // 105
    const int nwg = nbx * nby;                   // 735
    const int q = nwg >> 3, r = nwg & 7;
    const int xcd = blockIdx.x & 7, bidx = blockIdx.x >> 3;
    const int wg = (xcd < r ? xcd * (q + 1) : r * (q + 1) + (xcd - r) * q) + bidx;
    const int by = wg / nbx, bx = wg - by * nbx;
    const int m0 = by * 192, n0 = bx << 8;

    const int NT = K >> 6;                       // K-tiles of 64: 28 (L2) / 2 (L1)

    const int qq = lane >> 4, rr = lane & 15;

    auto stageA = [&](int kt, int b) {
        #pragma unroll
        for (int i = 0; i < 3; ++i) {
            int slot = i * 512 + tid;
            int row = slot >> 3, pch = slot & 7;
            int lc = pch ^ (row & 7);            // pre-swizzled global source (rule #21)
            int gr = m0 + row; if (gr > M - 1) gr = M - 1;
            async_copy16(&lds[b][slot * 8], A + (size_t)gr * K + (kt << 6) + lc * 8);
        }
    };
    auto stageB = [&](int kt, int b) {
        #pragma unroll
        for (int i = 0; i < 4; ++i) {
            int slot = i * 512 + tid;
            int row = slot >> 3, pch = slot & 7;
            int lc = pch ^ (row & 7);
            async_copy16(&lds[b][12288 + slot * 8], Bt + (size_t)(n0 + row) * K + (kt << 6) + lc * 8);
        }
    };

    floatx4 zero = {0.f, 0.f, 0.f, 0.f};
    floatx4 acc[6][4];
    #pragma unroll
    for (int i = 0; i < 6; ++i)
        #pragma unroll
        for (int jj = 0; jj < 4; ++jj) acc[i][jj] = zero;

    bf16x8 aF[3][2], bA[2][2], bB[2][2];

    auto loadA = [&](int b, int mg) {
        #pragma unroll
        for (int mf = 0; mf < 3; ++mf)
            #pragma unroll
            for (int s = 0; s < 2; ++s) {
                int row = wm * 96 + mg * 48 + mf * 16 + rr;
                int pch = (s * 4 + qq) ^ (row & 7);
                aF[mf][s] = *(const bf16x8*)&lds[b][row * 64 + pch * 8];
            }
    };
    auto loadB = [&](int b, bf16x8 (&bF)[2][2], int ng) {
        #pragma unroll
        for (int nf = 0; nf < 2; ++nf)
            #pragma unroll
            for (int s = 0; s < 2; ++s) {
                int row = wn * 64 + (ng * 2 + nf) * 16 + rr;
                int pch = (s * 4 + qq) ^ (row & 7);
                bF[nf][s] = *(const bf16x8*)&lds[b][12288 + row * 64 + pch * 8];
            }
    };
    auto mfmaQ = [&](int mg, int ng, bf16x8 (&bF)[2][2]) {
        #pragma unroll
        for (int mf = 0; mf < 3; ++mf)
            #pragma unroll
            for (int nf = 0; nf < 2; ++nf)
                #pragma unroll
                for (int s = 0; s < 2; ++s)
                    acc[mg * 3 + mf][ng * 2 + nf] = __builtin_amdgcn_mfma_f32_16x16x32_bf16(
                        aF[mf][s], bF[nf][s], acc[mg * 3 + mf][ng * 2 + nf], 0, 0, 0);
    };

#define SB0 __builtin_amdgcn_sched_barrier(0)
#define GBAR do { SB0; __builtin_amdgcn_s_barrier(); SB0; } while (0)

    stageB(0, 0); stageA(0, 0);
    stageB(1, 1); stageA(1, 1);
    SB0;
    asm volatile("s_waitcnt vmcnt(7)" ::: "memory");
    GBAR;

    for (int t = 0; t < NT; ++t) {
        const int p = t & 1;
        int tp = t + 2; while (tp >= NT) tp -= 2;

        loadA(p, 0); loadB(p, bA, 0);
        GBAR;
        __builtin_amdgcn_s_setprio(1);
        mfmaQ(0, 0, bA);
        __builtin_amdgcn_s_setprio(0);
        GBAR;

        loadB(p, bB, 1);
        stageB(tp, p);
        GBAR;
        __builtin_amdgcn_s_setprio(1);
        mfmaQ(0, 1, bB);
        __builtin_amdgcn_s_setprio(0);
        GBAR;

        loadA(p, 1);
        stageA(tp, p);
        SB0;
        asm volatile("s_waitcnt vmcnt(7)" ::: "memory");
        GBAR;
        __builtin_amdgcn_s_setprio(1);
        mfmaQ(1, 1, bB);
        mfmaQ(1, 0, bA);
        __builtin_amdgcn_s_setprio(0);
        GBAR;
    }
#undef GBAR
#undef SB0

    // epilogue: fp8 quantize + store (row-major)
    #pragma unroll
    for (int mt = 0; mt < 6; ++mt) {
        #pragma unroll
        for (int r4 = 0; r4 < 4; ++r4) {
            int rowc = m0 + wm * 96 + mt * 16 + (lane >> 4) * 4 + r4;
            if (rowc < M) {
                float v0 = acc[mt][0][r4], v1 = acc[mt][1][r4];
                float v2 = acc[mt][2][r4], v3 = acc[mt][3][r4];
                unsigned char q8[4];
#if __has_builtin(__builtin_amdgcn_cvt_pk_fp8_f32)
                u32 p01 = (u32)__builtin_amdgcn_cvt_pk_fp8_f32(v0, v1, 0, false);
                u32 p23 = (u32)__builtin_amdgcn_cvt_pk_fp8_f32(v2, v3, 0, false);
                q8[0] = p01 & 0xff; q8[1] = (p01 >> 8) & 0xff;
                q8[2] = p23 & 0xff; q8[3] = (p23 >> 8) & 0xff;
#else
                { __hip_fp8_e4m3 t0(v0), t1(v1), t2(v2), t3(v3);
                  q8[0] = t0.__x; q8[1] = t1.__x; q8[2] = t2.__x; q8[3] = t3.__x; }
#endif
                #pragma unroll
                for (int nt = 0; nt < 4; ++nt) {
                    int col = n0 + wn * 64 + nt * 16 + (lane & 15);
                    C8[(size_t)rowc * N + col] = q8[nt];
                }
            }
        }
    }
}

// ---------------- attention scores from fp8 h: as/ad[n,h] = sum_o h[n,h,o]*att[h,o] ----------------
__global__ __launch_bounds__(256) void attn_score(const unsigned char* __restrict__ h8,
                                                  const float* __restrict__ att_src,
                                                  const float* __restrict__ att_dst,
                                                  float* __restrict__ as_,
                                                  float* __restrict__ ad_) {
    int wave = threadIdx.x >> 6, lane = threadIdx.x & 63;
    int node = blockIdx.x * 4 + wave;
    if (node >= NN || lane >= NH) return;
    const uint2* hp = (const uint2*)(h8 + (size_t)node * DD1 + lane * OC);   // 32 B / head
    float s = 0.f, d = 0.f;
    #pragma unroll
    for (int jj = 0; jj < 4; ++jj) {
        uint2 u2 = hp[jj];
        u32 us[2] = {u2.x, u2.y};
        #pragma unroll
        for (int w = 0; w < 2; ++w) {
            float v[4];
            dec_fp8x4(us[w], v);
            #pragma unroll
            for (int b = 0; b < 4; ++b) {
                int o = jj * 8 + w * 4 + b;
                s += v[b] * att_src[lane * OC + o];
                d += v[b] * att_dst[lane * OC + o];
            }
        }
    }
    as_[(size_t)node * NH + lane] = s;
    ad_[(size_t)node * NH + lane] = d;
}

// ---------------- node-boundary flush for the fused streaming aggregate ----------------
// acc holds UNNORMALIZED weighted sums; divide by den here.
// LAYER==1: bf16 h1p[cur][slice] = BN1(ELU(acc/den + b1))
// LAYER==2: head-reduce in-wave, write per-slice partial (non-atomic) to h2part[cur][f][32]
template <int LAYER>
__device__ __forceinline__ void flush_node(float* acc, float den, int cur, int f, int lane,
                                           const float* __restrict__ bias,
                                           const float* __restrict__ bng,
                                           const float* __restrict__ bnb,
                                           const float* __restrict__ bnm,
                                           const float* __restrict__ bnv,
                                           void* __restrict__ outp) {
    float inv = 1.f / den;
    #pragma unroll
    for (int k = 0; k < 4; ++k) acc[k] *= inv;

    if constexpr (LAYER == 1) {
        int d0 = f * 256 + lane * 4;
        u32 r01, r23;
        {
            float v0 = acc[0] + bias[d0 + 0];
            float v1 = acc[1] + bias[d0 + 1];
            float v2 = acc[2] + bias[d0 + 2];
            float v3 = acc[3] + bias[d0 + 3];
            v0 = v0 > 0.f ? v0 : expm1f(v0);
            v1 = v1 > 0.f ? v1 : expm1f(v1);
            v2 = v2 > 0.f ? v2 : expm1f(v2);
            v3 = v3 > 0.f ? v3 : expm1f(v3);
            v0 = (v0 - bnm[d0 + 0]) * rsqrtf(bnv[d0 + 0] + EPS_BN) * bng[d0 + 0] + bnb[d0 + 0];
            v1 = (v1 - bnm[d0 + 1]) * rsqrtf(bnv[d0 + 1] + EPS_BN) * bng[d0 + 1] + bnb[d0 + 1];
            v2 = (v2 - bnm[d0 + 2]) * rsqrtf(bnv[d0 + 2] + EPS_BN) * bng[d0 + 2] + bnb[d0 + 2];
            v3 = (v3 - bnm[d0 + 3]) * rsqrtf(bnv[d0 + 3] + EPS_BN) * bng[d0 + 3] + bnb[d0 + 3];
            __hip_bfloat16 b0 = __float2bfloat16(v0), b1 = __float2bfloat16(v1);
            __hip_bfloat16 b2 = __float2bfloat16(v2), b3 = __float2bfloat16(v3);
            r01 = (u32)*(unsigned short*)&b0 | ((u32)*(unsigned short*)&b1 << 16);
            r23 = (u32)*(unsigned short*)&b2 | ((u32)*(unsigned short*)&b3 << 16);
        }
        uint2 pk; pk.x = r01; pk.y = r23;
        *(uint2*)((__hip_bfloat16*)outp + (size_t)cur * DD1 + d0) = pk;
    } else {
        // sum over the 8 heads held by this wave (lane groups stride 8)
        #pragma unroll
        for (int k = 0; k < 4; ++k) {
            acc[k] += __shfl_xor(acc[k], 8, 64);
            acc[k] += __shfl_xor(acc[k], 16, 64);
            acc[k] += __shfl_xor(acc[k], 32, 64);
        }
        if (lane < 8) {
            floatx4 pk;
            #pragma unroll
            for (int k = 0; k < 4; ++k) pk[k] = acc[k] * (1.f / NH);
            *(floatx4*)((float*)outp + ((size_t)cur * 7 + f) * OC + lane * 4) = pk;
        }
    }
    acc[0] = acc[1] = acc[2] = acc[3] = 0.f;
}

// ---------------- fused streaming aggregation with ONLINE SOFTMAX + edge-batch dbuf ----------------
// Round-5 proven structure (node-major w = g*7+f: a block's 4 waves share the same
// src gather list and adjacent 256B slices of the same h8 rows -> L2-line sharing;
// row-major h8). ONE change vs round 5: edge batches are DOUBLE-BUFFERED (named A/B
// arrays, rule #20) so batch i+1's 32 loads issue before batch i's compute (T14) —
// overlaps the csr->{h8,as} dependent-gather latency chain. Costs +32 VGPR.
template <int LAYER>
__global__ __launch_bounds__(256) void attn_aggregate(const int* __restrict__ rowptr,
                                                      const int* __restrict__ csr_src,
                                                      const float* __restrict__ as_,
                                                      const float* __restrict__ ad_,
                                                      const unsigned char* __restrict__ h8,
                                                      const float* __restrict__ bias,
                                                      const float* __restrict__ bng,
                                                      const float* __restrict__ bnb,
                                                      const float* __restrict__ bnm,
                                                      const float* __restrict__ bnv,
                                                      void* __restrict__ outp) {
    const int wv = threadIdx.x >> 6, lane = threadIdx.x & 63;
    const int w = blockIdx.x * 4 + wv;
    const int NWAVES = 7 * (NN / GRP);
    if (w >= NWAVES) return;
    const int f  = w % 7;             // feature slice (256 B of the 1792-B row)
    const int g  = w / 7;             // node group
    const int n0 = g * GRP;
    const int off  = f * 256 + lane * 4;
    const int head = f * 8 + (lane >> 3);

    const int e0 = rowptr[n0], e1 = rowptr[n0 + GRP];
    int cur = n0;
    int bound = rowptr[n0 + 1];
    float adv = ad_[(size_t)cur * NH + head];

    float acc[4] = {0.f, 0.f, 0.f, 0.f};
    float m = -1e30f, den = 0.f;

    u32 hvA[EB], hvB[EB];
    float svA[EB], svB[EB];

    auto loadBatch = [&](int eb, u32* hv, float* sv) {
        #pragma unroll
        for (int i = 0; i < EB; ++i) {
            int idx = eb + i; if (idx > e1 - 1) idx = e1 - 1;    // clamp-padded, unconditional
            int s = csr_src[idx];
            hv[i] = *(const u32*)(h8 + (size_t)s * DD1 + off);
            sv[i] = as_[(size_t)s * NH + head];
        }
    };
    auto computeBatch = [&](int eb, u32* hv, float* sv) {
        #pragma unroll
        for (int i = 0; i < EB; ++i) {
            if (eb + i >= e1) break;                // tail padding: skip
            if (eb + i >= bound) {                  // crossed into next node
                flush_node<LAYER>(acc, den, cur, f, lane, bias, bng, bnb, bnm, bnv, outp);
                ++cur;
                bound = rowptr[cur + 1];
                adv = ad_[(size_t)cur * NH + head];
                m = -1e30f; den = 0.f;
            }
            float lr = sv[i] + adv;
            lr = lr > 0.f ? lr : 0.2f * lr;         // leaky_relu
            float wgt;
            if (lr > m) {                           // new max: rescale history
                float scale = __expf(m - lr);
                den = den * scale + 1.f;
                #pragma unroll
                for (int k = 0; k < 4; ++k) acc[k] *= scale;
                m = lr;
                wgt = 1.f;
            } else {
                wgt = __expf(lr - m);
                den += wgt;
            }
            fma_fp8x4(hv[i], wgt, acc);
        }
    };

    loadBatch(e0, hvA, svA);                        // prime buffer A
    for (int e = e0; e < e1; e += 2 * EB) {
        loadBatch(e + EB, hvB, svB);                // issue B's loads before computing A (T14)
        computeBatch(e, hvA, svA);
        loadBatch(e + 2 * EB, hvA, svA);            // issue A's next loads before computing B
        computeBatch(e + EB, hvB, svB);
    }
    flush_node<LAYER>(acc, den, cur, f, lane, bias, bng, bnb, bnm, bnv, outp);
}

// ---------------- mean pool: sorted-batch segmented reduction, minimal atomics ----------------
__global__ __launch_bounds__(256) void pool_kernel(const float* __restrict__ h2part,
                                                   const int* __restrict__ batch,
                                                   float* __restrict__ sums,
                                                   float* __restrict__ cnt) {
    __shared__ float red[4][OC];
    const int g = blockIdx.x >> 3, c = blockIdx.x & 7;
    const int t = threadIdx.x;
    const int ch = t & 31, nl = t >> 5;          // nl in 0..7
    int lo = 0, hi = NN;
    while (lo < hi) { int mid = (lo + hi) >> 1; if (batch[mid] < g) lo = mid + 1; else hi = mid; }
    const int s = lo;
    hi = NN;
    while (lo < hi) { int mid = (lo + hi) >> 1; if (batch[mid] <= g) lo = mid + 1; else hi = mid; }
    const int e = lo;
    const int len = e - s;
    const int n0 = s + (len * c) / 8;
    const int n1 = s + (len * (c + 1)) / 8;
    float acc = 0.f;
    for (int n = n0 + nl; n < n1; n += 8) {
        const float* p = h2part + (size_t)n * 7 * OC + ch;
        float a = 0.f;
        #pragma unroll
        for (int f = 0; f < 7; ++f) a += p[f * OC];
        acc += a;
    }
    acc += __shfl_xor(acc, 32, 64);
    if ((t & 32) == 0) red[t >> 6][ch] = acc;
    __syncthreads();
    if (t < OC) {
        float total = red[0][t] + red[1][t] + red[2][t] + red[3][t];
        atomicAdd(&sums[g * OC + t], total);
    }
    if (t == 0 && c == 0) cnt[g] = (float)len;
}

// final: pooled = sums/cnt; v = BN2(pooled + b2); out = v @ lin_w + lin_b
__global__ __launch_bounds__(128) void final_kernel(const float* __restrict__ sums,
                                                    const float* __restrict__ cnt,
                                                    const float* __restrict__ b2,
                                                    const float* __restrict__ bn2g,
                                                    const float* __restrict__ bn2b,
                                                    const float* __restrict__ bn2m,
                                                    const float* __restrict__ bn2v,
                                                    const float* __restrict__ lin_w,
                                                    const float* __restrict__ lin_b,
                                                    float* __restrict__ out) {
    int t = threadIdx.x;
    if (t >= NG * 2) return;
    int g = t >> 1, c = t & 1;
    float invc = 1.f / fmaxf(cnt[g], 1.f);
    float acc = lin_b[c];
    #pragma unroll
    for (int o = 0; o < OC; ++o) {
        float pooled = sums[g * OC + o] * invc + b2[o];
        float v = (pooled - bn2m[o]) * rsqrtf(bn2v[o] + EPS_BN) * bn2g[o] + bn2b[o];
        acc += v * lin_w[o * 2 + c];
    }
    out[t] = acc;
}

// ---------------- host-side launch ----------------
extern "C" void kernel_launch(void* const* d_in, const int* in_sizes, int n_in,
                              void* d_out, int out_size, void* d_ws, size_t ws_size,
                              hipStream_t stream) {
    const float* x    = (const float*)d_in[0];
    const int*   ei   = (const int*)d_in[1];
    const int*   bat  = (const int*)d_in[2];
    const float* W1   = (const float*)d_in[3];
    const float* at_s1 = (const float*)d_in[4];
    const float* at_d1 = (const float*)d_in[5];
    const float* b1   = (const float*)d_in[6];
    const float* bn1g = (const float*)d_in[7];
    const float* bn1b = (const float*)d_in[8];
    const float* bn1m = (const float*)d_in[9];
    const float* bn1v = (const float*)d_in[10];
    const float* W2   = (const float*)d_in[11];
    const float* at_s2 = (const float*)d_in[12];
    const float* at_d2 = (const float*)d_in[13];
    const float* b2   = (const float*)d_in[14];
    const float* bn2g = (const float*)d_in[15];
    const float* bn2b = (const float*)d_in[16];
    const float* bn2m = (const float*)d_in[17];
    const float* bn2v = (const float*)d_in[18];
    const float* linw = (const float*)d_in[19];
    const float* linb = (const float*)d_in[20];
    float* out = (float*)d_out;

    char* wsp = (char*)d_ws;
    auto alloc = [&](size_t bytes) -> void* {
        void* p = (void*)wsp;
        wsp += (bytes + 255) & ~(size_t)255;
        return p;
    };
    unsigned char*  h8  = (unsigned char*)alloc((size_t)NN * DD1);      // fp8 gemm output
    __hip_bfloat16* h1p = (__hip_bfloat16*)alloc((size_t)NN * DD1 * 2); // agg1 out (gemm2 A)
    __hip_bfloat16* xb  = (__hip_bfloat16*)alloc((size_t)NN * NF * 2);
    __hip_bfloat16* w1t = (__hip_bfloat16*)alloc((size_t)DD1 * NF * 2);
    __hip_bfloat16* w2t = (__hip_bfloat16*)alloc((size_t)DD1 * DD1 * 2);
    float* asb   = (float*)alloc((size_t)NN * NH * 4);
    float* adb   = (float*)alloc((size_t)NN * NH * 4);
    int*   deg   = (int*)alloc((size_t)NN * 4);
    int*   rowp  = (int*)alloc((size_t)(NN + 1) * 4);
    int*   curs  = (int*)alloc((size_t)NN * 4);
    int*   csr   = (int*)alloc((size_t)ETOT * 4);
    float* h2part = (float*)alloc((size_t)NN * 7 * OC * 4);
    float* sums  = (float*)alloc((size_t)(NG * OC + NG) * 4);
    float* cnt   = sums + NG * OC;

    hipMemsetAsync(deg, 0, (size_t)NN * 4, stream);
    hipMemsetAsync(sums, 0, (size_t)(NG * OC + NG) * 4, stream);

    cast_bf16_kernel<<<(NN * NF + 255) / 256, 256, 0, stream>>>(x, xb, NN * NF);
    transpose_cast_kernel<<<dim3(DD1 / 32, NF / 32), 256, 0, stream>>>(W1, w1t, NF, DD1);
    transpose_cast_kernel<<<dim3(DD1 / 32, DD1 / 32), 256, 0, stream>>>(W2, w2t, DD1, DD1);
    hist_kernel<<<(ETOT + 255) / 256, 256, 0, stream>>>(ei, deg);
    scan_kernel<<<1, 1024, 0, stream>>>(deg, rowp, curs);
    scatter_kernel<<<(ETOT + 255) / 256, 256, 0, stream>>>(ei, curs, csr);

    const int AGG_BLOCKS = (7 * (NN / GRP) + 3) / 4;
    const int NBY192 = (NN + 191) / 192;                   // 105
    const int GEMM_BLOCKS = NBY192 * (DD1 / 256);          // 735

    // layer 1
    gemm_192<<<GEMM_BLOCKS, 512, 0, stream>>>(xb, w1t, h8, NN, DD1, NF);
    attn_score<<<NN / 4, 256, 0, stream>>>(h8, at_s1, at_d1, asb, adb);
    attn_aggregate<1><<<AGG_BLOCKS, 256, 0, stream>>>(rowp, csr, asb, adb, h8, b1, bn1g, bn1b, bn1m, bn1v, (void*)h1p);

    // layer 2
    gemm_192<<<GEMM_BLOCKS, 512, 0, stream>>>(h1p, w2t, h8, NN, DD1, DD1);
    attn_score<<<NN / 4, 256, 0, stream>>>(h8, at_s2, at_d2, asb, adb);
    attn_aggregate<2><<<AGG_BLOCKS, 256, 0, stream>>>(rowp, csr, asb, adb, h8, b2, bn2g, bn2b, bn2m, bn2v, (void*)h2part);

    pool_kernel<<<NG * 8, 256, 0, stream>>>(h2part, bat, sums, cnt);
    final_kernel<<<1, 128, 0, stream>>>(sums, cnt, b2, bn2g, bn2b, bn2m, bn2v, linw, linb, out);
}

// Round 11
// 587.688 us; speedup vs baseline: 1.0806x; 1.0309x over previous
//
#include <hip/hip_runtime.h>
#include <hip/hip_bf16.h>
#include <hip/hip_fp8.h>
#include <cstdint>
#include <cstddef>

// Problem constants
#define NN     20000     // nodes
#define NF     128       // in features
#define NH     56        // heads
#define OC     32        // out channels per head
#define DD1    1792      // NH*OC
#define NE     100000    // edges (before self loops)
#define ETOT   120000    // edges + self loops
#define NG     50        // graphs
#define EPS_BN 1e-5f
#define GRP    16        // nodes per wave in aggregate
#define EB     16        // edge batch (round-5 proven single-buffer)
#define PKROW  2048      // packed h8 row bytes: 7 x (256B h + 32B as) + pad

typedef __bf16 bf16x8 __attribute__((ext_vector_type(8)));
typedef float  floatx4 __attribute__((ext_vector_type(4)));
typedef float  floatx2 __attribute__((ext_vector_type(2)));
typedef unsigned int u32;
typedef __attribute__((address_space(1))) u32 gu32;
typedef __attribute__((address_space(3))) u32 lu32;

__device__ __forceinline__ void async_copy16(void* lds, const void* g) {
    __builtin_amdgcn_global_load_lds((gu32*)const_cast<void*>(g), (lu32*)lds, 16, 0, 0);
}

// decode 4 fp8 (e4m3, packed in u32) to 4 floats (HW cvt when available)
__device__ __forceinline__ void dec_fp8x4(u32 u, float* v) {
#if __has_builtin(__builtin_amdgcn_cvt_pk_f32_fp8)
    floatx2 lo = __builtin_amdgcn_cvt_pk_f32_fp8(u, false);
    floatx2 hi = __builtin_amdgcn_cvt_pk_f32_fp8(u, true);
    v[0] = lo[0]; v[1] = lo[1]; v[2] = hi[0]; v[3] = hi[1];
#else
    #pragma unroll
    for (int b = 0; b < 4; ++b) {
        __hip_fp8_e4m3 t;
        t.__x = (u >> (8 * b)) & 0xff;
        v[b] = (float)t;
    }
#endif
}

__device__ __forceinline__ void fma_fp8x4(u32 u, float a, float* acc) {
    float v[4];
    dec_fp8x4(u, v);
    #pragma unroll
    for (int b = 0; b < 4; ++b) acc[b] += a * v[b];
}

// ---------------- elementwise cast fp32 -> bf16 ----------------
__global__ __launch_bounds__(256) void cast_bf16_kernel(const float* __restrict__ in,
                                                        __hip_bfloat16* __restrict__ out, int n) {
    int i = blockIdx.x * 256 + threadIdx.x;
    if (i < n) out[i] = __float2bfloat16(in[i]);
}

// ---------------- tiled transpose + cast: in[R][C] f32 -> out[C][R] bf16 ----------------
__global__ __launch_bounds__(256) void transpose_cast_kernel(const float* __restrict__ in,
                                                             __hip_bfloat16* __restrict__ out,
                                                             int R, int C) {
    __shared__ float tile[32][33];
    int c0 = blockIdx.x * 32, r0 = blockIdx.y * 32;
    int tx = threadIdx.x & 31, ty = threadIdx.x >> 5;   // ty in 0..7
    #pragma unroll
    for (int i = 0; i < 32; i += 8) {
        int r = r0 + ty + i, c = c0 + tx;
        if (r < R && c < C) tile[ty + i][tx] = in[(size_t)r * C + c];
    }
    __syncthreads();
    #pragma unroll
    for (int i = 0; i < 32; i += 8) {
        int c = c0 + ty + i, r = r0 + tx;
        if (c < C && r < R) out[(size_t)c * R + r] = __float2bfloat16(tile[tx][ty + i]);
    }
}

// ---------------- CSR build: histogram / scan / scatter ----------------
__global__ __launch_bounds__(256) void hist_kernel(const int* __restrict__ ei, int* __restrict__ deg) {
    int i = blockIdx.x * 256 + threadIdx.x;
    if (i >= ETOT) return;
    int dst = (i < NE) ? ei[NE + i] : (i - NE);
    atomicAdd(&deg[dst], 1);
}

__global__ __launch_bounds__(1024) void scan_kernel(const int* __restrict__ deg,
                                                    int* __restrict__ rowptr,
                                                    int* __restrict__ cursor) {
    __shared__ int buf[1024];
    int t = threadIdx.x;
    const int CH = (NN + 1023) >> 10;   // 20
    int base = t * CH;
    int s = 0;
    for (int j = 0; j < CH; ++j) { int idx = base + j; if (idx < NN) s += deg[idx]; }
    buf[t] = s;
    __syncthreads();
    for (int off = 1; off < 1024; off <<= 1) {
        int v = (t >= off) ? buf[t - off] : 0;
        __syncthreads();
        buf[t] += v;
        __syncthreads();
    }
    int run = buf[t] - s;   // exclusive
    for (int j = 0; j < CH; ++j) {
        int idx = base + j;
        if (idx < NN) { rowptr[idx] = run; cursor[idx] = run; run += deg[idx]; }
    }
    if (t == 1023) rowptr[NN] = buf[1023];
}

__global__ __launch_bounds__(256) void scatter_kernel(const int* __restrict__ ei,
                                                      int* __restrict__ cursor,
                                                      int* __restrict__ csr_src) {
    int i = blockIdx.x * 256 + threadIdx.x;
    if (i >= ETOT) return;
    int s, d;
    if (i < NE) { s = ei[i]; d = ei[NE + i]; } else { s = i - NE; d = i - NE; }
    int pos = atomicAdd(&cursor[d], 1);
    csr_src[pos] = s;
}

// ---------------- bf16 MFMA GEMM, 192x256 tile, 3-phase (round-5 proven, 8 waves) ----------------
// 8 waves (2Mx4N), per-wave C 96x64, BK=64, 2 LDS bufs, stage t+2 during t, single
// counted vmcnt(7) per K-tile (never drained: T4). Output into PACKED rows (PKROW=2048B):
// slice f = bx occupies bytes [bx*288, bx*288+256) of each row (as slots at +256 are
// filled by attn_score). Same store pattern as row-major, different stride: zero cost.
__global__ __launch_bounds__(512, 2) void gemm_192(const __hip_bfloat16* __restrict__ A,
                                                   const __hip_bfloat16* __restrict__ Bt,
                                                   unsigned char* __restrict__ C8,
                                                   int M, int N, int K) {
    __shared__ __align__(16) unsigned short lds[2][28672];  // per buf: A[192][64] | B[256][64]
    const int tid  = threadIdx.x;
    const int lane = tid & 63, wave = tid >> 6;
    const int wm = wave >> 2, wn = wave & 3;     // 2 x 4 wave grid; per-wave C: 96 x 64

    const int nbx = N >> 8;                      // 7
    const int nby = (M + 191) / 192;             // 105
    const int nwg = nbx * nby;                   // 735
    const int q = nwg >> 3, r = nwg & 7;
    const int xcd = blockIdx.x & 7, bidx = blockIdx.x >> 3;
    const int wg = (xcd < r ? xcd * (q + 1) : r * (q + 1) + (xcd - r) * q) + bidx;
    const int by = wg / nbx, bx = wg - by * nbx;
    const int m0 = by * 192, n0 = bx << 8;

    const int NT = K >> 6;                       // K-tiles of 64: 28 (L2) / 2 (L1)

    const int qq = lane >> 4, rr = lane & 15;

    auto stageA = [&](int kt, int b) {
        #pragma unroll
        for (int i = 0; i < 3; ++i) {
            int slot = i * 512 + tid;
            int row = slot >> 3, pch = slot & 7;
            int lc = pch ^ (row & 7);            // pre-swizzled global source (rule #21)
            int gr = m0 + row; if (gr > M - 1) gr = M - 1;
            async_copy16(&lds[b][slot * 8], A + (size_t)gr * K + (kt << 6) + lc * 8);
        }
    };
    auto stageB = [&](int kt, int b) {
        #pragma unroll
        for (int i = 0; i < 4; ++i) {
            int slot = i * 512 + tid;
            int row = slot >> 3, pch = slot & 7;
            int lc = pch ^ (row & 7);
            async_copy16(&lds[b][12288 + slot * 8], Bt + (size_t)(n0 + row) * K + (kt << 6) + lc * 8);
        }
    };

    floatx4 zero = {0.f, 0.f, 0.f, 0.f};
    floatx4 acc[6][4];
    #pragma unroll
    for (int i = 0; i < 6; ++i)
        #pragma unroll
        for (int jj = 0; jj < 4; ++jj) acc[i][jj] = zero;

    bf16x8 aF[3][2], bA[2][2], bB[2][2];

    auto loadA = [&](int b, int mg) {
        #pragma unroll
        for (int mf = 0; mf < 3; ++mf)
            #pragma unroll
            for (int s = 0; s < 2; ++s) {
                int row = wm * 96 + mg * 48 + mf * 16 + rr;
                int pch = (s * 4 + qq) ^ (row & 7);
                aF[mf][s] = *(const bf16x8*)&lds[b][row * 64 + pch * 8];
            }
    };
    auto loadB = [&](int b, bf16x8 (&bF)[2][2], int ng) {
        #pragma unroll
        for (int nf = 0; nf < 2; ++nf)
            #pragma unroll
            for (int s = 0; s < 2; ++s) {
                int row = wn * 64 + (ng * 2 + nf) * 16 + rr;
                int pch = (s * 4 + qq) ^ (row & 7);
                bF[nf][s] = *(const bf16x8*)&lds[b][12288 + row * 64 + pch * 8];
            }
    };
    auto mfmaQ = [&](int mg, int ng, bf16x8 (&bF)[2][2]) {
        #pragma unroll
        for (int mf = 0; mf < 3; ++mf)
            #pragma unroll
            for (int nf = 0; nf < 2; ++nf)
                #pragma unroll
                for (int s = 0; s < 2; ++s)
                    acc[mg * 3 + mf][ng * 2 + nf] = __builtin_amdgcn_mfma_f32_16x16x32_bf16(
                        aF[mf][s], bF[nf][s], acc[mg * 3 + mf][ng * 2 + nf], 0, 0, 0);
    };

#define SB0 __builtin_amdgcn_sched_barrier(0)
#define GBAR do { SB0; __builtin_amdgcn_s_barrier(); SB0; } while (0)

    stageB(0, 0); stageA(0, 0);
    stageB(1, 1); stageA(1, 1);
    SB0;
    asm volatile("s_waitcnt vmcnt(7)" ::: "memory");
    GBAR;

    for (int t = 0; t < NT; ++t) {
        const int p = t & 1;
        int tp = t + 2; while (tp >= NT) tp -= 2;

        loadA(p, 0); loadB(p, bA, 0);
        GBAR;
        __builtin_amdgcn_s_setprio(1);
        mfmaQ(0, 0, bA);
        __builtin_amdgcn_s_setprio(0);
        GBAR;

        loadB(p, bB, 1);
        stageB(tp, p);
        GBAR;
        __builtin_amdgcn_s_setprio(1);
        mfmaQ(0, 1, bB);
        __builtin_amdgcn_s_setprio(0);
        GBAR;

        loadA(p, 1);
        stageA(tp, p);
        SB0;
        asm volatile("s_waitcnt vmcnt(7)" ::: "memory");
        GBAR;
        __builtin_amdgcn_s_setprio(1);
        mfmaQ(1, 1, bB);
        mfmaQ(1, 0, bA);
        __builtin_amdgcn_s_setprio(0);
        GBAR;
    }
#undef GBAR
#undef SB0

    // epilogue: fp8 quantize + store into packed row (slice f = bx, inner < 256)
    #pragma unroll
    for (int mt = 0; mt < 6; ++mt) {
        #pragma unroll
        for (int r4 = 0; r4 < 4; ++r4) {
            int rowc = m0 + wm * 96 + mt * 16 + (lane >> 4) * 4 + r4;
            if (rowc < M) {
                float v0 = acc[mt][0][r4], v1 = acc[mt][1][r4];
                float v2 = acc[mt][2][r4], v3 = acc[mt][3][r4];
                unsigned char q8[4];
#if __has_builtin(__builtin_amdgcn_cvt_pk_fp8_f32)
                u32 p01 = (u32)__builtin_amdgcn_cvt_pk_fp8_f32(v0, v1, 0, false);
                u32 p23 = (u32)__builtin_amdgcn_cvt_pk_fp8_f32(v2, v3, 0, false);
                q8[0] = p01 & 0xff; q8[1] = (p01 >> 8) & 0xff;
                q8[2] = p23 & 0xff; q8[3] = (p23 >> 8) & 0xff;
#else
                { __hip_fp8_e4m3 t0(v0), t1(v1), t2(v2), t3(v3);
                  q8[0] = t0.__x; q8[1] = t1.__x; q8[2] = t2.__x; q8[3] = t3.__x; }
#endif
                #pragma unroll
                for (int nt = 0; nt < 4; ++nt) {
                    int inner = wn * 64 + nt * 16 + (lane & 15);       // < 256
                    C8[(size_t)rowc * PKROW + bx * 288 + inner] = q8[nt];
                }
            }
        }
    }
}

// ---------------- attention scores from packed h8; write as INTO the packed row ----------------
// head h: slice f = h>>3, sub j = h&7; h-data at [n*PKROW + f*288 + j*32], as slot at
// [n*PKROW + f*288 + 256 + j*4]. ad stays in its own dst-indexed buffer (uniform reads).
__global__ __launch_bounds__(256) void attn_score(unsigned char* __restrict__ h8,
                                                  const float* __restrict__ att_src,
                                                  const float* __restrict__ att_dst,
                                                  float* __restrict__ ad_) {
    int wave = threadIdx.x >> 6, lane = threadIdx.x & 63;
    int node = blockIdx.x * 4 + wave;
    if (node >= NN || lane >= NH) return;
    const int f = lane >> 3, j = lane & 7;
    const uint2* hp = (const uint2*)(h8 + (size_t)node * PKROW + f * 288 + j * 32);
    float s = 0.f, d = 0.f;
    #pragma unroll
    for (int jj = 0; jj < 4; ++jj) {
        uint2 u2 = hp[jj];
        u32 us[2] = {u2.x, u2.y};
        #pragma unroll
        for (int w = 0; w < 2; ++w) {
            float v[4];
            dec_fp8x4(us[w], v);
            #pragma unroll
            for (int b = 0; b < 4; ++b) {
                int o = jj * 8 + w * 4 + b;
                s += v[b] * att_src[lane * OC + o];
                d += v[b] * att_dst[lane * OC + o];
            }
        }
    }
    *(float*)(h8 + (size_t)node * PKROW + f * 288 + 256 + j * 4) = s;   // packed as
    ad_[(size_t)node * NH + lane] = d;
}

// ---------------- node-boundary flush for the fused streaming aggregate ----------------
// acc holds UNNORMALIZED weighted sums; divide by den here.
// LAYER==1: bf16 h1p[cur][slice] = BN1(ELU(acc/den + b1))
// LAYER==2: head-reduce in-wave, write per-slice partial (non-atomic) to h2part[cur][f][32]
template <int LAYER>
__device__ __forceinline__ void flush_node(float* acc, float den, int cur, int f, int lane,
                                           const float* __restrict__ bias,
                                           const float* __restrict__ bng,
                                           const float* __restrict__ bnb,
                                           const float* __restrict__ bnm,
                                           const float* __restrict__ bnv,
                                           void* __restrict__ outp) {
    float inv = 1.f / den;
    #pragma unroll
    for (int k = 0; k < 4; ++k) acc[k] *= inv;

    if constexpr (LAYER == 1) {
        int d0 = f * 256 + lane * 4;
        u32 r01, r23;
        {
            float v0 = acc[0] + bias[d0 + 0];
            float v1 = acc[1] + bias[d0 + 1];
            float v2 = acc[2] + bias[d0 + 2];
            float v3 = acc[3] + bias[d0 + 3];
            v0 = v0 > 0.f ? v0 : expm1f(v0);
            v1 = v1 > 0.f ? v1 : expm1f(v1);
            v2 = v2 > 0.f ? v2 : expm1f(v2);
            v3 = v3 > 0.f ? v3 : expm1f(v3);
            v0 = (v0 - bnm[d0 + 0]) * rsqrtf(bnv[d0 + 0] + EPS_BN) * bng[d0 + 0] + bnb[d0 + 0];
            v1 = (v1 - bnm[d0 + 1]) * rsqrtf(bnv[d0 + 1] + EPS_BN) * bng[d0 + 1] + bnb[d0 + 1];
            v2 = (v2 - bnm[d0 + 2]) * rsqrtf(bnv[d0 + 2] + EPS_BN) * bng[d0 + 2] + bnb[d0 + 2];
            v3 = (v3 - bnm[d0 + 3]) * rsqrtf(bnv[d0 + 3] + EPS_BN) * bng[d0 + 3] + bnb[d0 + 3];
            __hip_bfloat16 b0 = __float2bfloat16(v0), b1 = __float2bfloat16(v1);
            __hip_bfloat16 b2 = __float2bfloat16(v2), b3 = __float2bfloat16(v3);
            r01 = (u32)*(unsigned short*)&b0 | ((u32)*(unsigned short*)&b1 << 16);
            r23 = (u32)*(unsigned short*)&b2 | ((u32)*(unsigned short*)&b3 << 16);
        }
        uint2 pk; pk.x = r01; pk.y = r23;
        *(uint2*)((__hip_bfloat16*)outp + (size_t)cur * DD1 + d0) = pk;
    } else {
        // sum over the 8 heads held by this wave (lane groups stride 8)
        #pragma unroll
        for (int k = 0; k < 4; ++k) {
            acc[k] += __shfl_xor(acc[k], 8, 64);
            acc[k] += __shfl_xor(acc[k], 16, 64);
            acc[k] += __shfl_xor(acc[k], 32, 64);
        }
        if (lane < 8) {
            floatx4 pk;
            #pragma unroll
            for (int k = 0; k < 4; ++k) pk[k] = acc[k] * (1.f / NH);
            *(floatx4*)((float*)outp + ((size_t)cur * 7 + f) * OC + lane * 4) = pk;
        }
    }
    acc[0] = acc[1] = acc[2] = acc[3] = 0.f;
}

// ---------------- fused streaming aggregation with ONLINE SOFTMAX (round-5 loop) ----------------
// Node-major wave mapping (w = g*7+f: block's 4 waves share the gather list, adjacent
// 288B chunks of the same packed rows). Per edge ONE contiguous region serves both h
// and as (packed row): 16 fully-used 128B lines/row vs 21 partially-used before.
// m204 bijective swizzle on the AGG grid keeps the 2 blocks of a group on one XCD
// so their shared lines hit the same L2.
template <int LAYER>
__global__ __launch_bounds__(256) void attn_aggregate(const int* __restrict__ rowptr,
                                                      const int* __restrict__ csr_src,
                                                      const float* __restrict__ ad_,
                                                      const unsigned char* __restrict__ h8,
                                                      const float* __restrict__ bias,
                                                      const float* __restrict__ bng,
                                                      const float* __restrict__ bnb,
                                                      const float* __restrict__ bnm,
                                                      const float* __restrict__ bnv,
                                                      void* __restrict__ outp,
                                                      int nblocks) {
    // bijective XCD swizzle (m204): consecutive logical blocks -> same XCD chunk
    const int q = nblocks >> 3, r = nblocks & 7;
    const int xcd = blockIdx.x & 7, bidx = blockIdx.x >> 3;
    const int bid = (xcd < r ? xcd * (q + 1) : r * (q + 1) + (xcd - r) * q) + bidx;

    const int wv = threadIdx.x >> 6, lane = threadIdx.x & 63;
    const int w = bid * 4 + wv;
    const int NWAVES = 7 * (NN / GRP);
    if (w >= NWAVES) return;
    const int f  = w % 7;             // feature slice (288-B chunk of the packed row)
    const int g  = w / 7;             // node group
    const int n0 = g * GRP;
    const int hoff = f * 288 + lane * 4;               // h bytes within packed row
    const int soff = f * 288 + 256 + (lane >> 3) * 4;  // as slot within packed row
    const int head = f * 8 + (lane >> 3);

    const int e0 = rowptr[n0], e1 = rowptr[n0 + GRP];
    int cur = n0;
    int bound = rowptr[n0 + 1];
    float adv = ad_[(size_t)cur * NH + head];

    float acc[4] = {0.f, 0.f, 0.f, 0.f};
    float m = -1e30f, den = 0.f;

    for (int e = e0; e < e1; e += EB) {
        u32   hv[EB];
        float sv[EB];
        // unconditional clamp-padded loads: EB independent chains in flight
        #pragma unroll
        for (int i = 0; i < EB; ++i) {
            int idx = (e + i < e1) ? e + i : e1 - 1;
            int s = csr_src[idx];
            const unsigned char* row = h8 + (size_t)s * PKROW;
            hv[i] = *(const u32*)(row + hoff);
            sv[i] = *(const float*)(row + soff);
        }
        #pragma unroll
        for (int i = 0; i < EB; ++i) {
            if (e + i >= e1) break;                 // tail padding: skip
            if (e + i >= bound) {                   // crossed into next node
                flush_node<LAYER>(acc, den, cur, f, lane, bias, bng, bnb, bnm, bnv, outp);
                ++cur;
                bound = rowptr[cur + 1];
                adv = ad_[(size_t)cur * NH + head];
                m = -1e30f; den = 0.f;
            }
            float lr = sv[i] + adv;
            lr = lr > 0.f ? lr : 0.2f * lr;         // leaky_relu
            float wgt;
            if (lr > m) {                           // new max: rescale history
                float scale = __expf(m - lr);
                den = den * scale + 1.f;
                #pragma unroll
                for (int k = 0; k < 4; ++k) acc[k] *= scale;
                m = lr;
                wgt = 1.f;
            } else {
                wgt = __expf(lr - m);
                den += wgt;
            }
            fma_fp8x4(hv[i], wgt, acc);
        }
    }
    flush_node<LAYER>(acc, den, cur, f, lane, bias, bng, bnb, bnm, bnv, outp);
}

// ---------------- mean pool: sorted-batch segmented reduction, minimal atomics ----------------
__global__ __launch_bounds__(256) void pool_kernel(const float* __restrict__ h2part,
                                                   const int* __restrict__ batch,
                                                   float* __restrict__ sums,
                                                   float* __restrict__ cnt) {
    __shared__ float red[4][OC];
    const int g = blockIdx.x >> 3, c = blockIdx.x & 7;
    const int t = threadIdx.x;
    const int ch = t & 31, nl = t >> 5;          // nl in 0..7
    int lo = 0, hi = NN;
    while (lo < hi) { int mid = (lo + hi) >> 1; if (batch[mid] < g) lo = mid + 1; else hi = mid; }
    const int s = lo;
    hi = NN;
    while (lo < hi) { int mid = (lo + hi) >> 1; if (batch[mid] <= g) lo = mid + 1; else hi = mid; }
    const int e = lo;
    const int len = e - s;
    const int n0 = s + (len * c) / 8;
    const int n1 = s + (len * (c + 1)) / 8;
    float acc = 0.f;
    for (int n = n0 + nl; n < n1; n += 8) {
        const float* p = h2part + (size_t)n * 7 * OC + ch;
        float a = 0.f;
        #pragma unroll
        for (int f = 0; f < 7; ++f) a += p[f * OC];
        acc += a;
    }
    acc += __shfl_xor(acc, 32, 64);
    if ((t & 32) == 0) red[t >> 6][ch] = acc;
    __syncthreads();
    if (t < OC) {
        float total = red[0][t] + red[1][t] + red[2][t] + red[3][t];
        atomicAdd(&sums[g * OC + t], total);
    }
    if (t == 0 && c == 0) cnt[g] = (float)len;
}

// final: pooled = sums/cnt; v = BN2(pooled + b2); out = v @ lin_w + lin_b
__global__ __launch_bounds__(128) void final_kernel(const float* __restrict__ sums,
                                                    const float* __restrict__ cnt,
                                                    const float* __restrict__ b2,
                                                    const float* __restrict__ bn2g,
                                                    const float* __restrict__ bn2b,
                                                    const float* __restrict__ bn2m,
                                                    const float* __restrict__ bn2v,
                                                    const float* __restrict__ lin_w,
                                                    const float* __restrict__ lin_b,
                                                    float* __restrict__ out) {
    int t = threadIdx.x;
    if (t >= NG * 2) return;
    int g = t >> 1, c = t & 1;
    float invc = 1.f / fmaxf(cnt[g], 1.f);
    float acc = lin_b[c];
    #pragma unroll
    for (int o = 0; o < OC; ++o) {
        float pooled = sums[g * OC + o] * invc + b2[o];
        float v = (pooled - bn2m[o]) * rsqrtf(bn2v[o] + EPS_BN) * bn2g[o] + bn2b[o];
        acc += v * lin_w[o * 2 + c];
    }
    out[t] = acc;
}

// ---------------- host-side launch ----------------
extern "C" void kernel_launch(void* const* d_in, const int* in_sizes, int n_in,
                              void* d_out, int out_size, void* d_ws, size_t ws_size,
                              hipStream_t stream) {
    const float* x    = (const float*)d_in[0];
    const int*   ei   = (const int*)d_in[1];
    const int*   bat  = (const int*)d_in[2];
    const float* W1   = (const float*)d_in[3];
    const float* at_s1 = (const float*)d_in[4];
    const float* at_d1 = (const float*)d_in[5];
    const float* b1   = (const float*)d_in[6];
    const float* bn1g = (const float*)d_in[7];
    const float* bn1b = (const float*)d_in[8];
    const float* bn1m = (const float*)d_in[9];
    const float* bn1v = (const float*)d_in[10];
    const float* W2   = (const float*)d_in[11];
    const float* at_s2 = (const float*)d_in[12];
    const float* at_d2 = (const float*)d_in[13];
    const float* b2   = (const float*)d_in[14];
    const float* bn2g = (const float*)d_in[15];
    const float* bn2b = (const float*)d_in[16];
    const float* bn2m = (const float*)d_in[17];
    const float* bn2v = (const float*)d_in[18];
    const float* linw = (const float*)d_in[19];
    const float* linb = (const float*)d_in[20];
    float* out = (float*)d_out;

    char* wsp = (char*)d_ws;
    auto alloc = [&](size_t bytes) -> void* {
        void* p = (void*)wsp;
        wsp += (bytes + 255) & ~(size_t)255;
        return p;
    };
    unsigned char*  h8  = (unsigned char*)alloc((size_t)NN * PKROW);    // packed fp8 rows + as slots
    __hip_bfloat16* h1p = (__hip_bfloat16*)alloc((size_t)NN * DD1 * 2); // agg1 out (gemm2 A)
    __hip_bfloat16* xb  = (__hip_bfloat16*)alloc((size_t)NN * NF * 2);
    __hip_bfloat16* w1t = (__hip_bfloat16*)alloc((size_t)DD1 * NF * 2);
    __hip_bfloat16* w2t = (__hip_bfloat16*)alloc((size_t)DD1 * DD1 * 2);
    float* adb   = (float*)alloc((size_t)NN * NH * 4);
    int*   deg   = (int*)alloc((size_t)NN * 4);
    int*   rowp  = (int*)alloc((size_t)(NN + 1) * 4);
    int*   curs  = (int*)alloc((size_t)NN * 4);
    int*   csr   = (int*)alloc((size_t)ETOT * 4);
    float* h2part = (float*)alloc((size_t)NN * 7 * OC * 4);
    float* sums  = (float*)alloc((size_t)(NG * OC + NG) * 4);
    float* cnt   = sums + NG * OC;

    hipMemsetAsync(deg, 0, (size_t)NN * 4, stream);
    hipMemsetAsync(sums, 0, (size_t)(NG * OC + NG) * 4, stream);

    cast_bf16_kernel<<<(NN * NF + 255) / 256, 256, 0, stream>>>(x, xb, NN * NF);
    transpose_cast_kernel<<<dim3(DD1 / 32, NF / 32), 256, 0, stream>>>(W1, w1t, NF, DD1);
    transpose_cast_kernel<<<dim3(DD1 / 32, DD1 / 32), 256, 0, stream>>>(W2, w2t, DD1, DD1);
    hist_kernel<<<(ETOT + 255) / 256, 256, 0, stream>>>(ei, deg);
    scan_kernel<<<1, 1024, 0, stream>>>(deg, rowp, curs);
    scatter_kernel<<<(ETOT + 255) / 256, 256, 0, stream>>>(ei, curs, csr);

    const int AGG_BLOCKS = (7 * (NN / GRP) + 3) / 4;       // 2188
    const int NBY192 = (NN + 191) / 192;                   // 105
    const int GEMM_BLOCKS = NBY192 * (DD1 / 256);          // 735

    // layer 1
    gemm_192<<<GEMM_BLOCKS, 512, 0, stream>>>(xb, w1t, h8, NN, DD1, NF);
    attn_score<<<NN / 4, 256, 0, stream>>>(h8, at_s1, at_d1, adb);
    attn_aggregate<1><<<AGG_BLOCKS, 256, 0, stream>>>(rowp, csr, adb, h8, b1, bn1g, bn1b, bn1m, bn1v, (void*)h1p, AGG_BLOCKS);

    // layer 2
    gemm_192<<<GEMM_BLOCKS, 512, 0, stream>>>(h1p, w2t, h8, NN, DD1, DD1);
    attn_score<<<NN / 4, 256, 0, stream>>>(h8, at_s2, at_d2, adb);
    attn_aggregate<2><<<AGG_BLOCKS, 256, 0, stream>>>(rowp, csr, adb, h8, b2, bn2g, bn2b, bn2m, bn2v, (void*)h2part, AGG_BLOCKS);

    pool_kernel<<<NG * 8, 256, 0, stream>>>(h2part, bat, sums, cnt);
    final_kernel<<<1, 128, 0, stream>>>(sums, cnt, b2, bn2g, bn2b, bn2m, bn2v, linw, linb, out);
}

// Round 12
// 552.140 us; speedup vs baseline: 1.1502x; 1.0644x over previous
//
#include <hip/hip_runtime.h>
#include <hip/hip_bf16.h>
#include <hip/hip_fp8.h>
#include <cstdint>
#include <cstddef>

// Problem constants
#define NN     20000     // nodes
#define NF     128       // in features
#define NH     56        // heads
#define OC     32        // out channels per head
#define DD1    1792      // NH*OC
#define NE     100000    // edges (before self loops)
#define ETOT   120000    // edges + self loops
#define NG     50        // graphs
#define EPS_BN 1e-5f
#define GRP    16        // nodes per wave in aggregate
#define EB     16        // edge batch (round-5 proven single-buffer)

typedef __bf16 bf16x8 __attribute__((ext_vector_type(8)));
typedef float  floatx4 __attribute__((ext_vector_type(4)));
typedef float  floatx2 __attribute__((ext_vector_type(2)));
typedef unsigned int u32;
typedef __attribute__((address_space(1))) u32 gu32;
typedef __attribute__((address_space(3))) u32 lu32;

__device__ __forceinline__ void async_copy16(void* lds, const void* g) {
    __builtin_amdgcn_global_load_lds((gu32*)const_cast<void*>(g), (lu32*)lds, 16, 0, 0);
}

// decode 4 fp8 (e4m3, packed in u32) to 4 floats (HW cvt when available)
__device__ __forceinline__ void dec_fp8x4(u32 u, float* v) {
#if __has_builtin(__builtin_amdgcn_cvt_pk_f32_fp8)
    floatx2 lo = __builtin_amdgcn_cvt_pk_f32_fp8(u, false);
    floatx2 hi = __builtin_amdgcn_cvt_pk_f32_fp8(u, true);
    v[0] = lo[0]; v[1] = lo[1]; v[2] = hi[0]; v[3] = hi[1];
#else
    #pragma unroll
    for (int b = 0; b < 4; ++b) {
        __hip_fp8_e4m3 t;
        t.__x = (u >> (8 * b)) & 0xff;
        v[b] = (float)t;
    }
#endif
}

__device__ __forceinline__ void fma_fp8x4(u32 u, float a, float* acc) {
    float v[4];
    dec_fp8x4(u, v);
    #pragma unroll
    for (int b = 0; b < 4; ++b) acc[b] += a * v[b];
}

// ---------------- elementwise cast fp32 -> bf16 ----------------
__global__ __launch_bounds__(256) void cast_bf16_kernel(const float* __restrict__ in,
                                                        __hip_bfloat16* __restrict__ out, int n) {
    int i = blockIdx.x * 256 + threadIdx.x;
    if (i < n) out[i] = __float2bfloat16(in[i]);
}

// ---------------- tiled transpose + cast: in[R][C] f32 -> out[C][R] bf16 ----------------
__global__ __launch_bounds__(256) void transpose_cast_kernel(const float* __restrict__ in,
                                                             __hip_bfloat16* __restrict__ out,
                                                             int R, int C) {
    __shared__ float tile[32][33];
    int c0 = blockIdx.x * 32, r0 = blockIdx.y * 32;
    int tx = threadIdx.x & 31, ty = threadIdx.x >> 5;   // ty in 0..7
    #pragma unroll
    for (int i = 0; i < 32; i += 8) {
        int r = r0 + ty + i, c = c0 + tx;
        if (r < R && c < C) tile[ty + i][tx] = in[(size_t)r * C + c];
    }
    __syncthreads();
    #pragma unroll
    for (int i = 0; i < 32; i += 8) {
        int c = c0 + ty + i, r = r0 + tx;
        if (c < C && r < R) out[(size_t)c * R + r] = __float2bfloat16(tile[tx][ty + i]);
    }
}

// ---------------- CSR build: histogram / scan / scatter ----------------
__global__ __launch_bounds__(256) void hist_kernel(const int* __restrict__ ei, int* __restrict__ deg) {
    int i = blockIdx.x * 256 + threadIdx.x;
    if (i >= ETOT) return;
    int dst = (i < NE) ? ei[NE + i] : (i - NE);
    atomicAdd(&deg[dst], 1);
}

__global__ __launch_bounds__(1024) void scan_kernel(const int* __restrict__ deg,
                                                    int* __restrict__ rowptr,
                                                    int* __restrict__ cursor) {
    __shared__ int buf[1024];
    int t = threadIdx.x;
    const int CH = (NN + 1023) >> 10;   // 20
    int base = t * CH;
    int s = 0;
    for (int j = 0; j < CH; ++j) { int idx = base + j; if (idx < NN) s += deg[idx]; }
    buf[t] = s;
    __syncthreads();
    for (int off = 1; off < 1024; off <<= 1) {
        int v = (t >= off) ? buf[t - off] : 0;
        __syncthreads();
        buf[t] += v;
        __syncthreads();
    }
    int run = buf[t] - s;   // exclusive
    for (int j = 0; j < CH; ++j) {
        int idx = base + j;
        if (idx < NN) { rowptr[idx] = run; cursor[idx] = run; run += deg[idx]; }
    }
    if (t == 1023) rowptr[NN] = buf[1023];
}

__global__ __launch_bounds__(256) void scatter_kernel(const int* __restrict__ ei,
                                                      int* __restrict__ cursor,
                                                      int* __restrict__ csr_src) {
    int i = blockIdx.x * 256 + threadIdx.x;
    if (i >= ETOT) return;
    int s, d;
    if (i < NE) { s = ei[i]; d = ei[NE + i]; } else { s = i - NE; d = i - NE; }
    int pos = atomicAdd(&cursor[d], 1);
    csr_src[pos] = s;
}

// ---------------- bf16 MFMA GEMM, 192x256 tile, 3-phase (round-5 proven, 8 waves) ----------------
// 8 waves (2Mx4N), per-wave C 96x64, BK=64, 2 LDS bufs, stage t+2 during t, single
// counted vmcnt(7) per K-tile (never drained: T4). ROW-MAJOR C8 output.
// NEW: attn_score FUSED into the epilogue — each wave's 64-col band covers exactly 2
// complete heads (h = bx*8 + wn*2 + {0,1}); as/ad[row][head] = 2 FMAs per fragment +
// 16-lane shfl_xor butterfly (masks 1/2/4/8 stay within the quarter that owns the row).
// Saves 2 kernel launches + 2 full 35.8MB h8 re-reads; as/ad now from f32 acc (closer
// to reference than the old fp8-requantized path).
__global__ __launch_bounds__(512, 2) void gemm_192(const __hip_bfloat16* __restrict__ A,
                                                   const __hip_bfloat16* __restrict__ Bt,
                                                   unsigned char* __restrict__ C8,
                                                   const float* __restrict__ att_src,
                                                   const float* __restrict__ att_dst,
                                                   float* __restrict__ as_,
                                                   float* __restrict__ ad_,
                                                   int M, int N, int K) {
    __shared__ __align__(16) unsigned short lds[2][28672];  // per buf: A[192][64] | B[256][64]
    const int tid  = threadIdx.x;
    const int lane = tid & 63, wave = tid >> 6;
    const int wm = wave >> 2, wn = wave & 3;     // 2 x 4 wave grid; per-wave C: 96 x 64

    const int nbx = N >> 8;                      // 7
    const int nby = (M + 191) / 192;             // 105
    const int nwg = nbx * nby;                   // 735
    const int q = nwg >> 3, r = nwg & 7;
    const int xcd = blockIdx.x & 7, bidx = blockIdx.x >> 3;
    const int wg = (xcd < r ? xcd * (q + 1) : r * (q + 1) + (xcd - r) * q) + bidx;
    const int by = wg / nbx, bx = wg - by * nbx;
    const int m0 = by * 192, n0 = bx << 8;

    const int NT = K >> 6;                       // K-tiles of 64: 28 (L2) / 2 (L1)

    const int qq = lane >> 4, rr = lane & 15;

    auto stageA = [&](int kt, int b) {
        #pragma unroll
        for (int i = 0; i < 3; ++i) {
            int slot = i * 512 + tid;
            int row = slot >> 3, pch = slot & 7;
            int lc = pch ^ (row & 7);            // pre-swizzled global source (rule #21)
            int gr = m0 + row; if (gr > M - 1) gr = M - 1;
            async_copy16(&lds[b][slot * 8], A + (size_t)gr * K + (kt << 6) + lc * 8);
        }
    };
    auto stageB = [&](int kt, int b) {
        #pragma unroll
        for (int i = 0; i < 4; ++i) {
            int slot = i * 512 + tid;
            int row = slot >> 3, pch = slot & 7;
            int lc = pch ^ (row & 7);
            async_copy16(&lds[b][12288 + slot * 8], Bt + (size_t)(n0 + row) * K + (kt << 6) + lc * 8);
        }
    };

    floatx4 zero = {0.f, 0.f, 0.f, 0.f};
    floatx4 acc[6][4];
    #pragma unroll
    for (int i = 0; i < 6; ++i)
        #pragma unroll
        for (int jj = 0; jj < 4; ++jj) acc[i][jj] = zero;

    bf16x8 aF[3][2], bA[2][2], bB[2][2];

    auto loadA = [&](int b, int mg) {
        #pragma unroll
        for (int mf = 0; mf < 3; ++mf)
            #pragma unroll
            for (int s = 0; s < 2; ++s) {
                int row = wm * 96 + mg * 48 + mf * 16 + rr;
                int pch = (s * 4 + qq) ^ (row & 7);
                aF[mf][s] = *(const bf16x8*)&lds[b][row * 64 + pch * 8];
            }
    };
    auto loadB = [&](int b, bf16x8 (&bF)[2][2], int ng) {
        #pragma unroll
        for (int nf = 0; nf < 2; ++nf)
            #pragma unroll
            for (int s = 0; s < 2; ++s) {
                int row = wn * 64 + (ng * 2 + nf) * 16 + rr;
                int pch = (s * 4 + qq) ^ (row & 7);
                bF[nf][s] = *(const bf16x8*)&lds[b][12288 + row * 64 + pch * 8];
            }
    };
    auto mfmaQ = [&](int mg, int ng, bf16x8 (&bF)[2][2]) {
        #pragma unroll
        for (int mf = 0; mf < 3; ++mf)
            #pragma unroll
            for (int nf = 0; nf < 2; ++nf)
                #pragma unroll
                for (int s = 0; s < 2; ++s)
                    acc[mg * 3 + mf][ng * 2 + nf] = __builtin_amdgcn_mfma_f32_16x16x32_bf16(
                        aF[mf][s], bF[nf][s], acc[mg * 3 + mf][ng * 2 + nf], 0, 0, 0);
    };

#define SB0 __builtin_amdgcn_sched_barrier(0)
#define GBAR do { SB0; __builtin_amdgcn_s_barrier(); SB0; } while (0)

    stageB(0, 0); stageA(0, 0);
    stageB(1, 1); stageA(1, 1);
    SB0;
    asm volatile("s_waitcnt vmcnt(7)" ::: "memory");
    GBAR;

    for (int t = 0; t < NT; ++t) {
        const int p = t & 1;
        int tp = t + 2; while (tp >= NT) tp -= 2;

        loadA(p, 0); loadB(p, bA, 0);
        GBAR;
        __builtin_amdgcn_s_setprio(1);
        mfmaQ(0, 0, bA);
        __builtin_amdgcn_s_setprio(0);
        GBAR;

        loadB(p, bB, 1);
        stageB(tp, p);
        GBAR;
        __builtin_amdgcn_s_setprio(1);
        mfmaQ(0, 1, bB);
        __builtin_amdgcn_s_setprio(0);
        GBAR;

        loadA(p, 1);
        stageA(tp, p);
        SB0;
        asm volatile("s_waitcnt vmcnt(7)" ::: "memory");
        GBAR;
        __builtin_amdgcn_s_setprio(1);
        mfmaQ(1, 1, bB);
        mfmaQ(1, 0, bA);
        __builtin_amdgcn_s_setprio(0);
        GBAR;
    }
#undef GBAR
#undef SB0

    // epilogue part 1: fp8 quantize + store (row-major, round-5 form)
    #pragma unroll
    for (int mt = 0; mt < 6; ++mt) {
        #pragma unroll
        for (int r4 = 0; r4 < 4; ++r4) {
            int rowc = m0 + wm * 96 + mt * 16 + (lane >> 4) * 4 + r4;
            if (rowc < M) {
                float v0 = acc[mt][0][r4], v1 = acc[mt][1][r4];
                float v2 = acc[mt][2][r4], v3 = acc[mt][3][r4];
                unsigned char q8[4];
#if __has_builtin(__builtin_amdgcn_cvt_pk_fp8_f32)
                u32 p01 = (u32)__builtin_amdgcn_cvt_pk_fp8_f32(v0, v1, 0, false);
                u32 p23 = (u32)__builtin_amdgcn_cvt_pk_fp8_f32(v2, v3, 0, false);
                q8[0] = p01 & 0xff; q8[1] = (p01 >> 8) & 0xff;
                q8[2] = p23 & 0xff; q8[3] = (p23 >> 8) & 0xff;
#else
                { __hip_fp8_e4m3 t0(v0), t1(v1), t2(v2), t3(v3);
                  q8[0] = t0.__x; q8[1] = t1.__x; q8[2] = t2.__x; q8[3] = t3.__x; }
#endif
                #pragma unroll
                for (int nt = 0; nt < 4; ++nt) {
                    int col = n0 + wn * 64 + nt * 16 + (lane & 15);
                    C8[(size_t)rowc * N + col] = q8[nt];
                }
            }
        }
    }

    // epilogue part 2: fused attention scores for this wave's 2 heads.
    // col = n0 + wn*64 + nt*16 + li  =>  head h0 = bx*8 + wn*2 (nt 0,1), h0+1 (nt 2,3);
    // o = (nt&1)*16 + li. Reduce over the 16 lanes of each quarter (one row per quarter).
    {
        const int li = lane & 15;
        const int h0 = bx * 8 + wn * 2;
        float ws00 = att_src[(h0)     * OC + li],      ws01 = att_src[(h0)     * OC + 16 + li];
        float ws10 = att_src[(h0 + 1) * OC + li],      ws11 = att_src[(h0 + 1) * OC + 16 + li];
        float wd00 = att_dst[(h0)     * OC + li],      wd01 = att_dst[(h0)     * OC + 16 + li];
        float wd10 = att_dst[(h0 + 1) * OC + li],      wd11 = att_dst[(h0 + 1) * OC + 16 + li];
        #pragma unroll
        for (int mt = 0; mt < 6; ++mt) {
            #pragma unroll
            for (int r4 = 0; r4 < 4; ++r4) {
                float s0 = acc[mt][0][r4] * ws00 + acc[mt][1][r4] * ws01;
                float s1 = acc[mt][2][r4] * ws10 + acc[mt][3][r4] * ws11;
                float d0 = acc[mt][0][r4] * wd00 + acc[mt][1][r4] * wd01;
                float d1 = acc[mt][2][r4] * wd10 + acc[mt][3][r4] * wd11;
                #pragma unroll
                for (int mk = 1; mk < 16; mk <<= 1) {
                    s0 += __shfl_xor(s0, mk, 64);
                    s1 += __shfl_xor(s1, mk, 64);
                    d0 += __shfl_xor(d0, mk, 64);
                    d1 += __shfl_xor(d1, mk, 64);
                }
                int rowc = m0 + wm * 96 + mt * 16 + (lane >> 4) * 4 + r4;
                if (li == 0 && rowc < M) {
                    as_[(size_t)rowc * NH + h0]     = s0;
                    as_[(size_t)rowc * NH + h0 + 1] = s1;
                    ad_[(size_t)rowc * NH + h0]     = d0;
                    ad_[(size_t)rowc * NH + h0 + 1] = d1;
                }
            }
        }
    }
}

// ---------------- node-boundary flush for the fused streaming aggregate ----------------
// acc holds UNNORMALIZED weighted sums; divide by den here.
// LAYER==1: bf16 h1p[cur][slice] = BN1(ELU(acc/den + b1))
// LAYER==2: head-reduce in-wave, write per-slice partial (non-atomic) to h2part[cur][f][32]
template <int LAYER>
__device__ __forceinline__ void flush_node(float* acc, float den, int cur, int f, int lane,
                                           const float* __restrict__ bias,
                                           const float* __restrict__ bng,
                                           const float* __restrict__ bnb,
                                           const float* __restrict__ bnm,
                                           const float* __restrict__ bnv,
                                           void* __restrict__ outp) {
    float inv = 1.f / den;
    #pragma unroll
    for (int k = 0; k < 4; ++k) acc[k] *= inv;

    if constexpr (LAYER == 1) {
        int d0 = f * 256 + lane * 4;
        u32 r01, r23;
        {
            float v0 = acc[0] + bias[d0 + 0];
            float v1 = acc[1] + bias[d0 + 1];
            float v2 = acc[2] + bias[d0 + 2];
            float v3 = acc[3] + bias[d0 + 3];
            v0 = v0 > 0.f ? v0 : expm1f(v0);
            v1 = v1 > 0.f ? v1 : expm1f(v1);
            v2 = v2 > 0.f ? v2 : expm1f(v2);
            v3 = v3 > 0.f ? v3 : expm1f(v3);
            v0 = (v0 - bnm[d0 + 0]) * rsqrtf(bnv[d0 + 0] + EPS_BN) * bng[d0 + 0] + bnb[d0 + 0];
            v1 = (v1 - bnm[d0 + 1]) * rsqrtf(bnv[d0 + 1] + EPS_BN) * bng[d0 + 1] + bnb[d0 + 1];
            v2 = (v2 - bnm[d0 + 2]) * rsqrtf(bnv[d0 + 2] + EPS_BN) * bng[d0 + 2] + bnb[d0 + 2];
            v3 = (v3 - bnm[d0 + 3]) * rsqrtf(bnv[d0 + 3] + EPS_BN) * bng[d0 + 3] + bnb[d0 + 3];
            __hip_bfloat16 b0 = __float2bfloat16(v0), b1 = __float2bfloat16(v1);
            __hip_bfloat16 b2 = __float2bfloat16(v2), b3 = __float2bfloat16(v3);
            r01 = (u32)*(unsigned short*)&b0 | ((u32)*(unsigned short*)&b1 << 16);
            r23 = (u32)*(unsigned short*)&b2 | ((u32)*(unsigned short*)&b3 << 16);
        }
        uint2 pk; pk.x = r01; pk.y = r23;
        *(uint2*)((__hip_bfloat16*)outp + (size_t)cur * DD1 + d0) = pk;
    } else {
        // sum over the 8 heads held by this wave (lane groups stride 8)
        #pragma unroll
        for (int k = 0; k < 4; ++k) {
            acc[k] += __shfl_xor(acc[k], 8, 64);
            acc[k] += __shfl_xor(acc[k], 16, 64);
            acc[k] += __shfl_xor(acc[k], 32, 64);
        }
        if (lane < 8) {
            floatx4 pk;
            #pragma unroll
            for (int k = 0; k < 4; ++k) pk[k] = acc[k] * (1.f / NH);
            *(floatx4*)((float*)outp + ((size_t)cur * 7 + f) * OC + lane * 4) = pk;
        }
    }
    acc[0] = acc[1] = acc[2] = acc[3] = 0.f;
}

// ---------------- fused streaming aggregation with ONLINE SOFTMAX (round-5 proven) ----------------
template <int LAYER>
__global__ __launch_bounds__(256) void attn_aggregate(const int* __restrict__ rowptr,
                                                      const int* __restrict__ csr_src,
                                                      const float* __restrict__ as_,
                                                      const float* __restrict__ ad_,
                                                      const unsigned char* __restrict__ h8,
                                                      const float* __restrict__ bias,
                                                      const float* __restrict__ bng,
                                                      const float* __restrict__ bnb,
                                                      const float* __restrict__ bnm,
                                                      const float* __restrict__ bnv,
                                                      void* __restrict__ outp) {
    const int wv = threadIdx.x >> 6, lane = threadIdx.x & 63;
    const int w = blockIdx.x * 4 + wv;
    const int NWAVES = 7 * (NN / GRP);
    if (w >= NWAVES) return;
    const int f  = w % 7;             // feature slice (256 B of the 1792-B row)
    const int g  = w / 7;             // node group
    const int n0 = g * GRP;
    const int off  = f * 256 + lane * 4;
    const int head = f * 8 + (lane >> 3);

    const int e0 = rowptr[n0], e1 = rowptr[n0 + GRP];
    int cur = n0;
    int bound = rowptr[n0 + 1];
    float adv = ad_[(size_t)cur * NH + head];

    float acc[4] = {0.f, 0.f, 0.f, 0.f};
    float m = -1e30f, den = 0.f;

    for (int e = e0; e < e1; e += EB) {
        u32   hv[EB];
        float sv[EB];
        // unconditional clamp-padded loads: EB independent chains in flight
        #pragma unroll
        for (int i = 0; i < EB; ++i) {
            int idx = (e + i < e1) ? e + i : e1 - 1;
            int s = csr_src[idx];
            hv[i] = *(const u32*)(h8 + (size_t)s * DD1 + off);
            sv[i] = as_[(size_t)s * NH + head];
        }
        #pragma unroll
        for (int i = 0; i < EB; ++i) {
            if (e + i >= e1) break;                 // tail padding: skip
            if (e + i >= bound) {                   // crossed into next node
                flush_node<LAYER>(acc, den, cur, f, lane, bias, bng, bnb, bnm, bnv, outp);
                ++cur;
                bound = rowptr[cur + 1];
                adv = ad_[(size_t)cur * NH + head];
                m = -1e30f; den = 0.f;
            }
            float lr = sv[i] + adv;
            lr = lr > 0.f ? lr : 0.2f * lr;         // leaky_relu
            float wgt;
            if (lr > m) {                           // new max: rescale history
                float scale = __expf(m - lr);
                den = den * scale + 1.f;
                #pragma unroll
                for (int k = 0; k < 4; ++k) acc[k] *= scale;
                m = lr;
                wgt = 1.f;
            } else {
                wgt = __expf(lr - m);
                den += wgt;
            }
            fma_fp8x4(hv[i], wgt, acc);
        }
    }
    flush_node<LAYER>(acc, den, cur, f, lane, bias, bng, bnb, bnm, bnv, outp);
}

// ---------------- mean pool: sorted-batch segmented reduction, minimal atomics ----------------
__global__ __launch_bounds__(256) void pool_kernel(const float* __restrict__ h2part,
                                                   const int* __restrict__ batch,
                                                   float* __restrict__ sums,
                                                   float* __restrict__ cnt) {
    __shared__ float red[4][OC];
    const int g = blockIdx.x >> 3, c = blockIdx.x & 7;
    const int t = threadIdx.x;
    const int ch = t & 31, nl = t >> 5;          // nl in 0..7
    int lo = 0, hi = NN;
    while (lo < hi) { int mid = (lo + hi) >> 1; if (batch[mid] < g) lo = mid + 1; else hi = mid; }
    const int s = lo;
    hi = NN;
    while (lo < hi) { int mid = (lo + hi) >> 1; if (batch[mid] <= g) lo = mid + 1; else hi = mid; }
    const int e = lo;
    const int len = e - s;
    const int n0 = s + (len * c) / 8;
    const int n1 = s + (len * (c + 1)) / 8;
    float acc = 0.f;
    for (int n = n0 + nl; n < n1; n += 8) {
        const float* p = h2part + (size_t)n * 7 * OC + ch;
        float a = 0.f;
        #pragma unroll
        for (int f = 0; f < 7; ++f) a += p[f * OC];
        acc += a;
    }
    acc += __shfl_xor(acc, 32, 64);
    if ((t & 32) == 0) red[t >> 6][ch] = acc;
    __syncthreads();
    if (t < OC) {
        float total = red[0][t] + red[1][t] + red[2][t] + red[3][t];
        atomicAdd(&sums[g * OC + t], total);
    }
    if (t == 0 && c == 0) cnt[g] = (float)len;
}

// final: pooled = sums/cnt; v = BN2(pooled + b2); out = v @ lin_w + lin_b
__global__ __launch_bounds__(128) void final_kernel(const float* __restrict__ sums,
                                                    const float* __restrict__ cnt,
                                                    const float* __restrict__ b2,
                                                    const float* __restrict__ bn2g,
                                                    const float* __restrict__ bn2b,
                                                    const float* __restrict__ bn2m,
                                                    const float* __restrict__ bn2v,
                                                    const float* __restrict__ lin_w,
                                                    const float* __restrict__ lin_b,
                                                    float* __restrict__ out) {
    int t = threadIdx.x;
    if (t >= NG * 2) return;
    int g = t >> 1, c = t & 1;
    float invc = 1.f / fmaxf(cnt[g], 1.f);
    float acc = lin_b[c];
    #pragma unroll
    for (int o = 0; o < OC; ++o) {
        float pooled = sums[g * OC + o] * invc + b2[o];
        float v = (pooled - bn2m[o]) * rsqrtf(bn2v[o] + EPS_BN) * bn2g[o] + bn2b[o];
        acc += v * lin_w[o * 2 + c];
    }
    out[t] = acc;
}

// ---------------- host-side launch ----------------
extern "C" void kernel_launch(void* const* d_in, const int* in_sizes, int n_in,
                              void* d_out, int out_size, void* d_ws, size_t ws_size,
                              hipStream_t stream) {
    const float* x    = (const float*)d_in[0];
    const int*   ei   = (const int*)d_in[1];
    const int*   bat  = (const int*)d_in[2];
    const float* W1   = (const float*)d_in[3];
    const float* at_s1 = (const float*)d_in[4];
    const float* at_d1 = (const float*)d_in[5];
    const float* b1   = (const float*)d_in[6];
    const float* bn1g = (const float*)d_in[7];
    const float* bn1b = (const float*)d_in[8];
    const float* bn1m = (const float*)d_in[9];
    const float* bn1v = (const float*)d_in[10];
    const float* W2   = (const float*)d_in[11];
    const float* at_s2 = (const float*)d_in[12];
    const float* at_d2 = (const float*)d_in[13];
    const float* b2   = (const float*)d_in[14];
    const float* bn2g = (const float*)d_in[15];
    const float* bn2b = (const float*)d_in[16];
    const float* bn2m = (const float*)d_in[17];
    const float* bn2v = (const float*)d_in[18];
    const float* linw = (const float*)d_in[19];
    const float* linb = (const float*)d_in[20];
    float* out = (float*)d_out;

    char* wsp = (char*)d_ws;
    auto alloc = [&](size_t bytes) -> void* {
        void* p = (void*)wsp;
        wsp += (bytes + 255) & ~(size_t)255;
        return p;
    };
    unsigned char*  h8  = (unsigned char*)alloc((size_t)NN * DD1);      // fp8 gemm output
    __hip_bfloat16* h1p = (__hip_bfloat16*)alloc((size_t)NN * DD1 * 2); // agg1 out (gemm2 A)
    __hip_bfloat16* xb  = (__hip_bfloat16*)alloc((size_t)NN * NF * 2);
    __hip_bfloat16* w1t = (__hip_bfloat16*)alloc((size_t)DD1 * NF * 2);
    __hip_bfloat16* w2t = (__hip_bfloat16*)alloc((size_t)DD1 * DD1 * 2);
    float* asb   = (float*)alloc((size_t)NN * NH * 4);
    float* adb   = (float*)alloc((size_t)NN * NH * 4);
    int*   deg   = (int*)alloc((size_t)NN * 4);
    int*   rowp  = (int*)alloc((size_t)(NN + 1) * 4);
    int*   curs  = (int*)alloc((size_t)NN * 4);
    int*   csr   = (int*)alloc((size_t)ETOT * 4);
    float* h2part = (float*)alloc((size_t)NN * 7 * OC * 4);
    float* sums  = (float*)alloc((size_t)(NG * OC + NG) * 4);
    float* cnt   = sums + NG * OC;

    hipMemsetAsync(deg, 0, (size_t)NN * 4, stream);
    hipMemsetAsync(sums, 0, (size_t)(NG * OC + NG) * 4, stream);

    cast_bf16_kernel<<<(NN * NF + 255) / 256, 256, 0, stream>>>(x, xb, NN * NF);
    transpose_cast_kernel<<<dim3(DD1 / 32, NF / 32), 256, 0, stream>>>(W1, w1t, NF, DD1);
    transpose_cast_kernel<<<dim3(DD1 / 32, DD1 / 32), 256, 0, stream>>>(W2, w2t, DD1, DD1);
    hist_kernel<<<(ETOT + 255) / 256, 256, 0, stream>>>(ei, deg);
    scan_kernel<<<1, 1024, 0, stream>>>(deg, rowp, curs);
    scatter_kernel<<<(ETOT + 255) / 256, 256, 0, stream>>>(ei, curs, csr);

    const int AGG_BLOCKS = (7 * (NN / GRP) + 3) / 4;
    const int NBY192 = (NN + 191) / 192;                   // 105
    const int GEMM_BLOCKS = NBY192 * (DD1 / 256);          // 735

    // layer 1 (attn_score fused into gemm epilogue)
    gemm_192<<<GEMM_BLOCKS, 512, 0, stream>>>(xb, w1t, h8, at_s1, at_d1, asb, adb, NN, DD1, NF);
    attn_aggregate<1><<<AGG_BLOCKS, 256, 0, stream>>>(rowp, csr, asb, adb, h8, b1, bn1g, bn1b, bn1m, bn1v, (void*)h1p);

    // layer 2
    gemm_192<<<GEMM_BLOCKS, 512, 0, stream>>>(h1p, w2t, h8, at_s2, at_d2, asb, adb, NN, DD1, DD1);
    attn_aggregate<2><<<AGG_BLOCKS, 256, 0, stream>>>(rowp, csr, asb, adb, h8, b2, bn2g, bn2b, bn2m, bn2v, (void*)h2part);

    pool_kernel<<<NG * 8, 256, 0, stream>>>(h2part, bat, sums, cnt);
    final_kernel<<<1, 128, 0, stream>>>(sums, cnt, b2, bn2g, bn2b, bn2m, bn2v, linw, linb, out);
}

// Round 13
// 521.755 us; speedup vs baseline: 1.2171x; 1.0582x over previous
//
#include <hip/hip_runtime.h>
#include <hip/hip_bf16.h>
#include <hip/hip_fp8.h>
#include <cstdint>
#include <cstddef>

// Problem constants
#define NN     20000     // nodes
#define NF     128       // in features
#define NH     56        // heads
#define OC     32        // out channels per head
#define DD1    1792      // NH*OC
#define NE     100000    // edges (before self loops)
#define ETOT   120000    // edges + self loops
#define NG     50        // graphs
#define EPS_BN 1e-5f
#define GRP    16        // nodes per wave in aggregate
#define EB     16        // edge batch (round-5 proven single-buffer)

typedef __bf16 bf16x8 __attribute__((ext_vector_type(8)));
typedef float  floatx4 __attribute__((ext_vector_type(4)));
typedef float  floatx2 __attribute__((ext_vector_type(2)));
typedef unsigned int u32;
typedef __attribute__((address_space(1))) u32 gu32;
typedef __attribute__((address_space(3))) u32 lu32;

__device__ __forceinline__ void async_copy16(void* lds, const void* g) {
    __builtin_amdgcn_global_load_lds((gu32*)const_cast<void*>(g), (lu32*)lds, 16, 0, 0);
}

// decode 4 fp8 (e4m3, packed in u32) to 4 floats (HW cvt when available)
__device__ __forceinline__ void dec_fp8x4(u32 u, float* v) {
#if __has_builtin(__builtin_amdgcn_cvt_pk_f32_fp8)
    floatx2 lo = __builtin_amdgcn_cvt_pk_f32_fp8(u, false);
    floatx2 hi = __builtin_amdgcn_cvt_pk_f32_fp8(u, true);
    v[0] = lo[0]; v[1] = lo[1]; v[2] = hi[0]; v[3] = hi[1];
#else
    #pragma unroll
    for (int b = 0; b < 4; ++b) {
        __hip_fp8_e4m3 t;
        t.__x = (u >> (8 * b)) & 0xff;
        v[b] = (float)t;
    }
#endif
}

__device__ __forceinline__ void fma_fp8x4(u32 u, float a, float* acc) {
    float v[4];
    dec_fp8x4(u, v);
    #pragma unroll
    for (int b = 0; b < 4; ++b) acc[b] += a * v[b];
}

// ---- 16-lane row sum via DPP (VALU pipe, NO LDS traffic — __shfl_xor lowers to
// ds_swizzle/ds_bpermute which hammer the LDS pipe this kernel is bound on).
// row_ror:8 -> row_ror:4 -> quad_perm xor2 -> quad_perm xor1: after the 4 adds every
// lane of each 16-lane row holds the full row sum.
template <int CTRL>
__device__ __forceinline__ float dpp_row_add(float x) {
    int v = __builtin_amdgcn_mov_dpp(__float_as_int(x), CTRL, 0xf, 0xf, true);
    return x + __int_as_float(v);
}
__device__ __forceinline__ float dpp_add16(float x) {
    x = dpp_row_add<0x128>(x);   // row_ror:8
    x = dpp_row_add<0x124>(x);   // row_ror:4
    x = dpp_row_add<78>(x);      // quad_perm [2,3,0,1] = xor2
    x = dpp_row_add<177>(x);     // quad_perm [1,0,3,2] = xor1
    return x;
}

// ---------------- elementwise cast fp32 -> bf16 ----------------
__global__ __launch_bounds__(256) void cast_bf16_kernel(const float* __restrict__ in,
                                                        __hip_bfloat16* __restrict__ out, int n) {
    int i = blockIdx.x * 256 + threadIdx.x;
    if (i < n) out[i] = __float2bfloat16(in[i]);
}

// ---------------- tiled transpose + cast: in[R][C] f32 -> out[C][R] bf16 ----------------
__global__ __launch_bounds__(256) void transpose_cast_kernel(const float* __restrict__ in,
                                                             __hip_bfloat16* __restrict__ out,
                                                             int R, int C) {
    __shared__ float tile[32][33];
    int c0 = blockIdx.x * 32, r0 = blockIdx.y * 32;
    int tx = threadIdx.x & 31, ty = threadIdx.x >> 5;   // ty in 0..7
    #pragma unroll
    for (int i = 0; i < 32; i += 8) {
        int r = r0 + ty + i, c = c0 + tx;
        if (r < R && c < C) tile[ty + i][tx] = in[(size_t)r * C + c];
    }
    __syncthreads();
    #pragma unroll
    for (int i = 0; i < 32; i += 8) {
        int c = c0 + ty + i, r = r0 + tx;
        if (c < C && r < R) out[(size_t)c * R + r] = __float2bfloat16(tile[tx][ty + i]);
    }
}

// ---------------- CSR build: histogram / scan / scatter ----------------
__global__ __launch_bounds__(256) void hist_kernel(const int* __restrict__ ei, int* __restrict__ deg) {
    int i = blockIdx.x * 256 + threadIdx.x;
    if (i >= ETOT) return;
    int dst = (i < NE) ? ei[NE + i] : (i - NE);
    atomicAdd(&deg[dst], 1);
}

__global__ __launch_bounds__(1024) void scan_kernel(const int* __restrict__ deg,
                                                    int* __restrict__ rowptr,
                                                    int* __restrict__ cursor) {
    __shared__ int buf[1024];
    int t = threadIdx.x;
    const int CH = (NN + 1023) >> 10;   // 20
    int base = t * CH;
    int s = 0;
    for (int j = 0; j < CH; ++j) { int idx = base + j; if (idx < NN) s += deg[idx]; }
    buf[t] = s;
    __syncthreads();
    for (int off = 1; off < 1024; off <<= 1) {
        int v = (t >= off) ? buf[t - off] : 0;
        __syncthreads();
        buf[t] += v;
        __syncthreads();
    }
    int run = buf[t] - s;   // exclusive
    for (int j = 0; j < CH; ++j) {
        int idx = base + j;
        if (idx < NN) { rowptr[idx] = run; cursor[idx] = run; run += deg[idx]; }
    }
    if (t == 1023) rowptr[NN] = buf[1023];
}

__global__ __launch_bounds__(256) void scatter_kernel(const int* __restrict__ ei,
                                                      int* __restrict__ cursor,
                                                      int* __restrict__ csr_src) {
    int i = blockIdx.x * 256 + threadIdx.x;
    if (i >= ETOT) return;
    int s, d;
    if (i < NE) { s = ei[i]; d = ei[NE + i]; } else { s = i - NE; d = i - NE; }
    int pos = atomicAdd(&cursor[d], 1);
    csr_src[pos] = s;
}

// ---------------- bf16 MFMA GEMM, 192x256 tile, 3-phase (round-5 proven, 8 waves) ----------------
// 8 waves (2Mx4N), per-wave C 96x64, BK=64, 2 LDS bufs, stage t+2 during t, single
// counted vmcnt(7) per K-tile (never drained: T4). ROW-MAJOR C8 output.
// attn_score fused into the epilogue; score reduction now via DPP (VALU) instead of
// __shfl_xor (DS pipe) — round-12 showed the shuffle butterfly cost ~21us/gemm of
// LDS-pipe time (384 ds ops/wave on the kernel's bottleneck pipe).
__global__ __launch_bounds__(512, 2) void gemm_192(const __hip_bfloat16* __restrict__ A,
                                                   const __hip_bfloat16* __restrict__ Bt,
                                                   unsigned char* __restrict__ C8,
                                                   const float* __restrict__ att_src,
                                                   const float* __restrict__ att_dst,
                                                   float* __restrict__ as_,
                                                   float* __restrict__ ad_,
                                                   int M, int N, int K) {
    __shared__ __align__(16) unsigned short lds[2][28672];  // per buf: A[192][64] | B[256][64]
    const int tid  = threadIdx.x;
    const int lane = tid & 63, wave = tid >> 6;
    const int wm = wave >> 2, wn = wave & 3;     // 2 x 4 wave grid; per-wave C: 96 x 64

    const int nbx = N >> 8;                      // 7
    const int nby = (M + 191) / 192;             // 105
    const int nwg = nbx * nby;                   // 735
    const int q = nwg >> 3, r = nwg & 7;
    const int xcd = blockIdx.x & 7, bidx = blockIdx.x >> 3;
    const int wg = (xcd < r ? xcd * (q + 1) : r * (q + 1) + (xcd - r) * q) + bidx;
    const int by = wg / nbx, bx = wg - by * nbx;
    const int m0 = by * 192, n0 = bx << 8;

    const int NT = K >> 6;                       // K-tiles of 64: 28 (L2) / 2 (L1)

    const int qq = lane >> 4, rr = lane & 15;

    auto stageA = [&](int kt, int b) {
        #pragma unroll
        for (int i = 0; i < 3; ++i) {
            int slot = i * 512 + tid;
            int row = slot >> 3, pch = slot & 7;
            int lc = pch ^ (row & 7);            // pre-swizzled global source (rule #21)
            int gr = m0 + row; if (gr > M - 1) gr = M - 1;
            async_copy16(&lds[b][slot * 8], A + (size_t)gr * K + (kt << 6) + lc * 8);
        }
    };
    auto stageB = [&](int kt, int b) {
        #pragma unroll
        for (int i = 0; i < 4; ++i) {
            int slot = i * 512 + tid;
            int row = slot >> 3, pch = slot & 7;
            int lc = pch ^ (row & 7);
            async_copy16(&lds[b][12288 + slot * 8], Bt + (size_t)(n0 + row) * K + (kt << 6) + lc * 8);
        }
    };

    floatx4 zero = {0.f, 0.f, 0.f, 0.f};
    floatx4 acc[6][4];
    #pragma unroll
    for (int i = 0; i < 6; ++i)
        #pragma unroll
        for (int jj = 0; jj < 4; ++jj) acc[i][jj] = zero;

    bf16x8 aF[3][2], bA[2][2], bB[2][2];

    auto loadA = [&](int b, int mg) {
        #pragma unroll
        for (int mf = 0; mf < 3; ++mf)
            #pragma unroll
            for (int s = 0; s < 2; ++s) {
                int row = wm * 96 + mg * 48 + mf * 16 + rr;
                int pch = (s * 4 + qq) ^ (row & 7);
                aF[mf][s] = *(const bf16x8*)&lds[b][row * 64 + pch * 8];
            }
    };
    auto loadB = [&](int b, bf16x8 (&bF)[2][2], int ng) {
        #pragma unroll
        for (int nf = 0; nf < 2; ++nf)
            #pragma unroll
            for (int s = 0; s < 2; ++s) {
                int row = wn * 64 + (ng * 2 + nf) * 16 + rr;
                int pch = (s * 4 + qq) ^ (row & 7);
                bF[nf][s] = *(const bf16x8*)&lds[b][12288 + row * 64 + pch * 8];
            }
    };
    auto mfmaQ = [&](int mg, int ng, bf16x8 (&bF)[2][2]) {
        #pragma unroll
        for (int mf = 0; mf < 3; ++mf)
            #pragma unroll
            for (int nf = 0; nf < 2; ++nf)
                #pragma unroll
                for (int s = 0; s < 2; ++s)
                    acc[mg * 3 + mf][ng * 2 + nf] = __builtin_amdgcn_mfma_f32_16x16x32_bf16(
                        aF[mf][s], bF[nf][s], acc[mg * 3 + mf][ng * 2 + nf], 0, 0, 0);
    };

#define SB0 __builtin_amdgcn_sched_barrier(0)
#define GBAR do { SB0; __builtin_amdgcn_s_barrier(); SB0; } while (0)

    stageB(0, 0); stageA(0, 0);
    stageB(1, 1); stageA(1, 1);
    SB0;
    asm volatile("s_waitcnt vmcnt(7)" ::: "memory");
    GBAR;

    for (int t = 0; t < NT; ++t) {
        const int p = t & 1;
        int tp = t + 2; while (tp >= NT) tp -= 2;

        loadA(p, 0); loadB(p, bA, 0);
        GBAR;
        __builtin_amdgcn_s_setprio(1);
        mfmaQ(0, 0, bA);
        __builtin_amdgcn_s_setprio(0);
        GBAR;

        loadB(p, bB, 1);
        stageB(tp, p);
        GBAR;
        __builtin_amdgcn_s_setprio(1);
        mfmaQ(0, 1, bB);
        __builtin_amdgcn_s_setprio(0);
        GBAR;

        loadA(p, 1);
        stageA(tp, p);
        SB0;
        asm volatile("s_waitcnt vmcnt(7)" ::: "memory");
        GBAR;
        __builtin_amdgcn_s_setprio(1);
        mfmaQ(1, 1, bB);
        mfmaQ(1, 0, bA);
        __builtin_amdgcn_s_setprio(0);
        GBAR;
    }
#undef GBAR
#undef SB0

    // epilogue part 1: fp8 quantize + store (row-major, round-5 form)
    #pragma unroll
    for (int mt = 0; mt < 6; ++mt) {
        #pragma unroll
        for (int r4 = 0; r4 < 4; ++r4) {
            int rowc = m0 + wm * 96 + mt * 16 + (lane >> 4) * 4 + r4;
            if (rowc < M) {
                float v0 = acc[mt][0][r4], v1 = acc[mt][1][r4];
                float v2 = acc[mt][2][r4], v3 = acc[mt][3][r4];
                unsigned char q8[4];
#if __has_builtin(__builtin_amdgcn_cvt_pk_fp8_f32)
                u32 p01 = (u32)__builtin_amdgcn_cvt_pk_fp8_f32(v0, v1, 0, false);
                u32 p23 = (u32)__builtin_amdgcn_cvt_pk_fp8_f32(v2, v3, 0, false);
                q8[0] = p01 & 0xff; q8[1] = (p01 >> 8) & 0xff;
                q8[2] = p23 & 0xff; q8[3] = (p23 >> 8) & 0xff;
#else
                { __hip_fp8_e4m3 t0(v0), t1(v1), t2(v2), t3(v3);
                  q8[0] = t0.__x; q8[1] = t1.__x; q8[2] = t2.__x; q8[3] = t3.__x; }
#endif
                #pragma unroll
                for (int nt = 0; nt < 4; ++nt) {
                    int col = n0 + wn * 64 + nt * 16 + (lane & 15);
                    C8[(size_t)rowc * N + col] = q8[nt];
                }
            }
        }
    }

    // epilogue part 2: fused attention scores for this wave's 2 heads.
    // col = n0 + wn*64 + nt*16 + li  =>  head h0 = bx*8 + wn*2 (nt 0,1), h0+1 (nt 2,3);
    // o = (nt&1)*16 + li. Row-sum over each 16-lane quarter via DPP (VALU-only).
    {
        const int li = lane & 15;
        const int h0 = bx * 8 + wn * 2;
        float ws00 = att_src[(h0)     * OC + li],      ws01 = att_src[(h0)     * OC + 16 + li];
        float ws10 = att_src[(h0 + 1) * OC + li],      ws11 = att_src[(h0 + 1) * OC + 16 + li];
        float wd00 = att_dst[(h0)     * OC + li],      wd01 = att_dst[(h0)     * OC + 16 + li];
        float wd10 = att_dst[(h0 + 1) * OC + li],      wd11 = att_dst[(h0 + 1) * OC + 16 + li];
        #pragma unroll
        for (int mt = 0; mt < 6; ++mt) {
            #pragma unroll
            for (int r4 = 0; r4 < 4; ++r4) {
                float s0 = dpp_add16(acc[mt][0][r4] * ws00 + acc[mt][1][r4] * ws01);
                float s1 = dpp_add16(acc[mt][2][r4] * ws10 + acc[mt][3][r4] * ws11);
                float d0 = dpp_add16(acc[mt][0][r4] * wd00 + acc[mt][1][r4] * wd01);
                float d1 = dpp_add16(acc[mt][2][r4] * wd10 + acc[mt][3][r4] * wd11);
                int rowc = m0 + wm * 96 + mt * 16 + (lane >> 4) * 4 + r4;
                if (li == 0 && rowc < M) {
                    as_[(size_t)rowc * NH + h0]     = s0;
                    as_[(size_t)rowc * NH + h0 + 1] = s1;
                    ad_[(size_t)rowc * NH + h0]     = d0;
                    ad_[(size_t)rowc * NH + h0 + 1] = d1;
                }
            }
        }
    }
}

// ---------------- node-boundary flush for the fused streaming aggregate ----------------
// acc holds UNNORMALIZED weighted sums; divide by den here.
// LAYER==1: bf16 h1p[cur][slice] = BN1(ELU(acc/den + b1))
// LAYER==2: head-reduce in-wave, write per-slice partial (non-atomic) to h2part[cur][f][32]
template <int LAYER>
__device__ __forceinline__ void flush_node(float* acc, float den, int cur, int f, int lane,
                                           const float* __restrict__ bias,
                                           const float* __restrict__ bng,
                                           const float* __restrict__ bnb,
                                           const float* __restrict__ bnm,
                                           const float* __restrict__ bnv,
                                           void* __restrict__ outp) {
    float inv = 1.f / den;
    #pragma unroll
    for (int k = 0; k < 4; ++k) acc[k] *= inv;

    if constexpr (LAYER == 1) {
        int d0 = f * 256 + lane * 4;
        u32 r01, r23;
        {
            float v0 = acc[0] + bias[d0 + 0];
            float v1 = acc[1] + bias[d0 + 1];
            float v2 = acc[2] + bias[d0 + 2];
            float v3 = acc[3] + bias[d0 + 3];
            v0 = v0 > 0.f ? v0 : expm1f(v0);
            v1 = v1 > 0.f ? v1 : expm1f(v1);
            v2 = v2 > 0.f ? v2 : expm1f(v2);
            v3 = v3 > 0.f ? v3 : expm1f(v3);
            v0 = (v0 - bnm[d0 + 0]) * rsqrtf(bnv[d0 + 0] + EPS_BN) * bng[d0 + 0] + bnb[d0 + 0];
            v1 = (v1 - bnm[d0 + 1]) * rsqrtf(bnv[d0 + 1] + EPS_BN) * bng[d0 + 1] + bnb[d0 + 1];
            v2 = (v2 - bnm[d0 + 2]) * rsqrtf(bnv[d0 + 2] + EPS_BN) * bng[d0 + 2] + bnb[d0 + 2];
            v3 = (v3 - bnm[d0 + 3]) * rsqrtf(bnv[d0 + 3] + EPS_BN) * bng[d0 + 3] + bnb[d0 + 3];
            __hip_bfloat16 b0 = __float2bfloat16(v0), b1 = __float2bfloat16(v1);
            __hip_bfloat16 b2 = __float2bfloat16(v2), b3 = __float2bfloat16(v3);
            r01 = (u32)*(unsigned short*)&b0 | ((u32)*(unsigned short*)&b1 << 16);
            r23 = (u32)*(unsigned short*)&b2 | ((u32)*(unsigned short*)&b3 << 16);
        }
        uint2 pk; pk.x = r01; pk.y = r23;
        *(uint2*)((__hip_bfloat16*)outp + (size_t)cur * DD1 + d0) = pk;
    } else {
        // sum over the 8 heads held by this wave (lane groups stride 8)
        #pragma unroll
        for (int k = 0; k < 4; ++k) {
            acc[k] += __shfl_xor(acc[k], 8, 64);
            acc[k] += __shfl_xor(acc[k], 16, 64);
            acc[k] += __shfl_xor(acc[k], 32, 64);
        }
        if (lane < 8) {
            floatx4 pk;
            #pragma unroll
            for (int k = 0; k < 4; ++k) pk[k] = acc[k] * (1.f / NH);
            *(floatx4*)((float*)outp + ((size_t)cur * 7 + f) * OC + lane * 4) = pk;
        }
    }
    acc[0] = acc[1] = acc[2] = acc[3] = 0.f;
}

// ---------------- fused streaming aggregation with ONLINE SOFTMAX (round-5 proven) ----------------
template <int LAYER>
__global__ __launch_bounds__(256) void attn_aggregate(const int* __restrict__ rowptr,
                                                      const int* __restrict__ csr_src,
                                                      const float* __restrict__ as_,
                                                      const float* __restrict__ ad_,
                                                      const unsigned char* __restrict__ h8,
                                                      const float* __restrict__ bias,
                                                      const float* __restrict__ bng,
                                                      const float* __restrict__ bnb,
                                                      const float* __restrict__ bnm,
                                                      const float* __restrict__ bnv,
                                                      void* __restrict__ outp) {
    const int wv = threadIdx.x >> 6, lane = threadIdx.x & 63;
    const int w = blockIdx.x * 4 + wv;
    const int NWAVES = 7 * (NN / GRP);
    if (w >= NWAVES) return;
    const int f  = w % 7;             // feature slice (256 B of the 1792-B row)
    const int g  = w / 7;             // node group
    const int n0 = g * GRP;
    const int off  = f * 256 + lane * 4;
    const int head = f * 8 + (lane >> 3);

    const int e0 = rowptr[n0], e1 = rowptr[n0 + GRP];
    int cur = n0;
    int bound = rowptr[n0 + 1];
    float adv = ad_[(size_t)cur * NH + head];

    float acc[4] = {0.f, 0.f, 0.f, 0.f};
    float m = -1e30f, den = 0.f;

    for (int e = e0; e < e1; e += EB) {
        u32   hv[EB];
        float sv[EB];
        // unconditional clamp-padded loads: EB independent chains in flight
        #pragma unroll
        for (int i = 0; i < EB; ++i) {
            int idx = (e + i < e1) ? e + i : e1 - 1;
            int s = csr_src[idx];
            hv[i] = *(const u32*)(h8 + (size_t)s * DD1 + off);
            sv[i] = as_[(size_t)s * NH + head];
        }
        #pragma unroll
        for (int i = 0; i < EB; ++i) {
            if (e + i >= e1) break;                 // tail padding: skip
            if (e + i >= bound) {                   // crossed into next node
                flush_node<LAYER>(acc, den, cur, f, lane, bias, bng, bnb, bnm, bnv, outp);
                ++cur;
                bound = rowptr[cur + 1];
                adv = ad_[(size_t)cur * NH + head];
                m = -1e30f; den = 0.f;
            }
            float lr = sv[i] + adv;
            lr = lr > 0.f ? lr : 0.2f * lr;         // leaky_relu
            float wgt;
            if (lr > m) {                           // new max: rescale history
                float scale = __expf(m - lr);
                den = den * scale + 1.f;
                #pragma unroll
                for (int k = 0; k < 4; ++k) acc[k] *= scale;
                m = lr;
                wgt = 1.f;
            } else {
                wgt = __expf(lr - m);
                den += wgt;
            }
            fma_fp8x4(hv[i], wgt, acc);
        }
    }
    flush_node<LAYER>(acc, den, cur, f, lane, bias, bng, bnb, bnm, bnv, outp);
}

// ---------------- mean pool: sorted-batch segmented reduction, minimal atomics ----------------
__global__ __launch_bounds__(256) void pool_kernel(const float* __restrict__ h2part,
                                                   const int* __restrict__ batch,
                                                   float* __restrict__ sums,
                                                   float* __restrict__ cnt) {
    __shared__ float red[4][OC];
    const int g = blockIdx.x >> 3, c = blockIdx.x & 7;
    const int t = threadIdx.x;
    const int ch = t & 31, nl = t >> 5;          // nl in 0..7
    int lo = 0, hi = NN;
    while (lo < hi) { int mid = (lo + hi) >> 1; if (batch[mid] < g) lo = mid + 1; else hi = mid; }
    const int s = lo;
    hi = NN;
    while (lo < hi) { int mid = (lo + hi) >> 1; if (batch[mid] <= g) lo = mid + 1; else hi = mid; }
    const int e = lo;
    const int len = e - s;
    const int n0 = s + (len * c) / 8;
    const int n1 = s + (len * (c + 1)) / 8;
    float acc = 0.f;
    for (int n = n0 + nl; n < n1; n += 8) {
        const float* p = h2part + (size_t)n * 7 * OC + ch;
        float a = 0.f;
        #pragma unroll
        for (int f = 0; f < 7; ++f) a += p[f * OC];
        acc += a;
    }
    acc += __shfl_xor(acc, 32, 64);
    if ((t & 32) == 0) red[t >> 6][ch] = acc;
    __syncthreads();
    if (t < OC) {
        float total = red[0][t] + red[1][t] + red[2][t] + red[3][t];
        atomicAdd(&sums[g * OC + t], total);
    }
    if (t == 0 && c == 0) cnt[g] = (float)len;
}

// final: pooled = sums/cnt; v = BN2(pooled + b2); out = v @ lin_w + lin_b
__global__ __launch_bounds__(128) void final_kernel(const float* __restrict__ sums,
                                                    const float* __restrict__ cnt,
                                                    const float* __restrict__ b2,
                                                    const float* __restrict__ bn2g,
                                                    const float* __restrict__ bn2b,
                                                    const float* __restrict__ bn2m,
                                                    const float* __restrict__ bn2v,
                                                    const float* __restrict__ lin_w,
                                                    const float* __restrict__ lin_b,
                                                    float* __restrict__ out) {
    int t = threadIdx.x;
    if (t >= NG * 2) return;
    int g = t >> 1, c = t & 1;
    float invc = 1.f / fmaxf(cnt[g], 1.f);
    float acc = lin_b[c];
    #pragma unroll
    for (int o = 0; o < OC; ++o) {
        float pooled = sums[g * OC + o] * invc + b2[o];
        float v = (pooled - bn2m[o]) * rsqrtf(bn2v[o] + EPS_BN) * bn2g[o] + bn2b[o];
        acc += v * lin_w[o * 2 + c];
    }
    out[t] = acc;
}

// ---------------- host-side launch ----------------
extern "C" void kernel_launch(void* const* d_in, const int* in_sizes, int n_in,
                              void* d_out, int out_size, void* d_ws, size_t ws_size,
                              hipStream_t stream) {
    const float* x    = (const float*)d_in[0];
    const int*   ei   = (const int*)d_in[1];
    const int*   bat  = (const int*)d_in[2];
    const float* W1   = (const float*)d_in[3];
    const float* at_s1 = (const float*)d_in[4];
    const float* at_d1 = (const float*)d_in[5];
    const float* b1   = (const float*)d_in[6];
    const float* bn1g = (const float*)d_in[7];
    const float* bn1b = (const float*)d_in[8];
    const float* bn1m = (const float*)d_in[9];
    const float* bn1v = (const float*)d_in[10];
    const float* W2   = (const float*)d_in[11];
    const float* at_s2 = (const float*)d_in[12];
    const float* at_d2 = (const float*)d_in[13];
    const float* b2   = (const float*)d_in[14];
    const float* bn2g = (const float*)d_in[15];
    const float* bn2b = (const float*)d_in[16];
    const float* bn2m = (const float*)d_in[17];
    const float* bn2v = (const float*)d_in[18];
    const float* linw = (const float*)d_in[19];
    const float* linb = (const float*)d_in[20];
    float* out = (float*)d_out;

    char* wsp = (char*)d_ws;
    auto alloc = [&](size_t bytes) -> void* {
        void* p = (void*)wsp;
        wsp += (bytes + 255) & ~(size_t)255;
        return p;
    };
    unsigned char*  h8  = (unsigned char*)alloc((size_t)NN * DD1);      // fp8 gemm output
    __hip_bfloat16* h1p = (__hip_bfloat16*)alloc((size_t)NN * DD1 * 2); // agg1 out (gemm2 A)
    __hip_bfloat16* xb  = (__hip_bfloat16*)alloc((size_t)NN * NF * 2);
    __hip_bfloat16* w1t = (__hip_bfloat16*)alloc((size_t)DD1 * NF * 2);
    __hip_bfloat16* w2t = (__hip_bfloat16*)alloc((size_t)DD1 * DD1 * 2);
    float* asb   = (float*)alloc((size_t)NN * NH * 4);
    float* adb   = (float*)alloc((size_t)NN * NH * 4);
    int*   deg   = (int*)alloc((size_t)NN * 4);
    int*   rowp  = (int*)alloc((size_t)(NN + 1) * 4);
    int*   curs  = (int*)alloc((size_t)NN * 4);
    int*   csr   = (int*)alloc((size_t)ETOT * 4);
    float* h2part = (float*)alloc((size_t)NN * 7 * OC * 4);
    float* sums  = (float*)alloc((size_t)(NG * OC + NG) * 4);
    float* cnt   = sums + NG * OC;

    hipMemsetAsync(deg, 0, (size_t)NN * 4, stream);
    hipMemsetAsync(sums, 0, (size_t)(NG * OC + NG) * 4, stream);

    cast_bf16_kernel<<<(NN * NF + 255) / 256, 256, 0, stream>>>(x, xb, NN * NF);
    transpose_cast_kernel<<<dim3(DD1 / 32, NF / 32), 256, 0, stream>>>(W1, w1t, NF, DD1);
    transpose_cast_kernel<<<dim3(DD1 / 32, DD1 / 32), 256, 0, stream>>>(W2, w2t, DD1, DD1);
    hist_kernel<<<(ETOT + 255) / 256, 256, 0, stream>>>(ei, deg);
    scan_kernel<<<1, 1024, 0, stream>>>(deg, rowp, curs);
    scatter_kernel<<<(ETOT + 255) / 256, 256, 0, stream>>>(ei, curs, csr);

    const int AGG_BLOCKS = (7 * (NN / GRP) + 3) / 4;
    const int NBY192 = (NN + 191) / 192;                   // 105
    const int GEMM_BLOCKS = NBY192 * (DD1 / 256);          // 735

    // layer 1 (attn_score fused into gemm epilogue)
    gemm_192<<<GEMM_BLOCKS, 512, 0, stream>>>(xb, w1t, h8, at_s1, at_d1, asb, adb, NN, DD1, NF);
    attn_aggregate<1><<<AGG_BLOCKS, 256, 0, stream>>>(rowp, csr, asb, adb, h8, b1, bn1g, bn1b, bn1m, bn1v, (void*)h1p);

    // layer 2
    gemm_192<<<GEMM_BLOCKS, 512, 0, stream>>>(h1p, w2t, h8, at_s2, at_d2, asb, adb, NN, DD1, DD1);
    attn_aggregate<2><<<AGG_BLOCKS, 256, 0, stream>>>(rowp, csr, asb, adb, h8, b2, bn2g, bn2b, bn2m, bn2v, (void*)h2part);

    pool_kernel<<<NG * 8, 256, 0, stream>>>(h2part, bat, sums, cnt);
    final_kernel<<<1, 128, 0, stream>>>(sums, cnt, b2, bn2g, bn2b, bn2m, bn2v, linw, linb, out);
}

// Round 14
// 517.713 us; speedup vs baseline: 1.2266x; 1.0078x over previous
//
#include <hip/hip_runtime.h>
#include <hip/hip_bf16.h>
#include <hip/hip_fp8.h>
#include <cstdint>
#include <cstddef>

// Problem constants
#define NN     20000     // nodes
#define NF     128       // in features
#define NH     56        // heads
#define OC     32        // out channels per head
#define DD1    1792      // NH*OC
#define NE     100000    // edges (before self loops)
#define ETOT   120000    // edges + self loops
#define NG     50        // graphs
#define EPS_BN 1e-5f
#define GRP    16        // nodes per wave in aggregate
#define EB     16        // edge batch (round-5 proven single-buffer)
#define W2SCL  16.0f     // W2 pre-scale (fp8 range); epilogue multiplies by 1/W2SCL

typedef __bf16 bf16x8 __attribute__((ext_vector_type(8)));
typedef float  floatx4 __attribute__((ext_vector_type(4)));
typedef float  floatx2 __attribute__((ext_vector_type(2)));
typedef unsigned int u32;
typedef __attribute__((address_space(1))) u32 gu32;
typedef __attribute__((address_space(3))) u32 lu32;

__device__ __forceinline__ void async_copy16(void* lds, const void* g) {
    __builtin_amdgcn_global_load_lds((gu32*)const_cast<void*>(g), (lu32*)lds, 16, 0, 0);
}

// decode 4 fp8 (e4m3, packed in u32) to 4 floats (HW cvt when available)
__device__ __forceinline__ void dec_fp8x4(u32 u, float* v) {
#if __has_builtin(__builtin_amdgcn_cvt_pk_f32_fp8)
    floatx2 lo = __builtin_amdgcn_cvt_pk_f32_fp8(u, false);
    floatx2 hi = __builtin_amdgcn_cvt_pk_f32_fp8(u, true);
    v[0] = lo[0]; v[1] = lo[1]; v[2] = hi[0]; v[3] = hi[1];
#else
    #pragma unroll
    for (int b = 0; b < 4; ++b) {
        __hip_fp8_e4m3 t;
        t.__x = (u >> (8 * b)) & 0xff;
        v[b] = (float)t;
    }
#endif
}

__device__ __forceinline__ u32 enc_fp8x4(float v0, float v1, float v2, float v3) {
#if __has_builtin(__builtin_amdgcn_cvt_pk_fp8_f32)
    u32 p01 = (u32)__builtin_amdgcn_cvt_pk_fp8_f32(v0, v1, 0, false);
    u32 p23 = (u32)__builtin_amdgcn_cvt_pk_fp8_f32(v2, v3, 0, false);
    return (p01 & 0xffff) | (p23 << 16);
#else
    __hip_fp8_e4m3 t0(v0), t1(v1), t2(v2), t3(v3);
    return (u32)t0.__x | ((u32)t1.__x << 8) | ((u32)t2.__x << 16) | ((u32)t3.__x << 24);
#endif
}

__device__ __forceinline__ void fma_fp8x4(u32 u, float a, float* acc) {
    float v[4];
    dec_fp8x4(u, v);
    #pragma unroll
    for (int b = 0; b < 4; ++b) acc[b] += a * v[b];
}

// ---- 16-lane row sum via DPP (VALU pipe, NO LDS traffic; round-13 proven) ----
template <int CTRL>
__device__ __forceinline__ float dpp_row_add(float x) {
    int v = __builtin_amdgcn_mov_dpp(__float_as_int(x), CTRL, 0xf, 0xf, true);
    return x + __int_as_float(v);
}
__device__ __forceinline__ float dpp_add16(float x) {
    x = dpp_row_add<0x128>(x);   // row_ror:8
    x = dpp_row_add<0x124>(x);   // row_ror:4
    x = dpp_row_add<78>(x);      // quad_perm [2,3,0,1] = xor2
    x = dpp_row_add<177>(x);     // quad_perm [1,0,3,2] = xor1
    return x;
}

// ---------------- elementwise cast fp32 -> bf16 ----------------
__global__ __launch_bounds__(256) void cast_bf16_kernel(const float* __restrict__ in,
                                                        __hip_bfloat16* __restrict__ out, int n) {
    int i = blockIdx.x * 256 + threadIdx.x;
    if (i < n) out[i] = __float2bfloat16(in[i]);
}

// ---------------- tiled transpose + cast: in[R][C] f32 -> out[C][R] bf16 ----------------
__global__ __launch_bounds__(256) void transpose_cast_kernel(const float* __restrict__ in,
                                                             __hip_bfloat16* __restrict__ out,
                                                             int R, int C) {
    __shared__ float tile[32][33];
    int c0 = blockIdx.x * 32, r0 = blockIdx.y * 32;
    int tx = threadIdx.x & 31, ty = threadIdx.x >> 5;   // ty in 0..7
    #pragma unroll
    for (int i = 0; i < 32; i += 8) {
        int r = r0 + ty + i, c = c0 + tx;
        if (r < R && c < C) tile[ty + i][tx] = in[(size_t)r * C + c];
    }
    __syncthreads();
    #pragma unroll
    for (int i = 0; i < 32; i += 8) {
        int c = c0 + ty + i, r = r0 + tx;
        if (c < C && r < R) out[(size_t)c * R + r] = __float2bfloat16(tile[tx][ty + i]);
    }
}

// ---------------- tiled transpose + fp8 cast with W2SCL pre-scale ----------------
__global__ __launch_bounds__(256) void transpose_fp8_kernel(const float* __restrict__ in,
                                                            unsigned char* __restrict__ out,
                                                            int R, int C) {
    __shared__ float tile[32][33];
    int c0 = blockIdx.x * 32, r0 = blockIdx.y * 32;
    int tx = threadIdx.x & 31, ty = threadIdx.x >> 5;
    #pragma unroll
    for (int i = 0; i < 32; i += 8) {
        int r = r0 + ty + i, c = c0 + tx;
        if (r < R && c < C) tile[ty + i][tx] = in[(size_t)r * C + c];
    }
    __syncthreads();
    #pragma unroll
    for (int i = 0; i < 32; i += 8) {
        int c = c0 + ty + i, r = r0 + tx;
        if (c < C && r < R) {
            __hip_fp8_e4m3 t(tile[tx][ty + i] * W2SCL);
            out[(size_t)c * R + r] = t.__x;
        }
    }
}

// ---------------- CSR build: histogram / scan / scatter ----------------
__global__ __launch_bounds__(256) void hist_kernel(const int* __restrict__ ei, int* __restrict__ deg) {
    int i = blockIdx.x * 256 + threadIdx.x;
    if (i >= ETOT) return;
    int dst = (i < NE) ? ei[NE + i] : (i - NE);
    atomicAdd(&deg[dst], 1);
}

__global__ __launch_bounds__(1024) void scan_kernel(const int* __restrict__ deg,
                                                    int* __restrict__ rowptr,
                                                    int* __restrict__ cursor) {
    __shared__ int buf[1024];
    int t = threadIdx.x;
    const int CH = (NN + 1023) >> 10;   // 20
    int base = t * CH;
    int s = 0;
    for (int j = 0; j < CH; ++j) { int idx = base + j; if (idx < NN) s += deg[idx]; }
    buf[t] = s;
    __syncthreads();
    for (int off = 1; off < 1024; off <<= 1) {
        int v = (t >= off) ? buf[t - off] : 0;
        __syncthreads();
        buf[t] += v;
        __syncthreads();
    }
    int run = buf[t] - s;   // exclusive
    for (int j = 0; j < CH; ++j) {
        int idx = base + j;
        if (idx < NN) { rowptr[idx] = run; cursor[idx] = run; run += deg[idx]; }
    }
    if (t == 1023) rowptr[NN] = buf[1023];
}

__global__ __launch_bounds__(256) void scatter_kernel(const int* __restrict__ ei,
                                                      int* __restrict__ cursor,
                                                      int* __restrict__ csr_src) {
    int i = blockIdx.x * 256 + threadIdx.x;
    if (i >= ETOT) return;
    int s, d;
    if (i < NE) { s = ei[i]; d = ei[NE + i]; } else { s = i - NE; d = i - NE; }
    int pos = atomicAdd(&cursor[d], 1);
    csr_src[pos] = s;
}

// ---------------- bf16 MFMA GEMM (layer 1), 192x256, 3-phase — round-13 proven ----------------
__global__ __launch_bounds__(512, 2) void gemm_192(const __hip_bfloat16* __restrict__ A,
                                                   const __hip_bfloat16* __restrict__ Bt,
                                                   unsigned char* __restrict__ C8,
                                                   const float* __restrict__ att_src,
                                                   const float* __restrict__ att_dst,
                                                   float* __restrict__ as_,
                                                   float* __restrict__ ad_,
                                                   int M, int N, int K) {
    __shared__ __align__(16) unsigned short lds[2][28672];  // per buf: A[192][64] | B[256][64]
    const int tid  = threadIdx.x;
    const int lane = tid & 63, wave = tid >> 6;
    const int wm = wave >> 2, wn = wave & 3;     // 2 x 4 wave grid; per-wave C: 96 x 64

    const int nbx = N >> 8;                      // 7
    const int nby = (M + 191) / 192;             // 105
    const int nwg = nbx * nby;                   // 735
    const int q = nwg >> 3, r = nwg & 7;
    const int xcd = blockIdx.x & 7, bidx = blockIdx.x >> 3;
    const int wg = (xcd < r ? xcd * (q + 1) : r * (q + 1) + (xcd - r) * q) + bidx;
    const int by = wg / nbx, bx = wg - by * nbx;
    const int m0 = by * 192, n0 = bx << 8;

    const int NT = K >> 6;                       // K-tiles of 64 (layer 1: 2)

    const int qq = lane >> 4, rr = lane & 15;

    auto stageA = [&](int kt, int b) {
        #pragma unroll
        for (int i = 0; i < 3; ++i) {
            int slot = i * 512 + tid;
            int row = slot >> 3, pch = slot & 7;
            int lc = pch ^ (row & 7);
            int gr = m0 + row; if (gr > M - 1) gr = M - 1;
            async_copy16(&lds[b][slot * 8], A + (size_t)gr * K + (kt << 6) + lc * 8);
        }
    };
    auto stageB = [&](int kt, int b) {
        #pragma unroll
        for (int i = 0; i < 4; ++i) {
            int slot = i * 512 + tid;
            int row = slot >> 3, pch = slot & 7;
            int lc = pch ^ (row & 7);
            async_copy16(&lds[b][12288 + slot * 8], Bt + (size_t)(n0 + row) * K + (kt << 6) + lc * 8);
        }
    };

    floatx4 zero = {0.f, 0.f, 0.f, 0.f};
    floatx4 acc[6][4];
    #pragma unroll
    for (int i = 0; i < 6; ++i)
        #pragma unroll
        for (int jj = 0; jj < 4; ++jj) acc[i][jj] = zero;

    bf16x8 aF[3][2], bA[2][2], bB[2][2];

    auto loadA = [&](int b, int mg) {
        #pragma unroll
        for (int mf = 0; mf < 3; ++mf)
            #pragma unroll
            for (int s = 0; s < 2; ++s) {
                int row = wm * 96 + mg * 48 + mf * 16 + rr;
                int pch = (s * 4 + qq) ^ (row & 7);
                aF[mf][s] = *(const bf16x8*)&lds[b][row * 64 + pch * 8];
            }
    };
    auto loadB = [&](int b, bf16x8 (&bF)[2][2], int ng) {
        #pragma unroll
        for (int nf = 0; nf < 2; ++nf)
            #pragma unroll
            for (int s = 0; s < 2; ++s) {
                int row = wn * 64 + (ng * 2 + nf) * 16 + rr;
                int pch = (s * 4 + qq) ^ (row & 7);
                bF[nf][s] = *(const bf16x8*)&lds[b][12288 + row * 64 + pch * 8];
            }
    };
    auto mfmaQ = [&](int mg, int ng, bf16x8 (&bF)[2][2]) {
        #pragma unroll
        for (int mf = 0; mf < 3; ++mf)
            #pragma unroll
            for (int nf = 0; nf < 2; ++nf)
                #pragma unroll
                for (int s = 0; s < 2; ++s)
                    acc[mg * 3 + mf][ng * 2 + nf] = __builtin_amdgcn_mfma_f32_16x16x32_bf16(
                        aF[mf][s], bF[nf][s], acc[mg * 3 + mf][ng * 2 + nf], 0, 0, 0);
    };

#define SB0 __builtin_amdgcn_sched_barrier(0)
#define GBAR do { SB0; __builtin_amdgcn_s_barrier(); SB0; } while (0)

    stageB(0, 0); stageA(0, 0);
    stageB(1, 1); stageA(1, 1);
    SB0;
    asm volatile("s_waitcnt vmcnt(7)" ::: "memory");
    GBAR;

    for (int t = 0; t < NT; ++t) {
        const int p = t & 1;
        int tp = t + 2; while (tp >= NT) tp -= 2;

        loadA(p, 0); loadB(p, bA, 0);
        GBAR;
        __builtin_amdgcn_s_setprio(1);
        mfmaQ(0, 0, bA);
        __builtin_amdgcn_s_setprio(0);
        GBAR;

        loadB(p, bB, 1);
        stageB(tp, p);
        GBAR;
        __builtin_amdgcn_s_setprio(1);
        mfmaQ(0, 1, bB);
        __builtin_amdgcn_s_setprio(0);
        GBAR;

        loadA(p, 1);
        stageA(tp, p);
        SB0;
        asm volatile("s_waitcnt vmcnt(7)" ::: "memory");
        GBAR;
        __builtin_amdgcn_s_setprio(1);
        mfmaQ(1, 1, bB);
        mfmaQ(1, 0, bA);
        __builtin_amdgcn_s_setprio(0);
        GBAR;
    }
#undef GBAR
#undef SB0

    // epilogue 1: fp8 quantize + store
    #pragma unroll
    for (int mt = 0; mt < 6; ++mt) {
        #pragma unroll
        for (int r4 = 0; r4 < 4; ++r4) {
            int rowc = m0 + wm * 96 + mt * 16 + (lane >> 4) * 4 + r4;
            if (rowc < M) {
                u32 word = enc_fp8x4(acc[mt][0][r4], acc[mt][1][r4], acc[mt][2][r4], acc[mt][3][r4]);
                unsigned char q8[4] = { (unsigned char)(word & 0xff), (unsigned char)((word >> 8) & 0xff),
                                        (unsigned char)((word >> 16) & 0xff), (unsigned char)(word >> 24) };
                #pragma unroll
                for (int nt = 0; nt < 4; ++nt) {
                    int col = n0 + wn * 64 + nt * 16 + (lane & 15);
                    C8[(size_t)rowc * N + col] = q8[nt];
                }
            }
        }
    }

    // epilogue 2: fused attention scores (DPP row-sum, round-13 proven)
    {
        const int li = lane & 15;
        const int h0 = bx * 8 + wn * 2;
        float ws00 = att_src[(h0)     * OC + li],      ws01 = att_src[(h0)     * OC + 16 + li];
        float ws10 = att_src[(h0 + 1) * OC + li],      ws11 = att_src[(h0 + 1) * OC + 16 + li];
        float wd00 = att_dst[(h0)     * OC + li],      wd01 = att_dst[(h0)     * OC + 16 + li];
        float wd10 = att_dst[(h0 + 1) * OC + li],      wd11 = att_dst[(h0 + 1) * OC + 16 + li];
        #pragma unroll
        for (int mt = 0; mt < 6; ++mt) {
            #pragma unroll
            for (int r4 = 0; r4 < 4; ++r4) {
                float s0 = dpp_add16(acc[mt][0][r4] * ws00 + acc[mt][1][r4] * ws01);
                float s1 = dpp_add16(acc[mt][2][r4] * ws10 + acc[mt][3][r4] * ws11);
                float d0 = dpp_add16(acc[mt][0][r4] * wd00 + acc[mt][1][r4] * wd01);
                float d1 = dpp_add16(acc[mt][2][r4] * wd10 + acc[mt][3][r4] * wd11);
                int rowc = m0 + wm * 96 + mt * 16 + (lane >> 4) * 4 + r4;
                if (li == 0 && rowc < M) {
                    as_[(size_t)rowc * NH + h0]     = s0;
                    as_[(size_t)rowc * NH + h0 + 1] = s1;
                    ad_[(size_t)rowc * NH + h0]     = d0;
                    ad_[(size_t)rowc * NH + h0 + 1] = d1;
                }
            }
        }
    }
}

// ---------------- fp8 MFMA GEMM (layer 2), 192x256, BK=128 — same skeleton, half LDS bytes ----------------
// Operands fp8 e4m3 (A = h1p, B = W2*16); mfma_f32_16x16x32_fp8_fp8 (same shape as bf16,
// 8B/lane fragments). K-tile = 128 fp8 = 128B rows: byte layout, staging slot counts
// (3A+4B loads/thread), XOR-chunk swizzle, 2x56KB LDS, 3-phase/vmcnt(7) all IDENTICAL
// to the proven bf16 kernel; NT halves (14), MFMA per phase doubles. LDS traffic per
// unit work halves -> attacks the measured LDS-bandwidth bound (round-7 model).
// Epilogue multiplies by 1/W2SCL (W2 pre-scaled into fp8 range).
__global__ __launch_bounds__(512, 2) void gemm_fp8(const unsigned char* __restrict__ A,
                                                   const unsigned char* __restrict__ Bt,
                                                   unsigned char* __restrict__ C8,
                                                   const float* __restrict__ att_src,
                                                   const float* __restrict__ att_dst,
                                                   float* __restrict__ as_,
                                                   float* __restrict__ ad_,
                                                   int M, int N, int K) {
    __shared__ __align__(16) unsigned char lds8[2][57344];  // per buf: A[192][128B] | B[256][128B]
    const int tid  = threadIdx.x;
    const int lane = tid & 63, wave = tid >> 6;
    const int wm = wave >> 2, wn = wave & 3;     // 2 x 4 wave grid; per-wave C: 96 x 64

    const int nbx = N >> 8;                      // 7
    const int nby = (M + 191) / 192;             // 105
    const int nwg = nbx * nby;                   // 735
    const int q = nwg >> 3, r = nwg & 7;
    const int xcd = blockIdx.x & 7, bidx = blockIdx.x >> 3;
    const int wg = (xcd < r ? xcd * (q + 1) : r * (q + 1) + (xcd - r) * q) + bidx;
    const int by = wg / nbx, bx = wg - by * nbx;
    const int m0 = by * 192, n0 = bx << 8;

    const int NT = K >> 7;                       // K-tiles of 128: 14

    const int qq = lane >> 4, rr = lane & 15;

    auto stageA = [&](int kt, int b) {           // 192 rows x 8 chunks = 1536 slots = 3/thread
        #pragma unroll
        for (int i = 0; i < 3; ++i) {
            int slot = i * 512 + tid;
            int row = slot >> 3, pch = slot & 7;
            int lc = pch ^ (row & 7);            // pre-swizzled global source (rule #21)
            int gr = m0 + row; if (gr > M - 1) gr = M - 1;
            async_copy16(&lds8[b][slot * 16], A + (size_t)gr * K + (kt << 7) + lc * 16);
        }
    };
    auto stageB = [&](int kt, int b) {           // 256 rows x 8 chunks = 2048 slots = 4/thread
        #pragma unroll
        for (int i = 0; i < 4; ++i) {
            int slot = i * 512 + tid;
            int row = slot >> 3, pch = slot & 7;
            int lc = pch ^ (row & 7);
            async_copy16(&lds8[b][24576 + slot * 16], Bt + (size_t)(n0 + row) * K + (kt << 7) + lc * 16);
        }
    };

    floatx4 zero = {0.f, 0.f, 0.f, 0.f};
    floatx4 acc[6][4];
    #pragma unroll
    for (int i = 0; i < 6; ++i)
        #pragma unroll
        for (int jj = 0; jj < 4; ++jj) acc[i][jj] = zero;

    long aF[3][4], bA[2][4], bB[2][4];

    // fragment for MFMA sub-K s (0..3): lane holds 8 fp8 at byte s*32 + qq*8 of the 128B row;
    // chunk = 2s + (qq>>1) (16B), inner = (qq&1)*8; chunk XOR'd with row&7 (staging swizzle).
    auto loadA = [&](int b, int mg) {
        #pragma unroll
        for (int mf = 0; mf < 3; ++mf)
            #pragma unroll
            for (int s = 0; s < 4; ++s) {
                int row = wm * 96 + mg * 48 + mf * 16 + rr;
                int ch = (2 * s + (qq >> 1)) ^ (row & 7);
                aF[mf][s] = *(const long*)&lds8[b][row * 128 + ch * 16 + (qq & 1) * 8];
            }
    };
    auto loadB = [&](int b, long (&bF)[2][4], int ng) {
        #pragma unroll
        for (int nf = 0; nf < 2; ++nf)
            #pragma unroll
            for (int s = 0; s < 4; ++s) {
                int row = wn * 64 + (ng * 2 + nf) * 16 + rr;
                int ch = (2 * s + (qq >> 1)) ^ (row & 7);
                bF[nf][s] = *(const long*)&lds8[b][24576 + row * 128 + ch * 16 + (qq & 1) * 8];
            }
    };
    auto mfmaQ = [&](int mg, int ng, long (&bF)[2][4]) {     // 24 MFMA quadrant (K=128)
        #pragma unroll
        for (int mf = 0; mf < 3; ++mf)
            #pragma unroll
            for (int nf = 0; nf < 2; ++nf)
                #pragma unroll
                for (int s = 0; s < 4; ++s)
                    acc[mg * 3 + mf][ng * 2 + nf] = __builtin_amdgcn_mfma_f32_16x16x32_fp8_fp8(
                        aF[mf][s], bF[nf][s], acc[mg * 3 + mf][ng * 2 + nf], 0, 0, 0);
    };

#define SB0 __builtin_amdgcn_sched_barrier(0)
#define GBAR do { SB0; __builtin_amdgcn_s_barrier(); SB0; } while (0)

    stageB(0, 0); stageA(0, 0);
    stageB(1, 1); stageA(1, 1);
    SB0;
    asm volatile("s_waitcnt vmcnt(7)" ::: "memory");
    GBAR;

    for (int t = 0; t < NT; ++t) {
        const int p = t & 1;
        int tp = t + 2; while (tp >= NT) tp -= 2;            // parity-preserving tail clamp

        loadA(p, 0); loadB(p, bA, 0);
        GBAR;
        __builtin_amdgcn_s_setprio(1);
        mfmaQ(0, 0, bA);
        __builtin_amdgcn_s_setprio(0);
        GBAR;

        loadB(p, bB, 1);
        stageB(tp, p);
        GBAR;
        __builtin_amdgcn_s_setprio(1);
        mfmaQ(0, 1, bB);
        __builtin_amdgcn_s_setprio(0);
        GBAR;

        loadA(p, 1);
        stageA(tp, p);
        SB0;
        asm volatile("s_waitcnt vmcnt(7)" ::: "memory");
        GBAR;
        __builtin_amdgcn_s_setprio(1);
        mfmaQ(1, 1, bB);
        mfmaQ(1, 0, bA);
        __builtin_amdgcn_s_setprio(0);
        GBAR;
    }
#undef GBAR
#undef SB0

    const float scl = 1.0f / W2SCL;

    // epilogue 1: unscale + fp8 quantize + store
    #pragma unroll
    for (int mt = 0; mt < 6; ++mt) {
        #pragma unroll
        for (int r4 = 0; r4 < 4; ++r4) {
            int rowc = m0 + wm * 96 + mt * 16 + (lane >> 4) * 4 + r4;
            if (rowc < M) {
                u32 word = enc_fp8x4(acc[mt][0][r4] * scl, acc[mt][1][r4] * scl,
                                     acc[mt][2][r4] * scl, acc[mt][3][r4] * scl);
                unsigned char q8[4] = { (unsigned char)(word & 0xff), (unsigned char)((word >> 8) & 0xff),
                                        (unsigned char)((word >> 16) & 0xff), (unsigned char)(word >> 24) };
                #pragma unroll
                for (int nt = 0; nt < 4; ++nt) {
                    int col = n0 + wn * 64 + nt * 16 + (lane & 15);
                    C8[(size_t)rowc * N + col] = q8[nt];
                }
            }
        }
    }

    // epilogue 2: fused attention scores (scale folded into the att weights)
    {
        const int li = lane & 15;
        const int h0 = bx * 8 + wn * 2;
        float ws00 = att_src[(h0)     * OC + li] * scl,  ws01 = att_src[(h0)     * OC + 16 + li] * scl;
        float ws10 = att_src[(h0 + 1) * OC + li] * scl,  ws11 = att_src[(h0 + 1) * OC + 16 + li] * scl;
        float wd00 = att_dst[(h0)     * OC + li] * scl,  wd01 = att_dst[(h0)     * OC + 16 + li] * scl;
        float wd10 = att_dst[(h0 + 1) * OC + li] * scl,  wd11 = att_dst[(h0 + 1) * OC + 16 + li] * scl;
        #pragma unroll
        for (int mt = 0; mt < 6; ++mt) {
            #pragma unroll
            for (int r4 = 0; r4 < 4; ++r4) {
                float s0 = dpp_add16(acc[mt][0][r4] * ws00 + acc[mt][1][r4] * ws01);
                float s1 = dpp_add16(acc[mt][2][r4] * ws10 + acc[mt][3][r4] * ws11);
                float d0 = dpp_add16(acc[mt][0][r4] * wd00 + acc[mt][1][r4] * wd01);
                float d1 = dpp_add16(acc[mt][2][r4] * wd10 + acc[mt][3][r4] * wd11);
                int rowc = m0 + wm * 96 + mt * 16 + (lane >> 4) * 4 + r4;
                if (li == 0 && rowc < M) {
                    as_[(size_t)rowc * NH + h0]     = s0;
                    as_[(size_t)rowc * NH + h0 + 1] = s1;
                    ad_[(size_t)rowc * NH + h0]     = d0;
                    ad_[(size_t)rowc * NH + h0 + 1] = d1;
                }
            }
        }
    }
}

// ---------------- node-boundary flush for the fused streaming aggregate ----------------
// LAYER==1: FP8 h1p[cur][slice] = fp8(BN1(ELU(acc/den + b1)))  (feeds gemm_fp8's A)
// LAYER==2: head-reduce in-wave, write per-slice partial to h2part[cur][f][32]
template <int LAYER>
__device__ __forceinline__ void flush_node(float* acc, float den, int cur, int f, int lane,
                                           const float* __restrict__ bias,
                                           const float* __restrict__ bng,
                                           const float* __restrict__ bnb,
                                           const float* __restrict__ bnm,
                                           const float* __restrict__ bnv,
                                           void* __restrict__ outp) {
    float inv = 1.f / den;
    #pragma unroll
    for (int k = 0; k < 4; ++k) acc[k] *= inv;

    if constexpr (LAYER == 1) {
        int d0 = f * 256 + lane * 4;
        float v0 = acc[0] + bias[d0 + 0];
        float v1 = acc[1] + bias[d0 + 1];
        float v2 = acc[2] + bias[d0 + 2];
        float v3 = acc[3] + bias[d0 + 3];
        v0 = v0 > 0.f ? v0 : expm1f(v0);
        v1 = v1 > 0.f ? v1 : expm1f(v1);
        v2 = v2 > 0.f ? v2 : expm1f(v2);
        v3 = v3 > 0.f ? v3 : expm1f(v3);
        v0 = (v0 - bnm[d0 + 0]) * rsqrtf(bnv[d0 + 0] + EPS_BN) * bng[d0 + 0] + bnb[d0 + 0];
        v1 = (v1 - bnm[d0 + 1]) * rsqrtf(bnv[d0 + 1] + EPS_BN) * bng[d0 + 1] + bnb[d0 + 1];
        v2 = (v2 - bnm[d0 + 2]) * rsqrtf(bnv[d0 + 2] + EPS_BN) * bng[d0 + 2] + bnb[d0 + 2];
        v3 = (v3 - bnm[d0 + 3]) * rsqrtf(bnv[d0 + 3] + EPS_BN) * bng[d0 + 3] + bnb[d0 + 3];
        u32 word = enc_fp8x4(v0, v1, v2, v3);
        *(u32*)((unsigned char*)outp + (size_t)cur * DD1 + d0) = word;
    } else {
        #pragma unroll
        for (int k = 0; k < 4; ++k) {
            acc[k] += __shfl_xor(acc[k], 8, 64);
            acc[k] += __shfl_xor(acc[k], 16, 64);
            acc[k] += __shfl_xor(acc[k], 32, 64);
        }
        if (lane < 8) {
            floatx4 pk;
            #pragma unroll
            for (int k = 0; k < 4; ++k) pk[k] = acc[k] * (1.f / NH);
            *(floatx4*)((float*)outp + ((size_t)cur * 7 + f) * OC + lane * 4) = pk;
        }
    }
    acc[0] = acc[1] = acc[2] = acc[3] = 0.f;
}

// ---------------- fused streaming aggregation with ONLINE SOFTMAX (round-5 proven) ----------------
template <int LAYER>
__global__ __launch_bounds__(256) void attn_aggregate(const int* __restrict__ rowptr,
                                                      const int* __restrict__ csr_src,
                                                      const float* __restrict__ as_,
                                                      const float* __restrict__ ad_,
                                                      const unsigned char* __restrict__ h8,
                                                      const float* __restrict__ bias,
                                                      const float* __restrict__ bng,
                                                      const float* __restrict__ bnb,
                                                      const float* __restrict__ bnm,
                                                      const float* __restrict__ bnv,
                                                      void* __restrict__ outp) {
    const int wv = threadIdx.x >> 6, lane = threadIdx.x & 63;
    const int w = blockIdx.x * 4 + wv;
    const int NWAVES = 7 * (NN / GRP);
    if (w >= NWAVES) return;
    const int f  = w % 7;             // feature slice (256 B of the 1792-B row)
    const int g  = w / 7;             // node group
    const int n0 = g * GRP;
    const int off  = f * 256 + lane * 4;
    const int head = f * 8 + (lane >> 3);

    const int e0 = rowptr[n0], e1 = rowptr[n0 + GRP];
    int cur = n0;
    int bound = rowptr[n0 + 1];
    float adv = ad_[(size_t)cur * NH + head];

    float acc[4] = {0.f, 0.f, 0.f, 0.f};
    float m = -1e30f, den = 0.f;

    for (int e = e0; e < e1; e += EB) {
        u32   hv[EB];
        float sv[EB];
        #pragma unroll
        for (int i = 0; i < EB; ++i) {
            int idx = (e + i < e1) ? e + i : e1 - 1;
            int s = csr_src[idx];
            hv[i] = *(const u32*)(h8 + (size_t)s * DD1 + off);
            sv[i] = as_[(size_t)s * NH + head];
        }
        #pragma unroll
        for (int i = 0; i < EB; ++i) {
            if (e + i >= e1) break;
            if (e + i >= bound) {
                flush_node<LAYER>(acc, den, cur, f, lane, bias, bng, bnb, bnm, bnv, outp);
                ++cur;
                bound = rowptr[cur + 1];
                adv = ad_[(size_t)cur * NH + head];
                m = -1e30f; den = 0.f;
            }
            float lr = sv[i] + adv;
            lr = lr > 0.f ? lr : 0.2f * lr;
            float wgt;
            if (lr > m) {
                float scale = __expf(m - lr);
                den = den * scale + 1.f;
                #pragma unroll
                for (int k = 0; k < 4; ++k) acc[k] *= scale;
                m = lr;
                wgt = 1.f;
            } else {
                wgt = __expf(lr - m);
                den += wgt;
            }
            fma_fp8x4(hv[i], wgt, acc);
        }
    }
    flush_node<LAYER>(acc, den, cur, f, lane, bias, bng, bnb, bnm, bnv, outp);
}

// ---------------- mean pool: sorted-batch segmented reduction, minimal atomics ----------------
__global__ __launch_bounds__(256) void pool_kernel(const float* __restrict__ h2part,
                                                   const int* __restrict__ batch,
                                                   float* __restrict__ sums,
                                                   float* __restrict__ cnt) {
    __shared__ float red[4][OC];
    const int g = blockIdx.x >> 3, c = blockIdx.x & 7;
    const int t = threadIdx.x;
    const int ch = t & 31, nl = t >> 5;
    int lo = 0, hi = NN;
    while (lo < hi) { int mid = (lo + hi) >> 1; if (batch[mid] < g) lo = mid + 1; else hi = mid; }
    const int s = lo;
    hi = NN;
    while (lo < hi) { int mid = (lo + hi) >> 1; if (batch[mid] <= g) lo = mid + 1; else hi = mid; }
    const int e = lo;
    const int len = e - s;
    const int n0 = s + (len * c) / 8;
    const int n1 = s + (len * (c + 1)) / 8;
    float acc = 0.f;
    for (int n = n0 + nl; n < n1; n += 8) {
        const float* p = h2part + (size_t)n * 7 * OC + ch;
        float a = 0.f;
        #pragma unroll
        for (int f = 0; f < 7; ++f) a += p[f * OC];
        acc += a;
    }
    acc += __shfl_xor(acc, 32, 64);
    if ((t & 32) == 0) red[t >> 6][ch] = acc;
    __syncthreads();
    if (t < OC) {
        float total = red[0][t] + red[1][t] + red[2][t] + red[3][t];
        atomicAdd(&sums[g * OC + t], total);
    }
    if (t == 0 && c == 0) cnt[g] = (float)len;
}

// final: pooled = sums/cnt; v = BN2(pooled + b2); out = v @ lin_w + lin_b
__global__ __launch_bounds__(128) void final_kernel(const float* __restrict__ sums,
                                                    const float* __restrict__ cnt,
                                                    const float* __restrict__ b2,
                                                    const float* __restrict__ bn2g,
                                                    const float* __restrict__ bn2b,
                                                    const float* __restrict__ bn2m,
                                                    const float* __restrict__ bn2v,
                                                    const float* __restrict__ lin_w,
                                                    const float* __restrict__ lin_b,
                                                    float* __restrict__ out) {
    int t = threadIdx.x;
    if (t >= NG * 2) return;
    int g = t >> 1, c = t & 1;
    float invc = 1.f / fmaxf(cnt[g], 1.f);
    float acc = lin_b[c];
    #pragma unroll
    for (int o = 0; o < OC; ++o) {
        float pooled = sums[g * OC + o] * invc + b2[o];
        float v = (pooled - bn2m[o]) * rsqrtf(bn2v[o] + EPS_BN) * bn2g[o] + bn2b[o];
        acc += v * lin_w[o * 2 + c];
    }
    out[t] = acc;
}

// ---------------- host-side launch ----------------
extern "C" void kernel_launch(void* const* d_in, const int* in_sizes, int n_in,
                              void* d_out, int out_size, void* d_ws, size_t ws_size,
                              hipStream_t stream) {
    const float* x    = (const float*)d_in[0];
    const int*   ei   = (const int*)d_in[1];
    const int*   bat  = (const int*)d_in[2];
    const float* W1   = (const float*)d_in[3];
    const float* at_s1 = (const float*)d_in[4];
    const float* at_d1 = (const float*)d_in[5];
    const float* b1   = (const float*)d_in[6];
    const float* bn1g = (const float*)d_in[7];
    const float* bn1b = (const float*)d_in[8];
    const float* bn1m = (const float*)d_in[9];
    const float* bn1v = (const float*)d_in[10];
    const float* W2   = (const float*)d_in[11];
    const float* at_s2 = (const float*)d_in[12];
    const float* at_d2 = (const float*)d_in[13];
    const float* b2   = (const float*)d_in[14];
    const float* bn2g = (const float*)d_in[15];
    const float* bn2b = (const float*)d_in[16];
    const float* bn2m = (const float*)d_in[17];
    const float* bn2v = (const float*)d_in[18];
    const float* linw = (const float*)d_in[19];
    const float* linb = (const float*)d_in[20];
    float* out = (float*)d_out;

    char* wsp = (char*)d_ws;
    auto alloc = [&](size_t bytes) -> void* {
        void* p = (void*)wsp;
        wsp += (bytes + 255) & ~(size_t)255;
        return p;
    };
    unsigned char*  h8   = (unsigned char*)alloc((size_t)NN * DD1);     // fp8 gemm output
    unsigned char*  h1p  = (unsigned char*)alloc((size_t)NN * DD1);     // agg1 out, FP8 (gemm_fp8 A)
    __hip_bfloat16* xb   = (__hip_bfloat16*)alloc((size_t)NN * NF * 2);
    __hip_bfloat16* w1t  = (__hip_bfloat16*)alloc((size_t)DD1 * NF * 2);
    unsigned char*  w2t8 = (unsigned char*)alloc((size_t)DD1 * DD1);    // W2^T * 16, fp8
    float* asb   = (float*)alloc((size_t)NN * NH * 4);
    float* adb   = (float*)alloc((size_t)NN * NH * 4);
    int*   deg   = (int*)alloc((size_t)NN * 4);
    int*   rowp  = (int*)alloc((size_t)(NN + 1) * 4);
    int*   curs  = (int*)alloc((size_t)NN * 4);
    int*   csr   = (int*)alloc((size_t)ETOT * 4);
    float* h2part = (float*)alloc((size_t)NN * 7 * OC * 4);
    float* sums  = (float*)alloc((size_t)(NG * OC + NG) * 4);
    float* cnt   = sums + NG * OC;

    hipMemsetAsync(deg, 0, (size_t)NN * 4, stream);
    hipMemsetAsync(sums, 0, (size_t)(NG * OC + NG) * 4, stream);

    cast_bf16_kernel<<<(NN * NF + 255) / 256, 256, 0, stream>>>(x, xb, NN * NF);
    transpose_cast_kernel<<<dim3(DD1 / 32, NF / 32), 256, 0, stream>>>(W1, w1t, NF, DD1);
    transpose_fp8_kernel<<<dim3(DD1 / 32, DD1 / 32), 256, 0, stream>>>(W2, w2t8, DD1, DD1);
    hist_kernel<<<(ETOT + 255) / 256, 256, 0, stream>>>(ei, deg);
    scan_kernel<<<1, 1024, 0, stream>>>(deg, rowp, curs);
    scatter_kernel<<<(ETOT + 255) / 256, 256, 0, stream>>>(ei, curs, csr);

    const int AGG_BLOCKS = (7 * (NN / GRP) + 3) / 4;
    const int NBY192 = (NN + 191) / 192;                   // 105
    const int GEMM_BLOCKS = NBY192 * (DD1 / 256);          // 735

    // layer 1 (bf16 gemm, fused scores)
    gemm_192<<<GEMM_BLOCKS, 512, 0, stream>>>(xb, w1t, h8, at_s1, at_d1, asb, adb, NN, DD1, NF);
    attn_aggregate<1><<<AGG_BLOCKS, 256, 0, stream>>>(rowp, csr, asb, adb, h8, b1, bn1g, bn1b, bn1m, bn1v, (void*)h1p);

    // layer 2 (fp8 gemm, fused scores)
    gemm_fp8<<<GEMM_BLOCKS, 512, 0, stream>>>(h1p, w2t8, h8, at_s2, at_d2, asb, adb, NN, DD1, DD1);
    attn_aggregate<2><<<AGG_BLOCKS, 256, 0, stream>>>(rowp, csr, asb, adb, h8, b2, bn2g, bn2b, bn2m, bn2v, (void*)h2part);

    pool_kernel<<<NG * 8, 256, 0, stream>>>(h2part, bat, sums, cnt);
    final_kernel<<<1, 128, 0, stream>>>(sums, cnt, b2, bn2g, bn2b, bn2m, bn2v, linw, linb, out);
}

// Round 15
// 508.145 us; speedup vs baseline: 1.2497x; 1.0188x over previous
//
#include <hip/hip_runtime.h>
#include <hip/hip_bf16.h>
#include <hip/hip_fp8.h>
#include <cstdint>
#include <cstddef>

// Problem constants
#define NN     20000     // nodes
#define NF     128       // in features
#define NH     56        // heads
#define OC     32        // out channels per head
#define DD1    1792      // NH*OC
#define NE     100000    // edges (before self loops)
#define ETOT   120000    // edges + self loops
#define NG     50        // graphs
#define EPS_BN 1e-5f
#define GRP    16        // nodes per wave in aggregate
#define EB     16        // edge batch (round-5 proven single-buffer)
#define W2SCL  16.0f     // W2 pre-scale (fp8 range); epilogue multiplies by 1/W2SCL

typedef __bf16 bf16x8 __attribute__((ext_vector_type(8)));
typedef float  floatx4 __attribute__((ext_vector_type(4)));
typedef float  floatx2 __attribute__((ext_vector_type(2)));
typedef long   longx2  __attribute__((ext_vector_type(2)));
typedef unsigned int u32;
typedef __attribute__((address_space(1))) u32 gu32;
typedef __attribute__((address_space(3))) u32 lu32;

__device__ __forceinline__ void async_copy16(void* lds, const void* g) {
    __builtin_amdgcn_global_load_lds((gu32*)const_cast<void*>(g), (lu32*)lds, 16, 0, 0);
}

// decode 4 fp8 (e4m3, packed in u32) to 4 floats (HW cvt when available)
__device__ __forceinline__ void dec_fp8x4(u32 u, float* v) {
#if __has_builtin(__builtin_amdgcn_cvt_pk_f32_fp8)
    floatx2 lo = __builtin_amdgcn_cvt_pk_f32_fp8(u, false);
    floatx2 hi = __builtin_amdgcn_cvt_pk_f32_fp8(u, true);
    v[0] = lo[0]; v[1] = lo[1]; v[2] = hi[0]; v[3] = hi[1];
#else
    #pragma unroll
    for (int b = 0; b < 4; ++b) {
        __hip_fp8_e4m3 t;
        t.__x = (u >> (8 * b)) & 0xff;
        v[b] = (float)t;
    }
#endif
}

__device__ __forceinline__ u32 enc_fp8x4(float v0, float v1, float v2, float v3) {
#if __has_builtin(__builtin_amdgcn_cvt_pk_fp8_f32)
    u32 p01 = (u32)__builtin_amdgcn_cvt_pk_fp8_f32(v0, v1, 0, false);
    u32 p23 = (u32)__builtin_amdgcn_cvt_pk_fp8_f32(v2, v3, 0, false);
    return (p01 & 0xffff) | (p23 << 16);
#else
    __hip_fp8_e4m3 t0(v0), t1(v1), t2(v2), t3(v3);
    return (u32)t0.__x | ((u32)t1.__x << 8) | ((u32)t2.__x << 16) | ((u32)t3.__x << 24);
#endif
}

__device__ __forceinline__ void fma_fp8x4(u32 u, float a, float* acc) {
    float v[4];
    dec_fp8x4(u, v);
    #pragma unroll
    for (int b = 0; b < 4; ++b) acc[b] += a * v[b];
}

// ---- 16-lane row sum via DPP (VALU pipe, NO LDS traffic; round-13 proven) ----
template <int CTRL>
__device__ __forceinline__ float dpp_row_add(float x) {
    int v = __builtin_amdgcn_mov_dpp(__float_as_int(x), CTRL, 0xf, 0xf, true);
    return x + __int_as_float(v);
}
__device__ __forceinline__ float dpp_add16(float x) {
    x = dpp_row_add<0x128>(x);   // row_ror:8
    x = dpp_row_add<0x124>(x);   // row_ror:4
    x = dpp_row_add<78>(x);      // quad_perm [2,3,0,1] = xor2
    x = dpp_row_add<177>(x);     // quad_perm [1,0,3,2] = xor1
    return x;
}

// ---------------- elementwise cast fp32 -> bf16 ----------------
__global__ __launch_bounds__(256) void cast_bf16_kernel(const float* __restrict__ in,
                                                        __hip_bfloat16* __restrict__ out, int n) {
    int i = blockIdx.x * 256 + threadIdx.x;
    if (i < n) out[i] = __float2bfloat16(in[i]);
}

// ---------------- tiled transpose + cast: in[R][C] f32 -> out[C][R] bf16 ----------------
__global__ __launch_bounds__(256) void transpose_cast_kernel(const float* __restrict__ in,
                                                             __hip_bfloat16* __restrict__ out,
                                                             int R, int C) {
    __shared__ float tile[32][33];
    int c0 = blockIdx.x * 32, r0 = blockIdx.y * 32;
    int tx = threadIdx.x & 31, ty = threadIdx.x >> 5;   // ty in 0..7
    #pragma unroll
    for (int i = 0; i < 32; i += 8) {
        int r = r0 + ty + i, c = c0 + tx;
        if (r < R && c < C) tile[ty + i][tx] = in[(size_t)r * C + c];
    }
    __syncthreads();
    #pragma unroll
    for (int i = 0; i < 32; i += 8) {
        int c = c0 + ty + i, r = r0 + tx;
        if (c < C && r < R) out[(size_t)c * R + r] = __float2bfloat16(tile[tx][ty + i]);
    }
}

// ---------------- tiled transpose + fp8 cast with W2SCL pre-scale ----------------
__global__ __launch_bounds__(256) void transpose_fp8_kernel(const float* __restrict__ in,
                                                            unsigned char* __restrict__ out,
                                                            int R, int C) {
    __shared__ float tile[32][33];
    int c0 = blockIdx.x * 32, r0 = blockIdx.y * 32;
    int tx = threadIdx.x & 31, ty = threadIdx.x >> 5;
    #pragma unroll
    for (int i = 0; i < 32; i += 8) {
        int r = r0 + ty + i, c = c0 + tx;
        if (r < R && c < C) tile[ty + i][tx] = in[(size_t)r * C + c];
    }
    __syncthreads();
    #pragma unroll
    for (int i = 0; i < 32; i += 8) {
        int c = c0 + ty + i, r = r0 + tx;
        if (c < C && r < R) {
            __hip_fp8_e4m3 t(tile[tx][ty + i] * W2SCL);
            out[(size_t)c * R + r] = t.__x;
        }
    }
}

// ---------------- CSR build: histogram / scan / scatter ----------------
__global__ __launch_bounds__(256) void hist_kernel(const int* __restrict__ ei, int* __restrict__ deg) {
    int i = blockIdx.x * 256 + threadIdx.x;
    if (i >= ETOT) return;
    int dst = (i < NE) ? ei[NE + i] : (i - NE);
    atomicAdd(&deg[dst], 1);
}

__global__ __launch_bounds__(1024) void scan_kernel(const int* __restrict__ deg,
                                                    int* __restrict__ rowptr,
                                                    int* __restrict__ cursor) {
    __shared__ int buf[1024];
    int t = threadIdx.x;
    const int CH = (NN + 1023) >> 10;   // 20
    int base = t * CH;
    int s = 0;
    for (int j = 0; j < CH; ++j) { int idx = base + j; if (idx < NN) s += deg[idx]; }
    buf[t] = s;
    __syncthreads();
    for (int off = 1; off < 1024; off <<= 1) {
        int v = (t >= off) ? buf[t - off] : 0;
        __syncthreads();
        buf[t] += v;
        __syncthreads();
    }
    int run = buf[t] - s;   // exclusive
    for (int j = 0; j < CH; ++j) {
        int idx = base + j;
        if (idx < NN) { rowptr[idx] = run; cursor[idx] = run; run += deg[idx]; }
    }
    if (t == 1023) rowptr[NN] = buf[1023];
}

__global__ __launch_bounds__(256) void scatter_kernel(const int* __restrict__ ei,
                                                      int* __restrict__ cursor,
                                                      int* __restrict__ csr_src) {
    int i = blockIdx.x * 256 + threadIdx.x;
    if (i >= ETOT) return;
    int s, d;
    if (i < NE) { s = ei[i]; d = ei[NE + i]; } else { s = i - NE; d = i - NE; }
    int pos = atomicAdd(&cursor[d], 1);
    csr_src[pos] = s;
}

// ---------------- bf16 MFMA GEMM (layer 1), 192x256, 3-phase — round-13 proven ----------------
__global__ __launch_bounds__(512, 2) void gemm_192(const __hip_bfloat16* __restrict__ A,
                                                   const __hip_bfloat16* __restrict__ Bt,
                                                   unsigned char* __restrict__ C8,
                                                   const float* __restrict__ att_src,
                                                   const float* __restrict__ att_dst,
                                                   float* __restrict__ as_,
                                                   float* __restrict__ ad_,
                                                   int M, int N, int K) {
    __shared__ __align__(16) unsigned short lds[2][28672];  // per buf: A[192][64] | B[256][64]
    const int tid  = threadIdx.x;
    const int lane = tid & 63, wave = tid >> 6;
    const int wm = wave >> 2, wn = wave & 3;     // 2 x 4 wave grid; per-wave C: 96 x 64

    const int nbx = N >> 8;                      // 7
    const int nby = (M + 191) / 192;             // 105
    const int nwg = nbx * nby;                   // 735
    const int q = nwg >> 3, r = nwg & 7;
    const int xcd = blockIdx.x & 7, bidx = blockIdx.x >> 3;
    const int wg = (xcd < r ? xcd * (q + 1) : r * (q + 1) + (xcd - r) * q) + bidx;
    const int by = wg / nbx, bx = wg - by * nbx;
    const int m0 = by * 192, n0 = bx << 8;

    const int NT = K >> 6;                       // K-tiles of 64 (layer 1: 2)

    const int qq = lane >> 4, rr = lane & 15;

    auto stageA = [&](int kt, int b) {
        #pragma unroll
        for (int i = 0; i < 3; ++i) {
            int slot = i * 512 + tid;
            int row = slot >> 3, pch = slot & 7;
            int lc = pch ^ (row & 7);
            int gr = m0 + row; if (gr > M - 1) gr = M - 1;
            async_copy16(&lds[b][slot * 8], A + (size_t)gr * K + (kt << 6) + lc * 8);
        }
    };
    auto stageB = [&](int kt, int b) {
        #pragma unroll
        for (int i = 0; i < 4; ++i) {
            int slot = i * 512 + tid;
            int row = slot >> 3, pch = slot & 7;
            int lc = pch ^ (row & 7);
            async_copy16(&lds[b][12288 + slot * 8], Bt + (size_t)(n0 + row) * K + (kt << 6) + lc * 8);
        }
    };

    floatx4 zero = {0.f, 0.f, 0.f, 0.f};
    floatx4 acc[6][4];
    #pragma unroll
    for (int i = 0; i < 6; ++i)
        #pragma unroll
        for (int jj = 0; jj < 4; ++jj) acc[i][jj] = zero;

    bf16x8 aF[3][2], bA[2][2], bB[2][2];

    auto loadA = [&](int b, int mg) {
        #pragma unroll
        for (int mf = 0; mf < 3; ++mf)
            #pragma unroll
            for (int s = 0; s < 2; ++s) {
                int row = wm * 96 + mg * 48 + mf * 16 + rr;
                int pch = (s * 4 + qq) ^ (row & 7);
                aF[mf][s] = *(const bf16x8*)&lds[b][row * 64 + pch * 8];
            }
    };
    auto loadB = [&](int b, bf16x8 (&bF)[2][2], int ng) {
        #pragma unroll
        for (int nf = 0; nf < 2; ++nf)
            #pragma unroll
            for (int s = 0; s < 2; ++s) {
                int row = wn * 64 + (ng * 2 + nf) * 16 + rr;
                int pch = (s * 4 + qq) ^ (row & 7);
                bF[nf][s] = *(const bf16x8*)&lds[b][12288 + row * 64 + pch * 8];
            }
    };
    auto mfmaQ = [&](int mg, int ng, bf16x8 (&bF)[2][2]) {
        #pragma unroll
        for (int mf = 0; mf < 3; ++mf)
            #pragma unroll
            for (int nf = 0; nf < 2; ++nf)
                #pragma unroll
                for (int s = 0; s < 2; ++s)
                    acc[mg * 3 + mf][ng * 2 + nf] = __builtin_amdgcn_mfma_f32_16x16x32_bf16(
                        aF[mf][s], bF[nf][s], acc[mg * 3 + mf][ng * 2 + nf], 0, 0, 0);
    };

#define SB0 __builtin_amdgcn_sched_barrier(0)
#define GBAR do { SB0; __builtin_amdgcn_s_barrier(); SB0; } while (0)

    stageB(0, 0); stageA(0, 0);
    stageB(1, 1); stageA(1, 1);
    SB0;
    asm volatile("s_waitcnt vmcnt(7)" ::: "memory");
    GBAR;

    for (int t = 0; t < NT; ++t) {
        const int p = t & 1;
        int tp = t + 2; while (tp >= NT) tp -= 2;

        loadA(p, 0); loadB(p, bA, 0);
        GBAR;
        __builtin_amdgcn_s_setprio(1);
        mfmaQ(0, 0, bA);
        __builtin_amdgcn_s_setprio(0);
        GBAR;

        loadB(p, bB, 1);
        stageB(tp, p);
        GBAR;
        __builtin_amdgcn_s_setprio(1);
        mfmaQ(0, 1, bB);
        __builtin_amdgcn_s_setprio(0);
        GBAR;

        loadA(p, 1);
        stageA(tp, p);
        SB0;
        asm volatile("s_waitcnt vmcnt(7)" ::: "memory");
        GBAR;
        __builtin_amdgcn_s_setprio(1);
        mfmaQ(1, 1, bB);
        mfmaQ(1, 0, bA);
        __builtin_amdgcn_s_setprio(0);
        GBAR;
    }
#undef GBAR
#undef SB0

    // epilogue 1: fp8 quantize + store
    #pragma unroll
    for (int mt = 0; mt < 6; ++mt) {
        #pragma unroll
        for (int r4 = 0; r4 < 4; ++r4) {
            int rowc = m0 + wm * 96 + mt * 16 + (lane >> 4) * 4 + r4;
            if (rowc < M) {
                u32 word = enc_fp8x4(acc[mt][0][r4], acc[mt][1][r4], acc[mt][2][r4], acc[mt][3][r4]);
                unsigned char q8[4] = { (unsigned char)(word & 0xff), (unsigned char)((word >> 8) & 0xff),
                                        (unsigned char)((word >> 16) & 0xff), (unsigned char)(word >> 24) };
                #pragma unroll
                for (int nt = 0; nt < 4; ++nt) {
                    int col = n0 + wn * 64 + nt * 16 + (lane & 15);
                    C8[(size_t)rowc * N + col] = q8[nt];
                }
            }
        }
    }

    // epilogue 2: fused attention scores (DPP row-sum, round-13 proven)
    {
        const int li = lane & 15;
        const int h0 = bx * 8 + wn * 2;
        float ws00 = att_src[(h0)     * OC + li],      ws01 = att_src[(h0)     * OC + 16 + li];
        float ws10 = att_src[(h0 + 1) * OC + li],      ws11 = att_src[(h0 + 1) * OC + 16 + li];
        float wd00 = att_dst[(h0)     * OC + li],      wd01 = att_dst[(h0)     * OC + 16 + li];
        float wd10 = att_dst[(h0 + 1) * OC + li],      wd11 = att_dst[(h0 + 1) * OC + 16 + li];
        #pragma unroll
        for (int mt = 0; mt < 6; ++mt) {
            #pragma unroll
            for (int r4 = 0; r4 < 4; ++r4) {
                float s0 = dpp_add16(acc[mt][0][r4] * ws00 + acc[mt][1][r4] * ws01);
                float s1 = dpp_add16(acc[mt][2][r4] * ws10 + acc[mt][3][r4] * ws11);
                float d0 = dpp_add16(acc[mt][0][r4] * wd00 + acc[mt][1][r4] * wd01);
                float d1 = dpp_add16(acc[mt][2][r4] * wd10 + acc[mt][3][r4] * wd11);
                int rowc = m0 + wm * 96 + mt * 16 + (lane >> 4) * 4 + r4;
                if (li == 0 && rowc < M) {
                    as_[(size_t)rowc * NH + h0]     = s0;
                    as_[(size_t)rowc * NH + h0 + 1] = s1;
                    ad_[(size_t)rowc * NH + h0]     = d0;
                    ad_[(size_t)rowc * NH + h0 + 1] = d1;
                }
            }
        }
    }
}

// ---------------- fp8 MFMA GEMM (layer 2), 192x256, BK=128 — b128 k-permuted reads ----------------
// Round-14 used b64 reads with chunk (2s+(qq>>1))^(row&7): quarter-waves collided on
// bank sets -> SQ_LDS_BANK_CONFLICT=1.185e7 (~19us). Fix: MFMA k-matching is POSITIONAL,
// so define sub-slice (j,half): lane qq supplies k = qq*32 + j*16 + half*8 + b for BOTH
// A and B. Lane's two fragments for (j,0)/(j,1) are 16 contiguous LDS bytes at chunk
// qq*2+j -> ONE b128 read, chunk index (qq*2+j)^(row&7) spanning all 8 chunks per
// 8-lane row group — structurally identical to the bf16 kernel's measured-0 pattern.
// Union over (qq,j,half,b) covers k=0..127 exactly once; A/B share the formula.
__global__ __launch_bounds__(512, 2) void gemm_fp8(const unsigned char* __restrict__ A,
                                                   const unsigned char* __restrict__ Bt,
                                                   unsigned char* __restrict__ C8,
                                                   const float* __restrict__ att_src,
                                                   const float* __restrict__ att_dst,
                                                   float* __restrict__ as_,
                                                   float* __restrict__ ad_,
                                                   int M, int N, int K) {
    __shared__ __align__(16) unsigned char lds8[2][57344];  // per buf: A[192][128B] | B[256][128B]
    const int tid  = threadIdx.x;
    const int lane = tid & 63, wave = tid >> 6;
    const int wm = wave >> 2, wn = wave & 3;     // 2 x 4 wave grid; per-wave C: 96 x 64

    const int nbx = N >> 8;                      // 7
    const int nby = (M + 191) / 192;             // 105
    const int nwg = nbx * nby;                   // 735
    const int q = nwg >> 3, r = nwg & 7;
    const int xcd = blockIdx.x & 7, bidx = blockIdx.x >> 3;
    const int wg = (xcd < r ? xcd * (q + 1) : r * (q + 1) + (xcd - r) * q) + bidx;
    const int by = wg / nbx, bx = wg - by * nbx;
    const int m0 = by * 192, n0 = bx << 8;

    const int NT = K >> 7;                       // K-tiles of 128: 14

    const int qq = lane >> 4, rr = lane & 15;

    auto stageA = [&](int kt, int b) {           // 192 rows x 8 chunks = 1536 slots = 3/thread
        #pragma unroll
        for (int i = 0; i < 3; ++i) {
            int slot = i * 512 + tid;
            int row = slot >> 3, pch = slot & 7;
            int lc = pch ^ (row & 7);            // pre-swizzled global source (rule #21)
            int gr = m0 + row; if (gr > M - 1) gr = M - 1;
            async_copy16(&lds8[b][slot * 16], A + (size_t)gr * K + (kt << 7) + lc * 16);
        }
    };
    auto stageB = [&](int kt, int b) {           // 256 rows x 8 chunks = 2048 slots = 4/thread
        #pragma unroll
        for (int i = 0; i < 4; ++i) {
            int slot = i * 512 + tid;
            int row = slot >> 3, pch = slot & 7;
            int lc = pch ^ (row & 7);
            async_copy16(&lds8[b][24576 + slot * 16], Bt + (size_t)(n0 + row) * K + (kt << 7) + lc * 16);
        }
    };

    floatx4 zero = {0.f, 0.f, 0.f, 0.f};
    floatx4 acc[6][4];
    #pragma unroll
    for (int i = 0; i < 6; ++i)
        #pragma unroll
        for (int jj = 0; jj < 4; ++jj) acc[i][jj] = zero;

    longx2 aF[3][2], bA[2][2], bB[2][2];         // [frag][j]: .x = half 0, .y = half 1

    auto loadA = [&](int b, int mg) {
        #pragma unroll
        for (int mf = 0; mf < 3; ++mf)
            #pragma unroll
            for (int j = 0; j < 2; ++j) {
                int row = wm * 96 + mg * 48 + mf * 16 + rr;
                int ch = ((qq << 1) + j) ^ (row & 7);
                aF[mf][j] = *(const longx2*)&lds8[b][row * 128 + ch * 16];
            }
    };
    auto loadB = [&](int b, longx2 (&bF)[2][2], int ng) {
        #pragma unroll
        for (int nf = 0; nf < 2; ++nf)
            #pragma unroll
            for (int j = 0; j < 2; ++j) {
                int row = wn * 64 + (ng * 2 + nf) * 16 + rr;
                int ch = ((qq << 1) + j) ^ (row & 7);
                bF[nf][j] = *(const longx2*)&lds8[b][24576 + row * 128 + ch * 16];
            }
    };
    auto mfmaQ = [&](int mg, int ng, longx2 (&bF)[2][2]) {   // 24 MFMA quadrant (K=128)
        #pragma unroll
        for (int mf = 0; mf < 3; ++mf)
            #pragma unroll
            for (int nf = 0; nf < 2; ++nf)
                #pragma unroll
                for (int j = 0; j < 2; ++j)
                    #pragma unroll
                    for (int h = 0; h < 2; ++h)
                        acc[mg * 3 + mf][ng * 2 + nf] = __builtin_amdgcn_mfma_f32_16x16x32_fp8_fp8(
                            aF[mf][j][h], bF[nf][j][h], acc[mg * 3 + mf][ng * 2 + nf], 0, 0, 0);
    };

#define SB0 __builtin_amdgcn_sched_barrier(0)
#define GBAR do { SB0; __builtin_amdgcn_s_barrier(); SB0; } while (0)

    stageB(0, 0); stageA(0, 0);
    stageB(1, 1); stageA(1, 1);
    SB0;
    asm volatile("s_waitcnt vmcnt(7)" ::: "memory");
    GBAR;

    for (int t = 0; t < NT; ++t) {
        const int p = t & 1;
        int tp = t + 2; while (tp >= NT) tp -= 2;            // parity-preserving tail clamp

        loadA(p, 0); loadB(p, bA, 0);
        GBAR;
        __builtin_amdgcn_s_setprio(1);
        mfmaQ(0, 0, bA);
        __builtin_amdgcn_s_setprio(0);
        GBAR;

        loadB(p, bB, 1);
        stageB(tp, p);
        GBAR;
        __builtin_amdgcn_s_setprio(1);
        mfmaQ(0, 1, bB);
        __builtin_amdgcn_s_setprio(0);
        GBAR;

        loadA(p, 1);
        stageA(tp, p);
        SB0;
        asm volatile("s_waitcnt vmcnt(7)" ::: "memory");
        GBAR;
        __builtin_amdgcn_s_setprio(1);
        mfmaQ(1, 1, bB);
        mfmaQ(1, 0, bA);
        __builtin_amdgcn_s_setprio(0);
        GBAR;
    }
#undef GBAR
#undef SB0

    const float scl = 1.0f / W2SCL;

    // epilogue 1: unscale + fp8 quantize + store
    #pragma unroll
    for (int mt = 0; mt < 6; ++mt) {
        #pragma unroll
        for (int r4 = 0; r4 < 4; ++r4) {
            int rowc = m0 + wm * 96 + mt * 16 + (lane >> 4) * 4 + r4;
            if (rowc < M) {
                u32 word = enc_fp8x4(acc[mt][0][r4] * scl, acc[mt][1][r4] * scl,
                                     acc[mt][2][r4] * scl, acc[mt][3][r4] * scl);
                unsigned char q8[4] = { (unsigned char)(word & 0xff), (unsigned char)((word >> 8) & 0xff),
                                        (unsigned char)((word >> 16) & 0xff), (unsigned char)(word >> 24) };
                #pragma unroll
                for (int nt = 0; nt < 4; ++nt) {
                    int col = n0 + wn * 64 + nt * 16 + (lane & 15);
                    C8[(size_t)rowc * N + col] = q8[nt];
                }
            }
        }
    }

    // epilogue 2: fused attention scores (scale folded into the att weights)
    {
        const int li = lane & 15;
        const int h0 = bx * 8 + wn * 2;
        float ws00 = att_src[(h0)     * OC + li] * scl,  ws01 = att_src[(h0)     * OC + 16 + li] * scl;
        float ws10 = att_src[(h0 + 1) * OC + li] * scl,  ws11 = att_src[(h0 + 1) * OC + 16 + li] * scl;
        float wd00 = att_dst[(h0)     * OC + li] * scl,  wd01 = att_dst[(h0)     * OC + 16 + li] * scl;
        float wd10 = att_dst[(h0 + 1) * OC + li] * scl,  wd11 = att_dst[(h0 + 1) * OC + 16 + li] * scl;
        #pragma unroll
        for (int mt = 0; mt < 6; ++mt) {
            #pragma unroll
            for (int r4 = 0; r4 < 4; ++r4) {
                float s0 = dpp_add16(acc[mt][0][r4] * ws00 + acc[mt][1][r4] * ws01);
                float s1 = dpp_add16(acc[mt][2][r4] * ws10 + acc[mt][3][r4] * ws11);
                float d0 = dpp_add16(acc[mt][0][r4] * wd00 + acc[mt][1][r4] * wd01);
                float d1 = dpp_add16(acc[mt][2][r4] * wd10 + acc[mt][3][r4] * wd11);
                int rowc = m0 + wm * 96 + mt * 16 + (lane >> 4) * 4 + r4;
                if (li == 0 && rowc < M) {
                    as_[(size_t)rowc * NH + h0]     = s0;
                    as_[(size_t)rowc * NH + h0 + 1] = s1;
                    ad_[(size_t)rowc * NH + h0]     = d0;
                    ad_[(size_t)rowc * NH + h0 + 1] = d1;
                }
            }
        }
    }
}

// ---------------- node-boundary flush for the fused streaming aggregate ----------------
// LAYER==1: FP8 h1p[cur][slice] = fp8(BN1(ELU(acc/den + b1)))  (feeds gemm_fp8's A)
// LAYER==2: head-reduce in-wave, write per-slice partial to h2part[cur][f][32]
template <int LAYER>
__device__ __forceinline__ void flush_node(float* acc, float den, int cur, int f, int lane,
                                           const float* __restrict__ bias,
                                           const float* __restrict__ bng,
                                           const float* __restrict__ bnb,
                                           const float* __restrict__ bnm,
                                           const float* __restrict__ bnv,
                                           void* __restrict__ outp) {
    float inv = 1.f / den;
    #pragma unroll
    for (int k = 0; k < 4; ++k) acc[k] *= inv;

    if constexpr (LAYER == 1) {
        int d0 = f * 256 + lane * 4;
        float v0 = acc[0] + bias[d0 + 0];
        float v1 = acc[1] + bias[d0 + 1];
        float v2 = acc[2] + bias[d0 + 2];
        float v3 = acc[3] + bias[d0 + 3];
        v0 = v0 > 0.f ? v0 : expm1f(v0);
        v1 = v1 > 0.f ? v1 : expm1f(v1);
        v2 = v2 > 0.f ? v2 : expm1f(v2);
        v3 = v3 > 0.f ? v3 : expm1f(v3);
        v0 = (v0 - bnm[d0 + 0]) * rsqrtf(bnv[d0 + 0] + EPS_BN) * bng[d0 + 0] + bnb[d0 + 0];
        v1 = (v1 - bnm[d0 + 1]) * rsqrtf(bnv[d0 + 1] + EPS_BN) * bng[d0 + 1] + bnb[d0 + 1];
        v2 = (v2 - bnm[d0 + 2]) * rsqrtf(bnv[d0 + 2] + EPS_BN) * bng[d0 + 2] + bnb[d0 + 2];
        v3 = (v3 - bnm[d0 + 3]) * rsqrtf(bnv[d0 + 3] + EPS_BN) * bng[d0 + 3] + bnb[d0 + 3];
        u32 word = enc_fp8x4(v0, v1, v2, v3);
        *(u32*)((unsigned char*)outp + (size_t)cur * DD1 + d0) = word;
    } else {
        #pragma unroll
        for (int k = 0; k < 4; ++k) {
            acc[k] += __shfl_xor(acc[k], 8, 64);
            acc[k] += __shfl_xor(acc[k], 16, 64);
            acc[k] += __shfl_xor(acc[k], 32, 64);
        }
        if (lane < 8) {
            floatx4 pk;
            #pragma unroll
            for (int k = 0; k < 4; ++k) pk[k] = acc[k] * (1.f / NH);
            *(floatx4*)((float*)outp + ((size_t)cur * 7 + f) * OC + lane * 4) = pk;
        }
    }
    acc[0] = acc[1] = acc[2] = acc[3] = 0.f;
}

// ---------------- fused streaming aggregation with ONLINE SOFTMAX (round-5 proven) ----------------
template <int LAYER>
__global__ __launch_bounds__(256) void attn_aggregate(const int* __restrict__ rowptr,
                                                      const int* __restrict__ csr_src,
                                                      const float* __restrict__ as_,
                                                      const float* __restrict__ ad_,
                                                      const unsigned char* __restrict__ h8,
                                                      const float* __restrict__ bias,
                                                      const float* __restrict__ bng,
                                                      const float* __restrict__ bnb,
                                                      const float* __restrict__ bnm,
                                                      const float* __restrict__ bnv,
                                                      void* __restrict__ outp) {
    const int wv = threadIdx.x >> 6, lane = threadIdx.x & 63;
    const int w = blockIdx.x * 4 + wv;
    const int NWAVES = 7 * (NN / GRP);
    if (w >= NWAVES) return;
    const int f  = w % 7;             // feature slice (256 B of the 1792-B row)
    const int g  = w / 7;             // node group
    const int n0 = g * GRP;
    const int off  = f * 256 + lane * 4;
    const int head = f * 8 + (lane >> 3);

    const int e0 = rowptr[n0], e1 = rowptr[n0 + GRP];
    int cur = n0;
    int bound = rowptr[n0 + 1];
    float adv = ad_[(size_t)cur * NH + head];

    float acc[4] = {0.f, 0.f, 0.f, 0.f};
    float m = -1e30f, den = 0.f;

    for (int e = e0; e < e1; e += EB) {
        u32   hv[EB];
        float sv[EB];
        #pragma unroll
        for (int i = 0; i < EB; ++i) {
            int idx = (e + i < e1) ? e + i : e1 - 1;
            int s = csr_src[idx];
            hv[i] = *(const u32*)(h8 + (size_t)s * DD1 + off);
            sv[i] = as_[(size_t)s * NH + head];
        }
        #pragma unroll
        for (int i = 0; i < EB; ++i) {
            if (e + i >= e1) break;
            if (e + i >= bound) {
                flush_node<LAYER>(acc, den, cur, f, lane, bias, bng, bnb, bnm, bnv, outp);
                ++cur;
                bound = rowptr[cur + 1];
                adv = ad_[(size_t)cur * NH + head];
                m = -1e30f; den = 0.f;
            }
            float lr = sv[i] + adv;
            lr = lr > 0.f ? lr : 0.2f * lr;
            float wgt;
            if (lr > m) {
                float scale = __expf(m - lr);
                den = den * scale + 1.f;
                #pragma unroll
                for (int k = 0; k < 4; ++k) acc[k] *= scale;
                m = lr;
                wgt = 1.f;
            } else {
                wgt = __expf(lr - m);
                den += wgt;
            }
            fma_fp8x4(hv[i], wgt, acc);
        }
    }
    flush_node<LAYER>(acc, den, cur, f, lane, bias, bng, bnb, bnm, bnv, outp);
}

// ---------------- mean pool: sorted-batch segmented reduction, minimal atomics ----------------
__global__ __launch_bounds__(256) void pool_kernel(const float* __restrict__ h2part,
                                                   const int* __restrict__ batch,
                                                   float* __restrict__ sums,
                                                   float* __restrict__ cnt) {
    __shared__ float red[4][OC];
    const int g = blockIdx.x >> 3, c = blockIdx.x & 7;
    const int t = threadIdx.x;
    const int ch = t & 31, nl = t >> 5;
    int lo = 0, hi = NN;
    while (lo < hi) { int mid = (lo + hi) >> 1; if (batch[mid] < g) lo = mid + 1; else hi = mid; }
    const int s = lo;
    hi = NN;
    while (lo < hi) { int mid = (lo + hi) >> 1; if (batch[mid] <= g) lo = mid + 1; else hi = mid; }
    const int e = lo;
    const int len = e - s;
    const int n0 = s + (len * c) / 8;
    const int n1 = s + (len * (c + 1)) / 8;
    float acc = 0.f;
    for (int n = n0 + nl; n < n1; n += 8) {
        const float* p = h2part + (size_t)n * 7 * OC + ch;
        float a = 0.f;
        #pragma unroll
        for (int f = 0; f < 7; ++f) a += p[f * OC];
        acc += a;
    }
    acc += __shfl_xor(acc, 32, 64);
    if ((t & 32) == 0) red[t >> 6][ch] = acc;
    __syncthreads();
    if (t < OC) {
        float total = red[0][t] + red[1][t] + red[2][t] + red[3][t];
        atomicAdd(&sums[g * OC + t], total);
    }
    if (t == 0 && c == 0) cnt[g] = (float)len;
}

// final: pooled = sums/cnt; v = BN2(pooled + b2); out = v @ lin_w + lin_b
__global__ __launch_bounds__(128) void final_kernel(const float* __restrict__ sums,
                                                    const float* __restrict__ cnt,
                                                    const float* __restrict__ b2,
                                                    const float* __restrict__ bn2g,
                                                    const float* __restrict__ bn2b,
                                                    const float* __restrict__ bn2m,
                                                    const float* __restrict__ bn2v,
                                                    const float* __restrict__ lin_w,
                                                    const float* __restrict__ lin_b,
                                                    float* __restrict__ out) {
    int t = threadIdx.x;
    if (t >= NG * 2) return;
    int g = t >> 1, c = t & 1;
    float invc = 1.f / fmaxf(cnt[g], 1.f);
    float acc = lin_b[c];
    #pragma unroll
    for (int o = 0; o < OC; ++o) {
        float pooled = sums[g * OC + o] * invc + b2[o];
        float v = (pooled - bn2m[o]) * rsqrtf(bn2v[o] + EPS_BN) * bn2g[o] + bn2b[o];
        acc += v * lin_w[o * 2 + c];
    }
    out[t] = acc;
}

// ---------------- host-side launch ----------------
extern "C" void kernel_launch(void* const* d_in, const int* in_sizes, int n_in,
                              void* d_out, int out_size, void* d_ws, size_t ws_size,
                              hipStream_t stream) {
    const float* x    = (const float*)d_in[0];
    const int*   ei   = (const int*)d_in[1];
    const int*   bat  = (const int*)d_in[2];
    const float* W1   = (const float*)d_in[3];
    const float* at_s1 = (const float*)d_in[4];
    const float* at_d1 = (const float*)d_in[5];
    const float* b1   = (const float*)d_in[6];
    const float* bn1g = (const float*)d_in[7];
    const float* bn1b = (const float*)d_in[8];
    const float* bn1m = (const float*)d_in[9];
    const float* bn1v = (const float*)d_in[10];
    const float* W2   = (const float*)d_in[11];
    const float* at_s2 = (const float*)d_in[12];
    const float* at_d2 = (const float*)d_in[13];
    const float* b2   = (const float*)d_in[14];
    const float* bn2g = (const float*)d_in[15];
    const float* bn2b = (const float*)d_in[16];
    const float* bn2m = (const float*)d_in[17];
    const float* bn2v = (const float*)d_in[18];
    const float* linw = (const float*)d_in[19];
    const float* linb = (const float*)d_in[20];
    float* out = (float*)d_out;

    char* wsp = (char*)d_ws;
    auto alloc = [&](size_t bytes) -> void* {
        void* p = (void*)wsp;
        wsp += (bytes + 255) & ~(size_t)255;
        return p;
    };
    unsigned char*  h8   = (unsigned char*)alloc((size_t)NN * DD1);     // fp8 gemm output
    unsigned char*  h1p  = (unsigned char*)alloc((size_t)NN * DD1);     // agg1 out, FP8 (gemm_fp8 A)
    __hip_bfloat16* xb   = (__hip_bfloat16*)alloc((size_t)NN * NF * 2);
    __hip_bfloat16* w1t  = (__hip_bfloat16*)alloc((size_t)DD1 * NF * 2);
    unsigned char*  w2t8 = (unsigned char*)alloc((size_t)DD1 * DD1);    // W2^T * 16, fp8
    float* asb   = (float*)alloc((size_t)NN * NH * 4);
    float* adb   = (float*)alloc((size_t)NN * NH * 4);
    int*   deg   = (int*)alloc((size_t)NN * 4);
    int*   rowp  = (int*)alloc((size_t)(NN + 1) * 4);
    int*   curs  = (int*)alloc((size_t)NN * 4);
    int*   csr   = (int*)alloc((size_t)ETOT * 4);
    float* h2part = (float*)alloc((size_t)NN * 7 * OC * 4);
    float* sums  = (float*)alloc((size_t)(NG * OC + NG) * 4);
    float* cnt   = sums + NG * OC;

    hipMemsetAsync(deg, 0, (size_t)NN * 4, stream);
    hipMemsetAsync(sums, 0, (size_t)(NG * OC + NG) * 4, stream);

    cast_bf16_kernel<<<(NN * NF + 255) / 256, 256, 0, stream>>>(x, xb, NN * NF);
    transpose_cast_kernel<<<dim3(DD1 / 32, NF / 32), 256, 0, stream>>>(W1, w1t, NF, DD1);
    transpose_fp8_kernel<<<dim3(DD1 / 32, DD1 / 32), 256, 0, stream>>>(W2, w2t8, DD1, DD1);
    hist_kernel<<<(ETOT + 255) / 256, 256, 0, stream>>>(ei, deg);
    scan_kernel<<<1, 1024, 0, stream>>>(deg, rowp, curs);
    scatter_kernel<<<(ETOT + 255) / 256, 256, 0, stream>>>(ei, curs, csr);

    const int AGG_BLOCKS = (7 * (NN / GRP) + 3) / 4;
    const int NBY192 = (NN + 191) / 192;                   // 105
    const int GEMM_BLOCKS = NBY192 * (DD1 / 256);          // 735

    // layer 1 (bf16 gemm, fused scores)
    gemm_192<<<GEMM_BLOCKS, 512, 0, stream>>>(xb, w1t, h8, at_s1, at_d1, asb, adb, NN, DD1, NF);
    attn_aggregate<1><<<AGG_BLOCKS, 256, 0, stream>>>(rowp, csr, asb, adb, h8, b1, bn1g, bn1b, bn1m, bn1v, (void*)h1p);

    // layer 2 (fp8 gemm, fused scores)
    gemm_fp8<<<GEMM_BLOCKS, 512, 0, stream>>>(h1p, w2t8, h8, at_s2, at_d2, asb, adb, NN, DD1, DD1);
    attn_aggregate<2><<<AGG_BLOCKS, 256, 0, stream>>>(rowp, csr, asb, adb, h8, b2, bn2g, bn2b, bn2m, bn2v, (void*)h2part);

    pool_kernel<<<NG * 8, 256, 0, stream>>>(h2part, bat, sums, cnt);
    final_kernel<<<1, 128, 0, stream>>>(sums, cnt, b2, bn2g, bn2b, bn2m, bn2v, linw, linb, out);
}

// Round 16
// 505.968 us; speedup vs baseline: 1.2551x; 1.0043x over previous
//
#include <hip/hip_runtime.h>
#include <hip/hip_bf16.h>
#include <hip/hip_fp8.h>
#include <cstdint>
#include <cstddef>

// Problem constants
#define NN     20000     // nodes
#define NF     128       // in features
#define NH     56        // heads
#define OC     32        // out channels per head
#define DD1    1792      // NH*OC
#define NE     100000    // edges (before self loops)
#define ETOT   120000    // edges + self loops
#define NG     50        // graphs
#define EPS_BN 1e-5f
#define GRP    16        // nodes per wave in aggregate
#define EB     16        // edge batch (round-5 proven single-buffer)
#define W2SCL  16.0f     // W2 pre-scale (fp8 range); epilogue multiplies by 1/W2SCL

typedef __bf16 bf16x8 __attribute__((ext_vector_type(8)));
typedef float  floatx4 __attribute__((ext_vector_type(4)));
typedef float  floatx2 __attribute__((ext_vector_type(2)));
typedef long   longx2  __attribute__((ext_vector_type(2)));
typedef unsigned int u32;
typedef __attribute__((address_space(1))) u32 gu32;
typedef __attribute__((address_space(3))) u32 lu32;

__device__ __forceinline__ void async_copy16(void* lds, const void* g) {
    __builtin_amdgcn_global_load_lds((gu32*)const_cast<void*>(g), (lu32*)lds, 16, 0, 0);
}

// 16B LDS load forced through the bf16x8 pattern (PROVEN to emit ds_read_b128 with 0
// bank conflicts across 10+ rounds), bit-cast to the fp8-MFMA operand pair.
// Round-15's direct longx2 load lowered to 2x ds_read_b64 -> half-wave 4-way conflicts
// (measured 6.59e6 = exactly +2cy per b64 read).
__device__ __forceinline__ longx2 ld_lds16(const unsigned char* p) {
    bf16x8 raw = *(const bf16x8*)p;
    return __builtin_bit_cast(longx2, raw);
}

// decode 4 fp8 (e4m3, packed in u32) to 4 floats (HW cvt when available)
__device__ __forceinline__ void dec_fp8x4(u32 u, float* v) {
#if __has_builtin(__builtin_amdgcn_cvt_pk_f32_fp8)
    floatx2 lo = __builtin_amdgcn_cvt_pk_f32_fp8(u, false);
    floatx2 hi = __builtin_amdgcn_cvt_pk_f32_fp8(u, true);
    v[0] = lo[0]; v[1] = lo[1]; v[2] = hi[0]; v[3] = hi[1];
#else
    #pragma unroll
    for (int b = 0; b < 4; ++b) {
        __hip_fp8_e4m3 t;
        t.__x = (u >> (8 * b)) & 0xff;
        v[b] = (float)t;
    }
#endif
}

__device__ __forceinline__ u32 enc_fp8x4(float v0, float v1, float v2, float v3) {
#if __has_builtin(__builtin_amdgcn_cvt_pk_fp8_f32)
    u32 p01 = (u32)__builtin_amdgcn_cvt_pk_fp8_f32(v0, v1, 0, false);
    u32 p23 = (u32)__builtin_amdgcn_cvt_pk_fp8_f32(v2, v3, 0, false);
    return (p01 & 0xffff) | (p23 << 16);
#else
    __hip_fp8_e4m3 t0(v0), t1(v1), t2(v2), t3(v3);
    return (u32)t0.__x | ((u32)t1.__x << 8) | ((u32)t2.__x << 16) | ((u32)t3.__x << 24);
#endif
}

__device__ __forceinline__ void fma_fp8x4(u32 u, float a, float* acc) {
    float v[4];
    dec_fp8x4(u, v);
    #pragma unroll
    for (int b = 0; b < 4; ++b) acc[b] += a * v[b];
}

// ---- 16-lane row sum via DPP (VALU pipe, NO LDS traffic; round-13 proven) ----
template <int CTRL>
__device__ __forceinline__ float dpp_row_add(float x) {
    int v = __builtin_amdgcn_mov_dpp(__float_as_int(x), CTRL, 0xf, 0xf, true);
    return x + __int_as_float(v);
}
__device__ __forceinline__ float dpp_add16(float x) {
    x = dpp_row_add<0x128>(x);   // row_ror:8
    x = dpp_row_add<0x124>(x);   // row_ror:4
    x = dpp_row_add<78>(x);      // quad_perm [2,3,0,1] = xor2
    x = dpp_row_add<177>(x);     // quad_perm [1,0,3,2] = xor1
    return x;
}

// ---------------- elementwise cast fp32 -> bf16 ----------------
__global__ __launch_bounds__(256) void cast_bf16_kernel(const float* __restrict__ in,
                                                        __hip_bfloat16* __restrict__ out, int n) {
    int i = blockIdx.x * 256 + threadIdx.x;
    if (i < n) out[i] = __float2bfloat16(in[i]);
}

// ---------------- tiled transpose + cast: in[R][C] f32 -> out[C][R] bf16 ----------------
__global__ __launch_bounds__(256) void transpose_cast_kernel(const float* __restrict__ in,
                                                             __hip_bfloat16* __restrict__ out,
                                                             int R, int C) {
    __shared__ float tile[32][33];
    int c0 = blockIdx.x * 32, r0 = blockIdx.y * 32;
    int tx = threadIdx.x & 31, ty = threadIdx.x >> 5;   // ty in 0..7
    #pragma unroll
    for (int i = 0; i < 32; i += 8) {
        int r = r0 + ty + i, c = c0 + tx;
        if (r < R && c < C) tile[ty + i][tx] = in[(size_t)r * C + c];
    }
    __syncthreads();
    #pragma unroll
    for (int i = 0; i < 32; i += 8) {
        int c = c0 + ty + i, r = r0 + tx;
        if (c < C && r < R) out[(size_t)c * R + r] = __float2bfloat16(tile[tx][ty + i]);
    }
}

// ---------------- tiled transpose + fp8 cast with W2SCL pre-scale ----------------
__global__ __launch_bounds__(256) void transpose_fp8_kernel(const float* __restrict__ in,
                                                            unsigned char* __restrict__ out,
                                                            int R, int C) {
    __shared__ float tile[32][33];
    int c0 = blockIdx.x * 32, r0 = blockIdx.y * 32;
    int tx = threadIdx.x & 31, ty = threadIdx.x >> 5;
    #pragma unroll
    for (int i = 0; i < 32; i += 8) {
        int r = r0 + ty + i, c = c0 + tx;
        if (r < R && c < C) tile[ty + i][tx] = in[(size_t)r * C + c];
    }
    __syncthreads();
    #pragma unroll
    for (int i = 0; i < 32; i += 8) {
        int c = c0 + ty + i, r = r0 + tx;
        if (c < C && r < R) {
            __hip_fp8_e4m3 t(tile[tx][ty + i] * W2SCL);
            out[(size_t)c * R + r] = t.__x;
        }
    }
}

// ---------------- CSR build: histogram / scan / scatter ----------------
__global__ __launch_bounds__(256) void hist_kernel(const int* __restrict__ ei, int* __restrict__ deg) {
    int i = blockIdx.x * 256 + threadIdx.x;
    if (i >= ETOT) return;
    int dst = (i < NE) ? ei[NE + i] : (i - NE);
    atomicAdd(&deg[dst], 1);
}

__global__ __launch_bounds__(1024) void scan_kernel(const int* __restrict__ deg,
                                                    int* __restrict__ rowptr,
                                                    int* __restrict__ cursor) {
    __shared__ int buf[1024];
    int t = threadIdx.x;
    const int CH = (NN + 1023) >> 10;   // 20
    int base = t * CH;
    int s = 0;
    for (int j = 0; j < CH; ++j) { int idx = base + j; if (idx < NN) s += deg[idx]; }
    buf[t] = s;
    __syncthreads();
    for (int off = 1; off < 1024; off <<= 1) {
        int v = (t >= off) ? buf[t - off] : 0;
        __syncthreads();
        buf[t] += v;
        __syncthreads();
    }
    int run = buf[t] - s;   // exclusive
    for (int j = 0; j < CH; ++j) {
        int idx = base + j;
        if (idx < NN) { rowptr[idx] = run; cursor[idx] = run; run += deg[idx]; }
    }
    if (t == 1023) rowptr[NN] = buf[1023];
}

__global__ __launch_bounds__(256) void scatter_kernel(const int* __restrict__ ei,
                                                      int* __restrict__ cursor,
                                                      int* __restrict__ csr_src) {
    int i = blockIdx.x * 256 + threadIdx.x;
    if (i >= ETOT) return;
    int s, d;
    if (i < NE) { s = ei[i]; d = ei[NE + i]; } else { s = i - NE; d = i - NE; }
    int pos = atomicAdd(&cursor[d], 1);
    csr_src[pos] = s;
}

// ---------------- bf16 MFMA GEMM (layer 1), 192x256, 3-phase — round-13 proven ----------------
__global__ __launch_bounds__(512, 2) void gemm_192(const __hip_bfloat16* __restrict__ A,
                                                   const __hip_bfloat16* __restrict__ Bt,
                                                   unsigned char* __restrict__ C8,
                                                   const float* __restrict__ att_src,
                                                   const float* __restrict__ att_dst,
                                                   float* __restrict__ as_,
                                                   float* __restrict__ ad_,
                                                   int M, int N, int K) {
    __shared__ __align__(16) unsigned short lds[2][28672];  // per buf: A[192][64] | B[256][64]
    const int tid  = threadIdx.x;
    const int lane = tid & 63, wave = tid >> 6;
    const int wm = wave >> 2, wn = wave & 3;     // 2 x 4 wave grid; per-wave C: 96 x 64

    const int nbx = N >> 8;                      // 7
    const int nby = (M + 191) / 192;             // 105
    const int nwg = nbx * nby;                   // 735
    const int q = nwg >> 3, r = nwg & 7;
    const int xcd = blockIdx.x & 7, bidx = blockIdx.x >> 3;
    const int wg = (xcd < r ? xcd * (q + 1) : r * (q + 1) + (xcd - r) * q) + bidx;
    const int by = wg / nbx, bx = wg - by * nbx;
    const int m0 = by * 192, n0 = bx << 8;

    const int NT = K >> 6;                       // K-tiles of 64 (layer 1: 2)

    const int qq = lane >> 4, rr = lane & 15;

    auto stageA = [&](int kt, int b) {
        #pragma unroll
        for (int i = 0; i < 3; ++i) {
            int slot = i * 512 + tid;
            int row = slot >> 3, pch = slot & 7;
            int lc = pch ^ (row & 7);
            int gr = m0 + row; if (gr > M - 1) gr = M - 1;
            async_copy16(&lds[b][slot * 8], A + (size_t)gr * K + (kt << 6) + lc * 8);
        }
    };
    auto stageB = [&](int kt, int b) {
        #pragma unroll
        for (int i = 0; i < 4; ++i) {
            int slot = i * 512 + tid;
            int row = slot >> 3, pch = slot & 7;
            int lc = pch ^ (row & 7);
            async_copy16(&lds[b][12288 + slot * 8], Bt + (size_t)(n0 + row) * K + (kt << 6) + lc * 8);
        }
    };

    floatx4 zero = {0.f, 0.f, 0.f, 0.f};
    floatx4 acc[6][4];
    #pragma unroll
    for (int i = 0; i < 6; ++i)
        #pragma unroll
        for (int jj = 0; jj < 4; ++jj) acc[i][jj] = zero;

    bf16x8 aF[3][2], bA[2][2], bB[2][2];

    auto loadA = [&](int b, int mg) {
        #pragma unroll
        for (int mf = 0; mf < 3; ++mf)
            #pragma unroll
            for (int s = 0; s < 2; ++s) {
                int row = wm * 96 + mg * 48 + mf * 16 + rr;
                int pch = (s * 4 + qq) ^ (row & 7);
                aF[mf][s] = *(const bf16x8*)&lds[b][row * 64 + pch * 8];
            }
    };
    auto loadB = [&](int b, bf16x8 (&bF)[2][2], int ng) {
        #pragma unroll
        for (int nf = 0; nf < 2; ++nf)
            #pragma unroll
            for (int s = 0; s < 2; ++s) {
                int row = wn * 64 + (ng * 2 + nf) * 16 + rr;
                int pch = (s * 4 + qq) ^ (row & 7);
                bF[nf][s] = *(const bf16x8*)&lds[b][12288 + row * 64 + pch * 8];
            }
    };
    auto mfmaQ = [&](int mg, int ng, bf16x8 (&bF)[2][2]) {
        #pragma unroll
        for (int mf = 0; mf < 3; ++mf)
            #pragma unroll
            for (int nf = 0; nf < 2; ++nf)
                #pragma unroll
                for (int s = 0; s < 2; ++s)
                    acc[mg * 3 + mf][ng * 2 + nf] = __builtin_amdgcn_mfma_f32_16x16x32_bf16(
                        aF[mf][s], bF[nf][s], acc[mg * 3 + mf][ng * 2 + nf], 0, 0, 0);
    };

#define SB0 __builtin_amdgcn_sched_barrier(0)
#define GBAR do { SB0; __builtin_amdgcn_s_barrier(); SB0; } while (0)

    stageB(0, 0); stageA(0, 0);
    stageB(1, 1); stageA(1, 1);
    SB0;
    asm volatile("s_waitcnt vmcnt(7)" ::: "memory");
    GBAR;

    for (int t = 0; t < NT; ++t) {
        const int p = t & 1;
        int tp = t + 2; while (tp >= NT) tp -= 2;

        loadA(p, 0); loadB(p, bA, 0);
        GBAR;
        __builtin_amdgcn_s_setprio(1);
        mfmaQ(0, 0, bA);
        __builtin_amdgcn_s_setprio(0);
        GBAR;

        loadB(p, bB, 1);
        stageB(tp, p);
        GBAR;
        __builtin_amdgcn_s_setprio(1);
        mfmaQ(0, 1, bB);
        __builtin_amdgcn_s_setprio(0);
        GBAR;

        loadA(p, 1);
        stageA(tp, p);
        SB0;
        asm volatile("s_waitcnt vmcnt(7)" ::: "memory");
        GBAR;
        __builtin_amdgcn_s_setprio(1);
        mfmaQ(1, 1, bB);
        mfmaQ(1, 0, bA);
        __builtin_amdgcn_s_setprio(0);
        GBAR;
    }
#undef GBAR
#undef SB0

    // epilogue 1: fp8 quantize + store
    #pragma unroll
    for (int mt = 0; mt < 6; ++mt) {
        #pragma unroll
        for (int r4 = 0; r4 < 4; ++r4) {
            int rowc = m0 + wm * 96 + mt * 16 + (lane >> 4) * 4 + r4;
            if (rowc < M) {
                u32 word = enc_fp8x4(acc[mt][0][r4], acc[mt][1][r4], acc[mt][2][r4], acc[mt][3][r4]);
                unsigned char q8[4] = { (unsigned char)(word & 0xff), (unsigned char)((word >> 8) & 0xff),
                                        (unsigned char)((word >> 16) & 0xff), (unsigned char)(word >> 24) };
                #pragma unroll
                for (int nt = 0; nt < 4; ++nt) {
                    int col = n0 + wn * 64 + nt * 16 + (lane & 15);
                    C8[(size_t)rowc * N + col] = q8[nt];
                }
            }
        }
    }

    // epilogue 2: fused attention scores (DPP row-sum, round-13 proven)
    {
        const int li = lane & 15;
        const int h0 = bx * 8 + wn * 2;
        float ws00 = att_src[(h0)     * OC + li],      ws01 = att_src[(h0)     * OC + 16 + li];
        float ws10 = att_src[(h0 + 1) * OC + li],      ws11 = att_src[(h0 + 1) * OC + 16 + li];
        float wd00 = att_dst[(h0)     * OC + li],      wd01 = att_dst[(h0)     * OC + 16 + li];
        float wd10 = att_dst[(h0 + 1) * OC + li],      wd11 = att_dst[(h0 + 1) * OC + 16 + li];
        #pragma unroll
        for (int mt = 0; mt < 6; ++mt) {
            #pragma unroll
            for (int r4 = 0; r4 < 4; ++r4) {
                float s0 = dpp_add16(acc[mt][0][r4] * ws00 + acc[mt][1][r4] * ws01);
                float s1 = dpp_add16(acc[mt][2][r4] * ws10 + acc[mt][3][r4] * ws11);
                float d0 = dpp_add16(acc[mt][0][r4] * wd00 + acc[mt][1][r4] * wd01);
                float d1 = dpp_add16(acc[mt][2][r4] * wd10 + acc[mt][3][r4] * wd11);
                int rowc = m0 + wm * 96 + mt * 16 + (lane >> 4) * 4 + r4;
                if (li == 0 && rowc < M) {
                    as_[(size_t)rowc * NH + h0]     = s0;
                    as_[(size_t)rowc * NH + h0 + 1] = s1;
                    ad_[(size_t)rowc * NH + h0]     = d0;
                    ad_[(size_t)rowc * NH + h0 + 1] = d1;
                }
            }
        }
    }
}

// ---------------- fp8 MFMA GEMM (layer 2), 192x256, BK=128 — b128 k-permuted reads ----------------
// k-permutation (round-15): sub-slice (j,half): lane qq supplies k = qq*32 + j*16 + half*8 + b
// for BOTH A and B (MFMA k-matching is positional). Lane's fragments for (j,0)/(j,1) are 16
// contiguous bytes at chunk (qq*2+j)^(row&7). Loads now go through ld_lds16 (bf16x8-typed,
// the proven-ds_read_b128 pattern) — round-15's longx2 loads lowered to 2x ds_read_b64,
// causing half-wave 4-way conflicts (6.59e6 measured).
__global__ __launch_bounds__(512, 2) void gemm_fp8(const unsigned char* __restrict__ A,
                                                   const unsigned char* __restrict__ Bt,
                                                   unsigned char* __restrict__ C8,
                                                   const float* __restrict__ att_src,
                                                   const float* __restrict__ att_dst,
                                                   float* __restrict__ as_,
                                                   float* __restrict__ ad_,
                                                   int M, int N, int K) {
    __shared__ __align__(16) unsigned char lds8[2][57344];  // per buf: A[192][128B] | B[256][128B]
    const int tid  = threadIdx.x;
    const int lane = tid & 63, wave = tid >> 6;
    const int wm = wave >> 2, wn = wave & 3;     // 2 x 4 wave grid; per-wave C: 96 x 64

    const int nbx = N >> 8;                      // 7
    const int nby = (M + 191) / 192;             // 105
    const int nwg = nbx * nby;                   // 735
    const int q = nwg >> 3, r = nwg & 7;
    const int xcd = blockIdx.x & 7, bidx = blockIdx.x >> 3;
    const int wg = (xcd < r ? xcd * (q + 1) : r * (q + 1) + (xcd - r) * q) + bidx;
    const int by = wg / nbx, bx = wg - by * nbx;
    const int m0 = by * 192, n0 = bx << 8;

    const int NT = K >> 7;                       // K-tiles of 128: 14

    const int qq = lane >> 4, rr = lane & 15;

    auto stageA = [&](int kt, int b) {           // 192 rows x 8 chunks = 1536 slots = 3/thread
        #pragma unroll
        for (int i = 0; i < 3; ++i) {
            int slot = i * 512 + tid;
            int row = slot >> 3, pch = slot & 7;
            int lc = pch ^ (row & 7);            // pre-swizzled global source (rule #21)
            int gr = m0 + row; if (gr > M - 1) gr = M - 1;
            async_copy16(&lds8[b][slot * 16], A + (size_t)gr * K + (kt << 7) + lc * 16);
        }
    };
    auto stageB = [&](int kt, int b) {           // 256 rows x 8 chunks = 2048 slots = 4/thread
        #pragma unroll
        for (int i = 0; i < 4; ++i) {
            int slot = i * 512 + tid;
            int row = slot >> 3, pch = slot & 7;
            int lc = pch ^ (row & 7);
            async_copy16(&lds8[b][24576 + slot * 16], Bt + (size_t)(n0 + row) * K + (kt << 7) + lc * 16);
        }
    };

    floatx4 zero = {0.f, 0.f, 0.f, 0.f};
    floatx4 acc[6][4];
    #pragma unroll
    for (int i = 0; i < 6; ++i)
        #pragma unroll
        for (int jj = 0; jj < 4; ++jj) acc[i][jj] = zero;

    longx2 aF[3][2], bA[2][2], bB[2][2];         // [frag][j]: .x = half 0, .y = half 1

    auto loadA = [&](int b, int mg) {
        #pragma unroll
        for (int mf = 0; mf < 3; ++mf)
            #pragma unroll
            for (int j = 0; j < 2; ++j) {
                int row = wm * 96 + mg * 48 + mf * 16 + rr;
                int ch = ((qq << 1) + j) ^ (row & 7);
                aF[mf][j] = ld_lds16(&lds8[b][row * 128 + ch * 16]);
            }
    };
    auto loadB = [&](int b, longx2 (&bF)[2][2], int ng) {
        #pragma unroll
        for (int nf = 0; nf < 2; ++nf)
            #pragma unroll
            for (int j = 0; j < 2; ++j) {
                int row = wn * 64 + (ng * 2 + nf) * 16 + rr;
                int ch = ((qq << 1) + j) ^ (row & 7);
                bF[nf][j] = ld_lds16(&lds8[b][24576 + row * 128 + ch * 16]);
            }
    };
    auto mfmaQ = [&](int mg, int ng, longx2 (&bF)[2][2]) {   // 24 MFMA quadrant (K=128)
        #pragma unroll
        for (int mf = 0; mf < 3; ++mf)
            #pragma unroll
            for (int nf = 0; nf < 2; ++nf)
                #pragma unroll
                for (int j = 0; j < 2; ++j)
                    #pragma unroll
                    for (int h = 0; h < 2; ++h)
                        acc[mg * 3 + mf][ng * 2 + nf] = __builtin_amdgcn_mfma_f32_16x16x32_fp8_fp8(
                            aF[mf][j][h], bF[nf][j][h], acc[mg * 3 + mf][ng * 2 + nf], 0, 0, 0);
    };

#define SB0 __builtin_amdgcn_sched_barrier(0)
#define GBAR do { SB0; __builtin_amdgcn_s_barrier(); SB0; } while (0)

    stageB(0, 0); stageA(0, 0);
    stageB(1, 1); stageA(1, 1);
    SB0;
    asm volatile("s_waitcnt vmcnt(7)" ::: "memory");
    GBAR;

    for (int t = 0; t < NT; ++t) {
        const int p = t & 1;
        int tp = t + 2; while (tp >= NT) tp -= 2;            // parity-preserving tail clamp

        loadA(p, 0); loadB(p, bA, 0);
        GBAR;
        __builtin_amdgcn_s_setprio(1);
        mfmaQ(0, 0, bA);
        __builtin_amdgcn_s_setprio(0);
        GBAR;

        loadB(p, bB, 1);
        stageB(tp, p);
        GBAR;
        __builtin_amdgcn_s_setprio(1);
        mfmaQ(0, 1, bB);
        __builtin_amdgcn_s_setprio(0);
        GBAR;

        loadA(p, 1);
        stageA(tp, p);
        SB0;
        asm volatile("s_waitcnt vmcnt(7)" ::: "memory");
        GBAR;
        __builtin_amdgcn_s_setprio(1);
        mfmaQ(1, 1, bB);
        mfmaQ(1, 0, bA);
        __builtin_amdgcn_s_setprio(0);
        GBAR;
    }
#undef GBAR
#undef SB0

    const float scl = 1.0f / W2SCL;

    // epilogue 1: unscale + fp8 quantize + store
    #pragma unroll
    for (int mt = 0; mt < 6; ++mt) {
        #pragma unroll
        for (int r4 = 0; r4 < 4; ++r4) {
            int rowc = m0 + wm * 96 + mt * 16 + (lane >> 4) * 4 + r4;
            if (rowc < M) {
                u32 word = enc_fp8x4(acc[mt][0][r4] * scl, acc[mt][1][r4] * scl,
                                     acc[mt][2][r4] * scl, acc[mt][3][r4] * scl);
                unsigned char q8[4] = { (unsigned char)(word & 0xff), (unsigned char)((word >> 8) & 0xff),
                                        (unsigned char)((word >> 16) & 0xff), (unsigned char)(word >> 24) };
                #pragma unroll
                for (int nt = 0; nt < 4; ++nt) {
                    int col = n0 + wn * 64 + nt * 16 + (lane & 15);
                    C8[(size_t)rowc * N + col] = q8[nt];
                }
            }
        }
    }

    // epilogue 2: fused attention scores (scale folded into the att weights)
    {
        const int li = lane & 15;
        const int h0 = bx * 8 + wn * 2;
        float ws00 = att_src[(h0)     * OC + li] * scl,  ws01 = att_src[(h0)     * OC + 16 + li] * scl;
        float ws10 = att_src[(h0 + 1) * OC + li] * scl,  ws11 = att_src[(h0 + 1) * OC + 16 + li] * scl;
        float wd00 = att_dst[(h0)     * OC + li] * scl,  wd01 = att_dst[(h0)     * OC + 16 + li] * scl;
        float wd10 = att_dst[(h0 + 1) * OC + li] * scl,  wd11 = att_dst[(h0 + 1) * OC + 16 + li] * scl;
        #pragma unroll
        for (int mt = 0; mt < 6; ++mt) {
            #pragma unroll
            for (int r4 = 0; r4 < 4; ++r4) {
                float s0 = dpp_add16(acc[mt][0][r4] * ws00 + acc[mt][1][r4] * ws01);
                float s1 = dpp_add16(acc[mt][2][r4] * ws10 + acc[mt][3][r4] * ws11);
                float d0 = dpp_add16(acc[mt][0][r4] * wd00 + acc[mt][1][r4] * wd01);
                float d1 = dpp_add16(acc[mt][2][r4] * wd10 + acc[mt][3][r4] * wd11);
                int rowc = m0 + wm * 96 + mt * 16 + (lane >> 4) * 4 + r4;
                if (li == 0 && rowc < M) {
                    as_[(size_t)rowc * NH + h0]     = s0;
                    as_[(size_t)rowc * NH + h0 + 1] = s1;
                    ad_[(size_t)rowc * NH + h0]     = d0;
                    ad_[(size_t)rowc * NH + h0 + 1] = d1;
                }
            }
        }
    }
}

// ---------------- node-boundary flush for the fused streaming aggregate ----------------
// LAYER==1: FP8 h1p[cur][slice] = fp8(BN1(ELU(acc/den + b1)))  (feeds gemm_fp8's A)
// LAYER==2: head-reduce in-wave, write per-slice partial to h2part[cur][f][32]
template <int LAYER>
__device__ __forceinline__ void flush_node(float* acc, float den, int cur, int f, int lane,
                                           const float* __restrict__ bias,
                                           const float* __restrict__ bng,
                                           const float* __restrict__ bnb,
                                           const float* __restrict__ bnm,
                                           const float* __restrict__ bnv,
                                           void* __restrict__ outp) {
    float inv = 1.f / den;
    #pragma unroll
    for (int k = 0; k < 4; ++k) acc[k] *= inv;

    if constexpr (LAYER == 1) {
        int d0 = f * 256 + lane * 4;
        float v0 = acc[0] + bias[d0 + 0];
        float v1 = acc[1] + bias[d0 + 1];
        float v2 = acc[2] + bias[d0 + 2];
        float v3 = acc[3] + bias[d0 + 3];
        v0 = v0 > 0.f ? v0 : expm1f(v0);
        v1 = v1 > 0.f ? v1 : expm1f(v1);
        v2 = v2 > 0.f ? v2 : expm1f(v2);
        v3 = v3 > 0.f ? v3 : expm1f(v3);
        v0 = (v0 - bnm[d0 + 0]) * rsqrtf(bnv[d0 + 0] + EPS_BN) * bng[d0 + 0] + bnb[d0 + 0];
        v1 = (v1 - bnm[d0 + 1]) * rsqrtf(bnv[d0 + 1] + EPS_BN) * bng[d0 + 1] + bnb[d0 + 1];
        v2 = (v2 - bnm[d0 + 2]) * rsqrtf(bnv[d0 + 2] + EPS_BN) * bng[d0 + 2] + bnb[d0 + 2];
        v3 = (v3 - bnm[d0 + 3]) * rsqrtf(bnv[d0 + 3] + EPS_BN) * bng[d0 + 3] + bnb[d0 + 3];
        u32 word = enc_fp8x4(v0, v1, v2, v3);
        *(u32*)((unsigned char*)outp + (size_t)cur * DD1 + d0) = word;
    } else {
        #pragma unroll
        for (int k = 0; k < 4; ++k) {
            acc[k] += __shfl_xor(acc[k], 8, 64);
            acc[k] += __shfl_xor(acc[k], 16, 64);
            acc[k] += __shfl_xor(acc[k], 32, 64);
        }
        if (lane < 8) {
            floatx4 pk;
            #pragma unroll
            for (int k = 0; k < 4; ++k) pk[k] = acc[k] * (1.f / NH);
            *(floatx4*)((float*)outp + ((size_t)cur * 7 + f) * OC + lane * 4) = pk;
        }
    }
    acc[0] = acc[1] = acc[2] = acc[3] = 0.f;
}

// ---------------- fused streaming aggregation with ONLINE SOFTMAX (round-5 proven) ----------------
template <int LAYER>
__global__ __launch_bounds__(256) void attn_aggregate(const int* __restrict__ rowptr,
                                                      const int* __restrict__ csr_src,
                                                      const float* __restrict__ as_,
                                                      const float* __restrict__ ad_,
                                                      const unsigned char* __restrict__ h8,
                                                      const float* __restrict__ bias,
                                                      const float* __restrict__ bng,
                                                      const float* __restrict__ bnb,
                                                      const float* __restrict__ bnm,
                                                      const float* __restrict__ bnv,
                                                      void* __restrict__ outp) {
    const int wv = threadIdx.x >> 6, lane = threadIdx.x & 63;
    const int w = blockIdx.x * 4 + wv;
    const int NWAVES = 7 * (NN / GRP);
    if (w >= NWAVES) return;
    const int f  = w % 7;             // feature slice (256 B of the 1792-B row)
    const int g  = w / 7;             // node group
    const int n0 = g * GRP;
    const int off  = f * 256 + lane * 4;
    const int head = f * 8 + (lane >> 3);

    const int e0 = rowptr[n0], e1 = rowptr[n0 + GRP];
    int cur = n0;
    int bound = rowptr[n0 + 1];
    float adv = ad_[(size_t)cur * NH + head];

    float acc[4] = {0.f, 0.f, 0.f, 0.f};
    float m = -1e30f, den = 0.f;

    for (int e = e0; e < e1; e += EB) {
        u32   hv[EB];
        float sv[EB];
        #pragma unroll
        for (int i = 0; i < EB; ++i) {
            int idx = (e + i < e1) ? e + i : e1 - 1;
            int s = csr_src[idx];
            hv[i] = *(const u32*)(h8 + (size_t)s * DD1 + off);
            sv[i] = as_[(size_t)s * NH + head];
        }
        #pragma unroll
        for (int i = 0; i < EB; ++i) {
            if (e + i >= e1) break;
            if (e + i >= bound) {
                flush_node<LAYER>(acc, den, cur, f, lane, bias, bng, bnb, bnm, bnv, outp);
                ++cur;
                bound = rowptr[cur + 1];
                adv = ad_[(size_t)cur * NH + head];
                m = -1e30f; den = 0.f;
            }
            float lr = sv[i] + adv;
            lr = lr > 0.f ? lr : 0.2f * lr;
            float wgt;
            if (lr > m) {
                float scale = __expf(m - lr);
                den = den * scale + 1.f;
                #pragma unroll
                for (int k = 0; k < 4; ++k) acc[k] *= scale;
                m = lr;
                wgt = 1.f;
            } else {
                wgt = __expf(lr - m);
                den += wgt;
            }
            fma_fp8x4(hv[i], wgt, acc);
        }
    }
    flush_node<LAYER>(acc, den, cur, f, lane, bias, bng, bnb, bnm, bnv, outp);
}

// ---------------- mean pool: sorted-batch segmented reduction, minimal atomics ----------------
__global__ __launch_bounds__(256) void pool_kernel(const float* __restrict__ h2part,
                                                   const int* __restrict__ batch,
                                                   float* __restrict__ sums,
                                                   float* __restrict__ cnt) {
    __shared__ float red[4][OC];
    const int g = blockIdx.x >> 3, c = blockIdx.x & 7;
    const int t = threadIdx.x;
    const int ch = t & 31, nl = t >> 5;
    int lo = 0, hi = NN;
    while (lo < hi) { int mid = (lo + hi) >> 1; if (batch[mid] < g) lo = mid + 1; else hi = mid; }
    const int s = lo;
    hi = NN;
    while (lo < hi) { int mid = (lo + hi) >> 1; if (batch[mid] <= g) lo = mid + 1; else hi = mid; }
    const int e = lo;
    const int len = e - s;
    const int n0 = s + (len * c) / 8;
    const int n1 = s + (len * (c + 1)) / 8;
    float acc = 0.f;
    for (int n = n0 + nl; n < n1; n += 8) {
        const float* p = h2part + (size_t)n * 7 * OC + ch;
        float a = 0.f;
        #pragma unroll
        for (int f = 0; f < 7; ++f) a += p[f * OC];
        acc += a;
    }
    acc += __shfl_xor(acc, 32, 64);
    if ((t & 32) == 0) red[t >> 6][ch] = acc;
    __syncthreads();
    if (t < OC) {
        float total = red[0][t] + red[1][t] + red[2][t] + red[3][t];
        atomicAdd(&sums[g * OC + t], total);
    }
    if (t == 0 && c == 0) cnt[g] = (float)len;
}

// final: pooled = sums/cnt; v = BN2(pooled + b2); out = v @ lin_w + lin_b
__global__ __launch_bounds__(128) void final_kernel(const float* __restrict__ sums,
                                                    const float* __restrict__ cnt,
                                                    const float* __restrict__ b2,
                                                    const float* __restrict__ bn2g,
                                                    const float* __restrict__ bn2b,
                                                    const float* __restrict__ bn2m,
                                                    const float* __restrict__ bn2v,
                                                    const float* __restrict__ lin_w,
                                                    const float* __restrict__ lin_b,
                                                    float* __restrict__ out) {
    int t = threadIdx.x;
    if (t >= NG * 2) return;
    int g = t >> 1, c = t & 1;
    float invc = 1.f / fmaxf(cnt[g], 1.f);
    float acc = lin_b[c];
    #pragma unroll
    for (int o = 0; o < OC; ++o) {
        float pooled = sums[g * OC + o] * invc + b2[o];
        float v = (pooled - bn2m[o]) * rsqrtf(bn2v[o] + EPS_BN) * bn2g[o] + bn2b[o];
        acc += v * lin_w[o * 2 + c];
    }
    out[t] = acc;
}

// ---------------- host-side launch ----------------
extern "C" void kernel_launch(void* const* d_in, const int* in_sizes, int n_in,
                              void* d_out, int out_size, void* d_ws, size_t ws_size,
                              hipStream_t stream) {
    const float* x    = (const float*)d_in[0];
    const int*   ei   = (const int*)d_in[1];
    const int*   bat  = (const int*)d_in[2];
    const float* W1   = (const float*)d_in[3];
    const float* at_s1 = (const float*)d_in[4];
    const float* at_d1 = (const float*)d_in[5];
    const float* b1   = (const float*)d_in[6];
    const float* bn1g = (const float*)d_in[7];
    const float* bn1b = (const float*)d_in[8];
    const float* bn1m = (const float*)d_in[9];
    const float* bn1v = (const float*)d_in[10];
    const float* W2   = (const float*)d_in[11];
    const float* at_s2 = (const float*)d_in[12];
    const float* at_d2 = (const float*)d_in[13];
    const float* b2   = (const float*)d_in[14];
    const float* bn2g = (const float*)d_in[15];
    const float* bn2b = (const float*)d_in[16];
    const float* bn2m = (const float*)d_in[17];
    const float* bn2v = (const float*)d_in[18];
    const float* linw = (const float*)d_in[19];
    const float* linb = (const float*)d_in[20];
    float* out = (float*)d_out;

    char* wsp = (char*)d_ws;
    auto alloc = [&](size_t bytes) -> void* {
        void* p = (void*)wsp;
        wsp += (bytes + 255) & ~(size_t)255;
        return p;
    };
    unsigned char*  h8   = (unsigned char*)alloc((size_t)NN * DD1);     // fp8 gemm output
    unsigned char*  h1p  = (unsigned char*)alloc((size_t)NN * DD1);     // agg1 out, FP8 (gemm_fp8 A)
    __hip_bfloat16* xb   = (__hip_bfloat16*)alloc((size_t)NN * NF * 2);
    __hip_bfloat16* w1t  = (__hip_bfloat16*)alloc((size_t)DD1 * NF * 2);
    unsigned char*  w2t8 = (unsigned char*)alloc((size_t)DD1 * DD1);    // W2^T * 16, fp8
    float* asb   = (float*)alloc((size_t)NN * NH * 4);
    float* adb   = (float*)alloc((size_t)NN * NH * 4);
    int*   deg   = (int*)alloc((size_t)NN * 4);
    int*   rowp  = (int*)alloc((size_t)(NN + 1) * 4);
    int*   curs  = (int*)alloc((size_t)NN * 4);
    int*   csr   = (int*)alloc((size_t)ETOT * 4);
    float* h2part = (float*)alloc((size_t)NN * 7 * OC * 4);
    float* sums  = (float*)alloc((size_t)(NG * OC + NG) * 4);
    float* cnt   = sums + NG * OC;

    hipMemsetAsync(deg, 0, (size_t)NN * 4, stream);
    hipMemsetAsync(sums, 0, (size_t)(NG * OC + NG) * 4, stream);

    cast_bf16_kernel<<<(NN * NF + 255) / 256, 256, 0, stream>>>(x, xb, NN * NF);
    transpose_cast_kernel<<<dim3(DD1 / 32, NF / 32), 256, 0, stream>>>(W1, w1t, NF, DD1);
    transpose_fp8_kernel<<<dim3(DD1 / 32, DD1 / 32), 256, 0, stream>>>(W2, w2t8, DD1, DD1);
    hist_kernel<<<(ETOT + 255) / 256, 256, 0, stream>>>(ei, deg);
    scan_kernel<<<1, 1024, 0, stream>>>(deg, rowp, curs);
    scatter_kernel<<<(ETOT + 255) / 256, 256, 0, stream>>>(ei, curs, csr);

    const int AGG_BLOCKS = (7 * (NN / GRP) + 3) / 4;
    const int NBY192 = (NN + 191) / 192;                   // 105
    const int GEMM_BLOCKS = NBY192 * (DD1 / 256);          // 735

    // layer 1 (bf16 gemm, fused scores)
    gemm_192<<<GEMM_BLOCKS, 512, 0, stream>>>(xb, w1t, h8, at_s1, at_d1, asb, adb, NN, DD1, NF);
    attn_aggregate<1><<<AGG_BLOCKS, 256, 0, stream>>>(rowp, csr, asb, adb, h8, b1, bn1g, bn1b, bn1m, bn1v, (void*)h1p);

    // layer 2 (fp8 gemm, fused scores)
    gemm_fp8<<<GEMM_BLOCKS, 512, 0, stream>>>(h1p, w2t8, h8, at_s2, at_d2, asb, adb, NN, DD1, DD1);
    attn_aggregate<2><<<AGG_BLOCKS, 256, 0, stream>>>(rowp, csr, asb, adb, h8, b2, bn2g, bn2b, bn2m, bn2v, (void*)h2part);

    pool_kernel<<<NG * 8, 256, 0, stream>>>(h2part, bat, sums, cnt);
    final_kernel<<<1, 128, 0, stream>>>(sums, cnt, b2, bn2g, bn2b, bn2m, bn2v, linw, linb, out);
}

// Round 17
// 497.794 us; speedup vs baseline: 1.2757x; 1.0164x over previous
//
#include <hip/hip_runtime.h>
#include <hip/hip_bf16.h>
#include <hip/hip_fp8.h>
#include <cstdint>
#include <cstddef>

// Problem constants
#define NN     20000     // nodes
#define NF     128       // in features
#define NH     56        // heads
#define OC     32        // out channels per head
#define DD1    1792      // NH*OC
#define NE     100000    // edges (before self loops)
#define ETOT   120000    // edges + self loops
#define NG     50        // graphs
#define EPS_BN 1e-5f
#define GRP    16        // nodes per wave in aggregate
#define EB     16        // edge batch (round-5 proven single-buffer)
#define W2SCL  16.0f     // W2 pre-scale (fp8 range); epilogue multiplies by 1/W2SCL

typedef __bf16 bf16x8 __attribute__((ext_vector_type(8)));
typedef float  floatx4 __attribute__((ext_vector_type(4)));
typedef float  floatx2 __attribute__((ext_vector_type(2)));
typedef long   longx2  __attribute__((ext_vector_type(2)));
typedef unsigned int u32;
typedef __attribute__((address_space(1))) u32 gu32;
typedef __attribute__((address_space(3))) u32 lu32;

__device__ __forceinline__ void async_copy16(void* lds, const void* g) {
    __builtin_amdgcn_global_load_lds((gu32*)const_cast<void*>(g), (lu32*)lds, 16, 0, 0);
}

// 16B LDS load via the bf16x8-typed pattern (emits ds_read_b128), bit-cast to the
// fp8-MFMA operand pair.
__device__ __forceinline__ longx2 ld_lds16(const unsigned char* p) {
    bf16x8 raw = *(const bf16x8*)p;
    return __builtin_bit_cast(longx2, raw);
}

// decode 4 fp8 (e4m3, packed in u32) to 4 floats (HW cvt when available)
__device__ __forceinline__ void dec_fp8x4(u32 u, float* v) {
#if __has_builtin(__builtin_amdgcn_cvt_pk_f32_fp8)
    floatx2 lo = __builtin_amdgcn_cvt_pk_f32_fp8(u, false);
    floatx2 hi = __builtin_amdgcn_cvt_pk_f32_fp8(u, true);
    v[0] = lo[0]; v[1] = lo[1]; v[2] = hi[0]; v[3] = hi[1];
#else
    #pragma unroll
    for (int b = 0; b < 4; ++b) {
        __hip_fp8_e4m3 t;
        t.__x = (u >> (8 * b)) & 0xff;
        v[b] = (float)t;
    }
#endif
}

__device__ __forceinline__ u32 enc_fp8x4(float v0, float v1, float v2, float v3) {
#if __has_builtin(__builtin_amdgcn_cvt_pk_fp8_f32)
    u32 p01 = (u32)__builtin_amdgcn_cvt_pk_fp8_f32(v0, v1, 0, false);
    u32 p23 = (u32)__builtin_amdgcn_cvt_pk_fp8_f32(v2, v3, 0, false);
    return (p01 & 0xffff) | (p23 << 16);
#else
    __hip_fp8_e4m3 t0(v0), t1(v1), t2(v2), t3(v3);
    return (u32)t0.__x | ((u32)t1.__x << 8) | ((u32)t2.__x << 16) | ((u32)t3.__x << 24);
#endif
}

__device__ __forceinline__ void fma_fp8x4(u32 u, float a, float* acc) {
    float v[4];
    dec_fp8x4(u, v);
    #pragma unroll
    for (int b = 0; b < 4; ++b) acc[b] += a * v[b];
}

// ---- 16-lane row sum via DPP (VALU pipe, NO LDS traffic; round-13 proven) ----
template <int CTRL>
__device__ __forceinline__ float dpp_row_add(float x) {
    int v = __builtin_amdgcn_mov_dpp(__float_as_int(x), CTRL, 0xf, 0xf, true);
    return x + __int_as_float(v);
}
__device__ __forceinline__ float dpp_add16(float x) {
    x = dpp_row_add<0x128>(x);   // row_ror:8
    x = dpp_row_add<0x124>(x);   // row_ror:4
    x = dpp_row_add<78>(x);      // quad_perm [2,3,0,1] = xor2
    x = dpp_row_add<177>(x);     // quad_perm [1,0,3,2] = xor1
    return x;
}

// ---------------- elementwise cast fp32 -> bf16 ----------------
__global__ __launch_bounds__(256) void cast_bf16_kernel(const float* __restrict__ in,
                                                        __hip_bfloat16* __restrict__ out, int n) {
    int i = blockIdx.x * 256 + threadIdx.x;
    if (i < n) out[i] = __float2bfloat16(in[i]);
}

// ---------------- tiled transpose + cast: in[R][C] f32 -> out[C][R] bf16 ----------------
__global__ __launch_bounds__(256) void transpose_cast_kernel(const float* __restrict__ in,
                                                             __hip_bfloat16* __restrict__ out,
                                                             int R, int C) {
    __shared__ float tile[32][33];
    int c0 = blockIdx.x * 32, r0 = blockIdx.y * 32;
    int tx = threadIdx.x & 31, ty = threadIdx.x >> 5;   // ty in 0..7
    #pragma unroll
    for (int i = 0; i < 32; i += 8) {
        int r = r0 + ty + i, c = c0 + tx;
        if (r < R && c < C) tile[ty + i][tx] = in[(size_t)r * C + c];
    }
    __syncthreads();
    #pragma unroll
    for (int i = 0; i < 32; i += 8) {
        int c = c0 + ty + i, r = r0 + tx;
        if (c < C && r < R) out[(size_t)c * R + r] = __float2bfloat16(tile[tx][ty + i]);
    }
}

// ---------------- tiled transpose + fp8 cast with W2SCL pre-scale ----------------
__global__ __launch_bounds__(256) void transpose_fp8_kernel(const float* __restrict__ in,
                                                            unsigned char* __restrict__ out,
                                                            int R, int C) {
    __shared__ float tile[32][33];
    int c0 = blockIdx.x * 32, r0 = blockIdx.y * 32;
    int tx = threadIdx.x & 31, ty = threadIdx.x >> 5;
    #pragma unroll
    for (int i = 0; i < 32; i += 8) {
        int r = r0 + ty + i, c = c0 + tx;
        if (r < R && c < C) tile[ty + i][tx] = in[(size_t)r * C + c];
    }
    __syncthreads();
    #pragma unroll
    for (int i = 0; i < 32; i += 8) {
        int c = c0 + ty + i, r = r0 + tx;
        if (c < C && r < R) {
            __hip_fp8_e4m3 t(tile[tx][ty + i] * W2SCL);
            out[(size_t)c * R + r] = t.__x;
        }
    }
}

// ---------------- CSR build: histogram / scan / scatter ----------------
__global__ __launch_bounds__(256) void hist_kernel(const int* __restrict__ ei, int* __restrict__ deg) {
    int i = blockIdx.x * 256 + threadIdx.x;
    if (i >= ETOT) return;
    int dst = (i < NE) ? ei[NE + i] : (i - NE);
    atomicAdd(&deg[dst], 1);
}

__global__ __launch_bounds__(1024) void scan_kernel(const int* __restrict__ deg,
                                                    int* __restrict__ rowptr,
                                                    int* __restrict__ cursor) {
    __shared__ int buf[1024];
    int t = threadIdx.x;
    const int CH = (NN + 1023) >> 10;   // 20
    int base = t * CH;
    int s = 0;
    for (int j = 0; j < CH; ++j) { int idx = base + j; if (idx < NN) s += deg[idx]; }
    buf[t] = s;
    __syncthreads();
    for (int off = 1; off < 1024; off <<= 1) {
        int v = (t >= off) ? buf[t - off] : 0;
        __syncthreads();
        buf[t] += v;
        __syncthreads();
    }
    int run = buf[t] - s;   // exclusive
    for (int j = 0; j < CH; ++j) {
        int idx = base + j;
        if (idx < NN) { rowptr[idx] = run; cursor[idx] = run; run += deg[idx]; }
    }
    if (t == 1023) rowptr[NN] = buf[1023];
}

__global__ __launch_bounds__(256) void scatter_kernel(const int* __restrict__ ei,
                                                      int* __restrict__ cursor,
                                                      int* __restrict__ csr_src) {
    int i = blockIdx.x * 256 + threadIdx.x;
    if (i >= ETOT) return;
    int s, d;
    if (i < NE) { s = ei[i]; d = ei[NE + i]; } else { s = i - NE; d = i - NE; }
    int pos = atomicAdd(&cursor[d], 1);
    csr_src[pos] = s;
}

// ---------------- bf16 MFMA GEMM (layer 1), 192x256, 3-phase — round-13 proven ----------------
__global__ __launch_bounds__(512, 2) void gemm_192(const __hip_bfloat16* __restrict__ A,
                                                   const __hip_bfloat16* __restrict__ Bt,
                                                   unsigned char* __restrict__ C8,
                                                   const float* __restrict__ att_src,
                                                   const float* __restrict__ att_dst,
                                                   float* __restrict__ as_,
                                                   float* __restrict__ ad_,
                                                   int M, int N, int K) {
    __shared__ __align__(16) unsigned short lds[2][28672];  // per buf: A[192][64] | B[256][64]
    const int tid  = threadIdx.x;
    const int lane = tid & 63, wave = tid >> 6;
    const int wm = wave >> 2, wn = wave & 3;     // 2 x 4 wave grid; per-wave C: 96 x 64

    const int nbx = N >> 8;                      // 7
    const int nby = (M + 191) / 192;             // 105
    const int nwg = nbx * nby;                   // 735
    const int q = nwg >> 3, r = nwg & 7;
    const int xcd = blockIdx.x & 7, bidx = blockIdx.x >> 3;
    const int wg = (xcd < r ? xcd * (q + 1) : r * (q + 1) + (xcd - r) * q) + bidx;
    const int by = wg / nbx, bx = wg - by * nbx;
    const int m0 = by * 192, n0 = bx << 8;

    const int NT = K >> 6;                       // K-tiles of 64 (layer 1: 2)

    const int qq = lane >> 4, rr = lane & 15;

    auto stageA = [&](int kt, int b) {
        #pragma unroll
        for (int i = 0; i < 3; ++i) {
            int slot = i * 512 + tid;
            int row = slot >> 3, pch = slot & 7;
            int lc = pch ^ (row & 7);
            int gr = m0 + row; if (gr > M - 1) gr = M - 1;
            async_copy16(&lds[b][slot * 8], A + (size_t)gr * K + (kt << 6) + lc * 8);
        }
    };
    auto stageB = [&](int kt, int b) {
        #pragma unroll
        for (int i = 0; i < 4; ++i) {
            int slot = i * 512 + tid;
            int row = slot >> 3, pch = slot & 7;
            int lc = pch ^ (row & 7);
            async_copy16(&lds[b][12288 + slot * 8], Bt + (size_t)(n0 + row) * K + (kt << 6) + lc * 8);
        }
    };

    floatx4 zero = {0.f, 0.f, 0.f, 0.f};
    floatx4 acc[6][4];
    #pragma unroll
    for (int i = 0; i < 6; ++i)
        #pragma unroll
        for (int jj = 0; jj < 4; ++jj) acc[i][jj] = zero;

    bf16x8 aF[3][2], bA[2][2], bB[2][2];

    auto loadA = [&](int b, int mg) {
        #pragma unroll
        for (int mf = 0; mf < 3; ++mf)
            #pragma unroll
            for (int s = 0; s < 2; ++s) {
                int row = wm * 96 + mg * 48 + mf * 16 + rr;
                int pch = (s * 4 + qq) ^ (row & 7);
                aF[mf][s] = *(const bf16x8*)&lds[b][row * 64 + pch * 8];
            }
    };
    auto loadB = [&](int b, bf16x8 (&bF)[2][2], int ng) {
        #pragma unroll
        for (int nf = 0; nf < 2; ++nf)
            #pragma unroll
            for (int s = 0; s < 2; ++s) {
                int row = wn * 64 + (ng * 2 + nf) * 16 + rr;
                int pch = (s * 4 + qq) ^ (row & 7);
                bF[nf][s] = *(const bf16x8*)&lds[b][12288 + row * 64 + pch * 8];
            }
    };
    auto mfmaQ = [&](int mg, int ng, bf16x8 (&bF)[2][2]) {
        #pragma unroll
        for (int mf = 0; mf < 3; ++mf)
            #pragma unroll
            for (int nf = 0; nf < 2; ++nf)
                #pragma unroll
                for (int s = 0; s < 2; ++s)
                    acc[mg * 3 + mf][ng * 2 + nf] = __builtin_amdgcn_mfma_f32_16x16x32_bf16(
                        aF[mf][s], bF[nf][s], acc[mg * 3 + mf][ng * 2 + nf], 0, 0, 0);
    };

#define SB0 __builtin_amdgcn_sched_barrier(0)
#define GBAR do { SB0; __builtin_amdgcn_s_barrier(); SB0; } while (0)

    stageB(0, 0); stageA(0, 0);
    stageB(1, 1); stageA(1, 1);
    SB0;
    asm volatile("s_waitcnt vmcnt(7)" ::: "memory");
    GBAR;

    for (int t = 0; t < NT; ++t) {
        const int p = t & 1;
        int tp = t + 2; while (tp >= NT) tp -= 2;

        loadA(p, 0); loadB(p, bA, 0);
        GBAR;
        __builtin_amdgcn_s_setprio(1);
        mfmaQ(0, 0, bA);
        __builtin_amdgcn_s_setprio(0);
        GBAR;

        loadB(p, bB, 1);
        stageB(tp, p);
        GBAR;
        __builtin_amdgcn_s_setprio(1);
        mfmaQ(0, 1, bB);
        __builtin_amdgcn_s_setprio(0);
        GBAR;

        loadA(p, 1);
        stageA(tp, p);
        SB0;
        asm volatile("s_waitcnt vmcnt(7)" ::: "memory");
        GBAR;
        __builtin_amdgcn_s_setprio(1);
        mfmaQ(1, 1, bB);
        mfmaQ(1, 0, bA);
        __builtin_amdgcn_s_setprio(0);
        GBAR;
    }
#undef GBAR
#undef SB0

    // epilogue 1: fp8 quantize + store
    #pragma unroll
    for (int mt = 0; mt < 6; ++mt) {
        #pragma unroll
        for (int r4 = 0; r4 < 4; ++r4) {
            int rowc = m0 + wm * 96 + mt * 16 + (lane >> 4) * 4 + r4;
            if (rowc < M) {
                u32 word = enc_fp8x4(acc[mt][0][r4], acc[mt][1][r4], acc[mt][2][r4], acc[mt][3][r4]);
                unsigned char q8[4] = { (unsigned char)(word & 0xff), (unsigned char)((word >> 8) & 0xff),
                                        (unsigned char)((word >> 16) & 0xff), (unsigned char)(word >> 24) };
                #pragma unroll
                for (int nt = 0; nt < 4; ++nt) {
                    int col = n0 + wn * 64 + nt * 16 + (lane & 15);
                    C8[(size_t)rowc * N + col] = q8[nt];
                }
            }
        }
    }

    // epilogue 2: fused attention scores (DPP row-sum, round-13 proven)
    {
        const int li = lane & 15;
        const int h0 = bx * 8 + wn * 2;
        float ws00 = att_src[(h0)     * OC + li],      ws01 = att_src[(h0)     * OC + 16 + li];
        float ws10 = att_src[(h0 + 1) * OC + li],      ws11 = att_src[(h0 + 1) * OC + 16 + li];
        float wd00 = att_dst[(h0)     * OC + li],      wd01 = att_dst[(h0)     * OC + 16 + li];
        float wd10 = att_dst[(h0 + 1) * OC + li],      wd11 = att_dst[(h0 + 1) * OC + 16 + li];
        #pragma unroll
        for (int mt = 0; mt < 6; ++mt) {
            #pragma unroll
            for (int r4 = 0; r4 < 4; ++r4) {
                float s0 = dpp_add16(acc[mt][0][r4] * ws00 + acc[mt][1][r4] * ws01);
                float s1 = dpp_add16(acc[mt][2][r4] * ws10 + acc[mt][3][r4] * ws11);
                float d0 = dpp_add16(acc[mt][0][r4] * wd00 + acc[mt][1][r4] * wd01);
                float d1 = dpp_add16(acc[mt][2][r4] * wd10 + acc[mt][3][r4] * wd11);
                int rowc = m0 + wm * 96 + mt * 16 + (lane >> 4) * 4 + r4;
                if (li == 0 && rowc < M) {
                    as_[(size_t)rowc * NH + h0]     = s0;
                    as_[(size_t)rowc * NH + h0 + 1] = s1;
                    ad_[(size_t)rowc * NH + h0]     = d0;
                    ad_[(size_t)rowc * NH + h0 + 1] = d1;
                }
            }
        }
    }
}

// ---------------- fp8 MFMA GEMM (layer 2), 192x256, BK=128 — bf16-identical LDS reads ----------------
// k-permutation with chunk mapping ch = (j*4 + qq) ^ (row&7): sub-slice (j,half) where lane qq
// supplies k from chunk j*4+qq (positional k-matching, A/B share the formula). This makes every
// LDS read byte address IDENTICAL to the bf16 kernel's measured-0-conflict pattern (round 15/16's
// ch = qq*2+j gave quarter-stride-2 chunk constants and a deterministic 6.59e6-conflict residue).
__global__ __launch_bounds__(512, 2) void gemm_fp8(const unsigned char* __restrict__ A,
                                                   const unsigned char* __restrict__ Bt,
                                                   unsigned char* __restrict__ C8,
                                                   const float* __restrict__ att_src,
                                                   const float* __restrict__ att_dst,
                                                   float* __restrict__ as_,
                                                   float* __restrict__ ad_,
                                                   int M, int N, int K) {
    __shared__ __align__(16) unsigned char lds8[2][57344];  // per buf: A[192][128B] | B[256][128B]
    const int tid  = threadIdx.x;
    const int lane = tid & 63, wave = tid >> 6;
    const int wm = wave >> 2, wn = wave & 3;     // 2 x 4 wave grid; per-wave C: 96 x 64

    const int nbx = N >> 8;                      // 7
    const int nby = (M + 191) / 192;             // 105
    const int nwg = nbx * nby;                   // 735
    const int q = nwg >> 3, r = nwg & 7;
    const int xcd = blockIdx.x & 7, bidx = blockIdx.x >> 3;
    const int wg = (xcd < r ? xcd * (q + 1) : r * (q + 1) + (xcd - r) * q) + bidx;
    const int by = wg / nbx, bx = wg - by * nbx;
    const int m0 = by * 192, n0 = bx << 8;

    const int NT = K >> 7;                       // K-tiles of 128: 14

    const int qq = lane >> 4, rr = lane & 15;

    auto stageA = [&](int kt, int b) {           // 192 rows x 8 chunks = 1536 slots = 3/thread
        #pragma unroll
        for (int i = 0; i < 3; ++i) {
            int slot = i * 512 + tid;
            int row = slot >> 3, pch = slot & 7;
            int lc = pch ^ (row & 7);            // pre-swizzled global source (rule #21)
            int gr = m0 + row; if (gr > M - 1) gr = M - 1;
            async_copy16(&lds8[b][slot * 16], A + (size_t)gr * K + (kt << 7) + lc * 16);
        }
    };
    auto stageB = [&](int kt, int b) {           // 256 rows x 8 chunks = 2048 slots = 4/thread
        #pragma unroll
        for (int i = 0; i < 4; ++i) {
            int slot = i * 512 + tid;
            int row = slot >> 3, pch = slot & 7;
            int lc = pch ^ (row & 7);
            async_copy16(&lds8[b][24576 + slot * 16], Bt + (size_t)(n0 + row) * K + (kt << 7) + lc * 16);
        }
    };

    floatx4 zero = {0.f, 0.f, 0.f, 0.f};
    floatx4 acc[6][4];
    #pragma unroll
    for (int i = 0; i < 6; ++i)
        #pragma unroll
        for (int jj = 0; jj < 4; ++jj) acc[i][jj] = zero;

    longx2 aF[3][2], bA[2][2], bB[2][2];         // [frag][j]: .x = half 0, .y = half 1

    auto loadA = [&](int b, int mg) {
        #pragma unroll
        for (int mf = 0; mf < 3; ++mf)
            #pragma unroll
            for (int j = 0; j < 2; ++j) {
                int row = wm * 96 + mg * 48 + mf * 16 + rr;
                int ch = ((j << 2) + qq) ^ (row & 7);        // bf16-identical chunk constants
                aF[mf][j] = ld_lds16(&lds8[b][row * 128 + ch * 16]);
            }
    };
    auto loadB = [&](int b, longx2 (&bF)[2][2], int ng) {
        #pragma unroll
        for (int nf = 0; nf < 2; ++nf)
            #pragma unroll
            for (int j = 0; j < 2; ++j) {
                int row = wn * 64 + (ng * 2 + nf) * 16 + rr;
                int ch = ((j << 2) + qq) ^ (row & 7);        // bf16-identical chunk constants
                bF[nf][j] = ld_lds16(&lds8[b][24576 + row * 128 + ch * 16]);
            }
    };
    auto mfmaQ = [&](int mg, int ng, longx2 (&bF)[2][2]) {   // 24 MFMA quadrant (K=128)
        #pragma unroll
        for (int mf = 0; mf < 3; ++mf)
            #pragma unroll
            for (int nf = 0; nf < 2; ++nf)
                #pragma unroll
                for (int j = 0; j < 2; ++j)
                    #pragma unroll
                    for (int h = 0; h < 2; ++h)
                        acc[mg * 3 + mf][ng * 2 + nf] = __builtin_amdgcn_mfma_f32_16x16x32_fp8_fp8(
                            aF[mf][j][h], bF[nf][j][h], acc[mg * 3 + mf][ng * 2 + nf], 0, 0, 0);
    };

#define SB0 __builtin_amdgcn_sched_barrier(0)
#define GBAR do { SB0; __builtin_amdgcn_s_barrier(); SB0; } while (0)

    stageB(0, 0); stageA(0, 0);
    stageB(1, 1); stageA(1, 1);
    SB0;
    asm volatile("s_waitcnt vmcnt(7)" ::: "memory");
    GBAR;

    for (int t = 0; t < NT; ++t) {
        const int p = t & 1;
        int tp = t + 2; while (tp >= NT) tp -= 2;            // parity-preserving tail clamp

        loadA(p, 0); loadB(p, bA, 0);
        GBAR;
        __builtin_amdgcn_s_setprio(1);
        mfmaQ(0, 0, bA);
        __builtin_amdgcn_s_setprio(0);
        GBAR;

        loadB(p, bB, 1);
        stageB(tp, p);
        GBAR;
        __builtin_amdgcn_s_setprio(1);
        mfmaQ(0, 1, bB);
        __builtin_amdgcn_s_setprio(0);
        GBAR;

        loadA(p, 1);
        stageA(tp, p);
        SB0;
        asm volatile("s_waitcnt vmcnt(7)" ::: "memory");
        GBAR;
        __builtin_amdgcn_s_setprio(1);
        mfmaQ(1, 1, bB);
        mfmaQ(1, 0, bA);
        __builtin_amdgcn_s_setprio(0);
        GBAR;
    }
#undef GBAR
#undef SB0

    const float scl = 1.0f / W2SCL;

    // epilogue 1: unscale + fp8 quantize + store
    #pragma unroll
    for (int mt = 0; mt < 6; ++mt) {
        #pragma unroll
        for (int r4 = 0; r4 < 4; ++r4) {
            int rowc = m0 + wm * 96 + mt * 16 + (lane >> 4) * 4 + r4;
            if (rowc < M) {
                u32 word = enc_fp8x4(acc[mt][0][r4] * scl, acc[mt][1][r4] * scl,
                                     acc[mt][2][r4] * scl, acc[mt][3][r4] * scl);
                unsigned char q8[4] = { (unsigned char)(word & 0xff), (unsigned char)((word >> 8) & 0xff),
                                        (unsigned char)((word >> 16) & 0xff), (unsigned char)(word >> 24) };
                #pragma unroll
                for (int nt = 0; nt < 4; ++nt) {
                    int col = n0 + wn * 64 + nt * 16 + (lane & 15);
                    C8[(size_t)rowc * N + col] = q8[nt];
                }
            }
        }
    }

    // epilogue 2: fused attention scores (scale folded into the att weights)
    {
        const int li = lane & 15;
        const int h0 = bx * 8 + wn * 2;
        float ws00 = att_src[(h0)     * OC + li] * scl,  ws01 = att_src[(h0)     * OC + 16 + li] * scl;
        float ws10 = att_src[(h0 + 1) * OC + li] * scl,  ws11 = att_src[(h0 + 1) * OC + 16 + li] * scl;
        float wd00 = att_dst[(h0)     * OC + li] * scl,  wd01 = att_dst[(h0)     * OC + 16 + li] * scl;
        float wd10 = att_dst[(h0 + 1) * OC + li] * scl,  wd11 = att_dst[(h0 + 1) * OC + 16 + li] * scl;
        #pragma unroll
        for (int mt = 0; mt < 6; ++mt) {
            #pragma unroll
            for (int r4 = 0; r4 < 4; ++r4) {
                float s0 = dpp_add16(acc[mt][0][r4] * ws00 + acc[mt][1][r4] * ws01);
                float s1 = dpp_add16(acc[mt][2][r4] * ws10 + acc[mt][3][r4] * ws11);
                float d0 = dpp_add16(acc[mt][0][r4] * wd00 + acc[mt][1][r4] * wd01);
                float d1 = dpp_add16(acc[mt][2][r4] * wd10 + acc[mt][3][r4] * wd11);
                int rowc = m0 + wm * 96 + mt * 16 + (lane >> 4) * 4 + r4;
                if (li == 0 && rowc < M) {
                    as_[(size_t)rowc * NH + h0]     = s0;
                    as_[(size_t)rowc * NH + h0 + 1] = s1;
                    ad_[(size_t)rowc * NH + h0]     = d0;
                    ad_[(size_t)rowc * NH + h0 + 1] = d1;
                }
            }
        }
    }
}

// ---------------- node-boundary flush for the fused streaming aggregate ----------------
// LAYER==1: FP8 h1p[cur][slice] = fp8(BN1(ELU(acc/den + b1)))  (feeds gemm_fp8's A)
// LAYER==2: head-reduce in-wave, write per-slice partial to h2part[cur][f][32]
template <int LAYER>
__device__ __forceinline__ void flush_node(float* acc, float den, int cur, int f, int lane,
                                           const float* __restrict__ bias,
                                           const float* __restrict__ bng,
                                           const float* __restrict__ bnb,
                                           const float* __restrict__ bnm,
                                           const float* __restrict__ bnv,
                                           void* __restrict__ outp) {
    float inv = 1.f / den;
    #pragma unroll
    for (int k = 0; k < 4; ++k) acc[k] *= inv;

    if constexpr (LAYER == 1) {
        int d0 = f * 256 + lane * 4;
        float v0 = acc[0] + bias[d0 + 0];
        float v1 = acc[1] + bias[d0 + 1];
        float v2 = acc[2] + bias[d0 + 2];
        float v3 = acc[3] + bias[d0 + 3];
        v0 = v0 > 0.f ? v0 : expm1f(v0);
        v1 = v1 > 0.f ? v1 : expm1f(v1);
        v2 = v2 > 0.f ? v2 : expm1f(v2);
        v3 = v3 > 0.f ? v3 : expm1f(v3);
        v0 = (v0 - bnm[d0 + 0]) * rsqrtf(bnv[d0 + 0] + EPS_BN) * bng[d0 + 0] + bnb[d0 + 0];
        v1 = (v1 - bnm[d0 + 1]) * rsqrtf(bnv[d0 + 1] + EPS_BN) * bng[d0 + 1] + bnb[d0 + 1];
        v2 = (v2 - bnm[d0 + 2]) * rsqrtf(bnv[d0 + 2] + EPS_BN) * bng[d0 + 2] + bnb[d0 + 2];
        v3 = (v3 - bnm[d0 + 3]) * rsqrtf(bnv[d0 + 3] + EPS_BN) * bng[d0 + 3] + bnb[d0 + 3];
        u32 word = enc_fp8x4(v0, v1, v2, v3);
        *(u32*)((unsigned char*)outp + (size_t)cur * DD1 + d0) = word;
    } else {
        #pragma unroll
        for (int k = 0; k < 4; ++k) {
            acc[k] += __shfl_xor(acc[k], 8, 64);
            acc[k] += __shfl_xor(acc[k], 16, 64);
            acc[k] += __shfl_xor(acc[k], 32, 64);
        }
        if (lane < 8) {
            floatx4 pk;
            #pragma unroll
            for (int k = 0; k < 4; ++k) pk[k] = acc[k] * (1.f / NH);
            *(floatx4*)((float*)outp + ((size_t)cur * 7 + f) * OC + lane * 4) = pk;
        }
    }
    acc[0] = acc[1] = acc[2] = acc[3] = 0.f;
}

// ---------------- fused streaming aggregation with ONLINE SOFTMAX (round-5 proven) ----------------
template <int LAYER>
__global__ __launch_bounds__(256) void attn_aggregate(const int* __restrict__ rowptr,
                                                      const int* __restrict__ csr_src,
                                                      const float* __restrict__ as_,
                                                      const float* __restrict__ ad_,
                                                      const unsigned char* __restrict__ h8,
                                                      const float* __restrict__ bias,
                                                      const float* __restrict__ bng,
                                                      const float* __restrict__ bnb,
                                                      const float* __restrict__ bnm,
                                                      const float* __restrict__ bnv,
                                                      void* __restrict__ outp) {
    const int wv = threadIdx.x >> 6, lane = threadIdx.x & 63;
    const int w = blockIdx.x * 4 + wv;
    const int NWAVES = 7 * (NN / GRP);
    if (w >= NWAVES) return;
    const int f  = w % 7;             // feature slice (256 B of the 1792-B row)
    const int g  = w / 7;             // node group
    const int n0 = g * GRP;
    const int off  = f * 256 + lane * 4;
    const int head = f * 8 + (lane >> 3);

    const int e0 = rowptr[n0], e1 = rowptr[n0 + GRP];
    int cur = n0;
    int bound = rowptr[n0 + 1];
    float adv = ad_[(size_t)cur * NH + head];

    float acc[4] = {0.f, 0.f, 0.f, 0.f};
    float m = -1e30f, den = 0.f;

    for (int e = e0; e < e1; e += EB) {
        u32   hv[EB];
        float sv[EB];
        #pragma unroll
        for (int i = 0; i < EB; ++i) {
            int idx = (e + i < e1) ? e + i : e1 - 1;
            int s = csr_src[idx];
            hv[i] = *(const u32*)(h8 + (size_t)s * DD1 + off);
            sv[i] = as_[(size_t)s * NH + head];
        }
        #pragma unroll
        for (int i = 0; i < EB; ++i) {
            if (e + i >= e1) break;
            if (e + i >= bound) {
                flush_node<LAYER>(acc, den, cur, f, lane, bias, bng, bnb, bnm, bnv, outp);
                ++cur;
                bound = rowptr[cur + 1];
                adv = ad_[(size_t)cur * NH + head];
                m = -1e30f; den = 0.f;
            }
            float lr = sv[i] + adv;
            lr = lr > 0.f ? lr : 0.2f * lr;
            float wgt;
            if (lr > m) {
                float scale = __expf(m - lr);
                den = den * scale + 1.f;
                #pragma unroll
                for (int k = 0; k < 4; ++k) acc[k] *= scale;
                m = lr;
                wgt = 1.f;
            } else {
                wgt = __expf(lr - m);
                den += wgt;
            }
            fma_fp8x4(hv[i], wgt, acc);
        }
    }
    flush_node<LAYER>(acc, den, cur, f, lane, bias, bng, bnb, bnm, bnv, outp);
}

// ---------------- mean pool: sorted-batch segmented reduction, minimal atomics ----------------
__global__ __launch_bounds__(256) void pool_kernel(const float* __restrict__ h2part,
                                                   const int* __restrict__ batch,
                                                   float* __restrict__ sums,
                                                   float* __restrict__ cnt) {
    __shared__ float red[4][OC];
    const int g = blockIdx.x >> 3, c = blockIdx.x & 7;
    const int t = threadIdx.x;
    const int ch = t & 31, nl = t >> 5;
    int lo = 0, hi = NN;
    while (lo < hi) { int mid = (lo + hi) >> 1; if (batch[mid] < g) lo = mid + 1; else hi = mid; }
    const int s = lo;
    hi = NN;
    while (lo < hi) { int mid = (lo + hi) >> 1; if (batch[mid] <= g) lo = mid + 1; else hi = mid; }
    const int e = lo;
    const int len = e - s;
    const int n0 = s + (len * c) / 8;
    const int n1 = s + (len * (c + 1)) / 8;
    float acc = 0.f;
    for (int n = n0 + nl; n < n1; n += 8) {
        const float* p = h2part + (size_t)n * 7 * OC + ch;
        float a = 0.f;
        #pragma unroll
        for (int f = 0; f < 7; ++f) a += p[f * OC];
        acc += a;
    }
    acc += __shfl_xor(acc, 32, 64);
    if ((t & 32) == 0) red[t >> 6][ch] = acc;
    __syncthreads();
    if (t < OC) {
        float total = red[0][t] + red[1][t] + red[2][t] + red[3][t];
        atomicAdd(&sums[g * OC + t], total);
    }
    if (t == 0 && c == 0) cnt[g] = (float)len;
}

// final: pooled = sums/cnt; v = BN2(pooled + b2); out = v @ lin_w + lin_b
__global__ __launch_bounds__(128) void final_kernel(const float* __restrict__ sums,
                                                    const float* __restrict__ cnt,
                                                    const float* __restrict__ b2,
                                                    const float* __restrict__ bn2g,
                                                    const float* __restrict__ bn2b,
                                                    const float* __restrict__ bn2m,
                                                    const float* __restrict__ bn2v,
                                                    const float* __restrict__ lin_w,
                                                    const float* __restrict__ lin_b,
                                                    float* __restrict__ out) {
    int t = threadIdx.x;
    if (t >= NG * 2) return;
    int g = t >> 1, c = t & 1;
    float invc = 1.f / fmaxf(cnt[g], 1.f);
    float acc = lin_b[c];
    #pragma unroll
    for (int o = 0; o < OC; ++o) {
        float pooled = sums[g * OC + o] * invc + b2[o];
        float v = (pooled - bn2m[o]) * rsqrtf(bn2v[o] + EPS_BN) * bn2g[o] + bn2b[o];
        acc += v * lin_w[o * 2 + c];
    }
    out[t] = acc;
}

// ---------------- host-side launch ----------------
extern "C" void kernel_launch(void* const* d_in, const int* in_sizes, int n_in,
                              void* d_out, int out_size, void* d_ws, size_t ws_size,
                              hipStream_t stream) {
    const float* x    = (const float*)d_in[0];
    const int*   ei   = (const int*)d_in[1];
    const int*   bat  = (const int*)d_in[2];
    const float* W1   = (const float*)d_in[3];
    const float* at_s1 = (const float*)d_in[4];
    const float* at_d1 = (const float*)d_in[5];
    const float* b1   = (const float*)d_in[6];
    const float* bn1g = (const float*)d_in[7];
    const float* bn1b = (const float*)d_in[8];
    const float* bn1m = (const float*)d_in[9];
    const float* bn1v = (const float*)d_in[10];
    const float* W2   = (const float*)d_in[11];
    const float* at_s2 = (const float*)d_in[12];
    const float* at_d2 = (const float*)d_in[13];
    const float* b2   = (const float*)d_in[14];
    const float* bn2g = (const float*)d_in[15];
    const float* bn2b = (const float*)d_in[16];
    const float* bn2m = (const float*)d_in[17];
    const float* bn2v = (const float*)d_in[18];
    const float* linw = (const float*)d_in[19];
    const float* linb = (const float*)d_in[20];
    float* out = (float*)d_out;

    char* wsp = (char*)d_ws;
    auto alloc = [&](size_t bytes) -> void* {
        void* p = (void*)wsp;
        wsp += (bytes + 255) & ~(size_t)255;
        return p;
    };
    unsigned char*  h8   = (unsigned char*)alloc((size_t)NN * DD1);     // fp8 gemm output
    unsigned char*  h1p  = (unsigned char*)alloc((size_t)NN * DD1);     // agg1 out, FP8 (gemm_fp8 A)
    __hip_bfloat16* xb   = (__hip_bfloat16*)alloc((size_t)NN * NF * 2);
    __hip_bfloat16* w1t  = (__hip_bfloat16*)alloc((size_t)DD1 * NF * 2);
    unsigned char*  w2t8 = (unsigned char*)alloc((size_t)DD1 * DD1);    // W2^T * 16, fp8
    float* asb   = (float*)alloc((size_t)NN * NH * 4);
    float* adb   = (float*)alloc((size_t)NN * NH * 4);
    int*   deg   = (int*)alloc((size_t)NN * 4);
    int*   rowp  = (int*)alloc((size_t)(NN + 1) * 4);
    int*   curs  = (int*)alloc((size_t)NN * 4);
    int*   csr   = (int*)alloc((size_t)ETOT * 4);
    float* h2part = (float*)alloc((size_t)NN * 7 * OC * 4);
    float* sums  = (float*)alloc((size_t)(NG * OC + NG) * 4);
    float* cnt   = sums + NG * OC;

    hipMemsetAsync(deg, 0, (size_t)NN * 4, stream);
    hipMemsetAsync(sums, 0, (size_t)(NG * OC + NG) * 4, stream);

    cast_bf16_kernel<<<(NN * NF + 255) / 256, 256, 0, stream>>>(x, xb, NN * NF);
    transpose_cast_kernel<<<dim3(DD1 / 32, NF / 32), 256, 0, stream>>>(W1, w1t, NF, DD1);
    transpose_fp8_kernel<<<dim3(DD1 / 32, DD1 / 32), 256, 0, stream>>>(W2, w2t8, DD1, DD1);
    hist_kernel<<<(ETOT + 255) / 256, 256, 0, stream>>>(ei, deg);
    scan_kernel<<<1, 1024, 0, stream>>>(deg, rowp, curs);
    scatter_kernel<<<(ETOT + 255) / 256, 256, 0, stream>>>(ei, curs, csr);

    const int AGG_BLOCKS = (7 * (NN / GRP) + 3) / 4;
    const int NBY192 = (NN + 191) / 192;                   // 105
    const int GEMM_BLOCKS = NBY192 * (DD1 / 256);          // 735

    // layer 1 (bf16 gemm, fused scores)
    gemm_192<<<GEMM_BLOCKS, 512, 0, stream>>>(xb, w1t, h8, at_s1, at_d1, asb, adb, NN, DD1, NF);
    attn_aggregate<1><<<AGG_BLOCKS, 256, 0, stream>>>(rowp, csr, asb, adb, h8, b1, bn1g, bn1b, bn1m, bn1v, (void*)h1p);

    // layer 2 (fp8 gemm, fused scores)
    gemm_fp8<<<GEMM_BLOCKS, 512, 0, stream>>>(h1p, w2t8, h8, at_s2, at_d2, asb, adb, NN, DD1, DD1);
    attn_aggregate<2><<<AGG_BLOCKS, 256, 0, stream>>>(rowp, csr, asb, adb, h8, b2, bn2g, bn2b, bn2m, bn2v, (void*)h2part);

    pool_kernel<<<NG * 8, 256, 0, stream>>>(h2part, bat, sums, cnt);
    final_kernel<<<1, 128, 0, stream>>>(sums, cnt, b2, bn2g, bn2b, bn2m, bn2v, linw, linb, out);
}